// Round 1
// baseline (419.767 us; speedup 1.0000x reference)
//
#include <hip/hip_runtime.h>

typedef unsigned short u16;
typedef unsigned int   u32;
typedef __attribute__((ext_vector_type(8))) short bf16x8;   // 8 bf16 in 4 VGPRs
typedef __attribute__((ext_vector_type(4))) float f32x4;

#define S_LEN 2048
#define EMB   1024
#define NH    16
#define HD    64
#define FF_DIM 4096
#define NROWS 4096   // B*S

__device__ __forceinline__ float b2f(u16 u){ union{u32 i; float f;} c; c.i = ((u32)u)<<16; return c.f; }
// round-half-up bf16 pack: 2 VALU ops (vs 5 for RNE); differs from RNE only on exact ties
__device__ __forceinline__ u16 f2b(float f){ union{float f; u32 u;} c; c.f=f; return (u16)((c.u + 0x8000u)>>16); }
__device__ __forceinline__ float gelu_f(float x){ return 0.5f*x*(1.0f + erff(x*0.70710678118f)); }

// async global->LDS, 16B per lane; lds dest = wave-uniform base + lane*16 (m97/m104)
__device__ __forceinline__ void load_lds16(const u16* g, u16* l) {
    __builtin_amdgcn_global_load_lds((const __attribute__((address_space(1))) u32*)g,
                                     (__attribute__((address_space(3))) u32*)l, 16, 0, 0);
}

// ---------------------------------------------------------------- LayerNorm
template<int XF32>
__global__ __launch_bounds__(256)
void ln_kernel(const void* __restrict__ Xv, const float* __restrict__ G,
               const float* __restrict__ Bv, u16* __restrict__ Y)
{
    const int row = blockIdx.x, t = threadIdx.x;
    float v0, v1, v2, v3;
    if constexpr (XF32) {
        float4 r4 = ((const float4*)((const float*)Xv + (size_t)row*EMB))[t];
        v0 = r4.x; v1 = r4.y; v2 = r4.z; v3 = r4.w;
    } else {
        const u16* xr = (const u16*)Xv + (size_t)row*EMB;
        uint2 raw = *(const uint2*)(xr + t*4);
        v0 = b2f(raw.x & 0xffff); v1 = b2f(raw.x >> 16);
        v2 = b2f(raw.y & 0xffff); v3 = b2f(raw.y >> 16);
    }
    float s  = v0+v1+v2+v3;
    float s2 = v0*v0+v1*v1+v2*v2+v3*v3;
    #pragma unroll
    for (int off = 1; off < 64; off <<= 1) {
        s  += __shfl_xor(s,  off, 64);
        s2 += __shfl_xor(s2, off, 64);
    }
    __shared__ float ps[4], ps2[4];
    const int w = t >> 6, lane = t & 63;
    if (lane == 0) { ps[w] = s; ps2[w] = s2; }
    __syncthreads();
    s  = ps[0]+ps[1]+ps[2]+ps[3];
    s2 = ps2[0]+ps2[1]+ps2[2]+ps2[3];
    const float mu   = s * (1.0f/EMB);
    const float rstd = rsqrtf(fmaxf(s2*(1.0f/EMB) - mu*mu, 0.f) + 1e-5f);
    float4 g4 = ((const float4*)G)[t];
    float4 c4 = ((const float4*)Bv)[t];
    u32 lo = (u32)f2b((v0-mu)*rstd*g4.x + c4.x) | ((u32)f2b((v1-mu)*rstd*g4.y + c4.y) << 16);
    u32 hi = (u32)f2b((v2-mu)*rstd*g4.z + c4.z) | ((u32)f2b((v3-mu)*rstd*g4.w + c4.w) << 16);
    uint2 o; o.x = lo; o.y = hi;
    *(uint2*)(Y + (size_t)row*EMB + t*4) = o;
}

// ---------------------------------------------------------------- transpose+downconvert (f32 [K][N] -> bf16 [N][K])
__global__ __launch_bounds__(256)
void transpose_k(const float* __restrict__ in, u16* __restrict__ out, int K, int N)
{
    __shared__ __align__(16) u16 T[64*72];
    const int k0 = blockIdx.y*64, n0 = blockIdx.x*64, t = threadIdx.x;
    #pragma unroll
    for (int c = 0; c < 4; ++c) {
        int e = t*4 + c*1024, ki = e >> 6, nj = e & 63;
        float4 f = *(const float4*)(in + (size_t)(k0+ki)*N + n0 + nj);
        ushort4 s4; s4.x = f2b(f.x); s4.y = f2b(f.y); s4.z = f2b(f.z); s4.w = f2b(f.w);
        *(ushort4*)&T[ki*72 + nj] = s4;
    }
    __syncthreads();
    #pragma unroll
    for (int c = 0; c < 2; ++c) {
        int e = t*8 + c*2048, ni = e >> 6, kj = e & 63;
        uint4 v; u16* pv = (u16*)&v;
        #pragma unroll
        for (int j = 0; j < 8; ++j) pv[j] = T[(kj+j)*72 + ni];
        *(uint4*)(out + (size_t)(n0+ni)*K + k0 + kj) = v;
    }
}

// ---------------------------------------------------------------- bf16 transpose: V [B*H][S][64] -> V^T [B*H][64][S]
__global__ __launch_bounds__(256)
void vtrans(const u16* __restrict__ in, u16* __restrict__ out)
{
    __shared__ __align__(16) u16 T[64*72];
    const int bh = blockIdx.y, s0 = blockIdx.x*64, t = threadIdx.x;
    const size_t base = (size_t)bh * (S_LEN*HD);
    #pragma unroll
    for (int c = 0; c < 2; ++c) {
        int e = t*8 + c*2048, r = e >> 6, d = e & 63;
        *(uint4*)&T[r*72 + d] = *(const uint4*)(in + base + (size_t)(s0 + r)*HD + d);
    }
    __syncthreads();
    #pragma unroll
    for (int c = 0; c < 2; ++c) {
        int e = t*8 + c*2048, d = e >> 6, sj = e & 63;
        uint4 v; u16* pv = (u16*)&v;
        #pragma unroll
        for (int j = 0; j < 8; ++j) pv[j] = T[(sj + j)*72 + d];
        *(uint4*)(out + base + (size_t)d*S_LEN + s0 + sj) = v;
    }
}

// ---------------------------------------------------------------- GEMM: C = A @ Bt^T + bias
// Double-buffered 2-phase K-loop (T3 minimum recipe): per 32-K chunk, issue next
// chunk's global_load_lds into buf^1 BEFORE ds_read+MFMA of buf, then ONE
// __syncthreads (vmcnt(0) drain lands after a full chunk of compute -> load
// latency overlapped instead of serial). Same 32 KB LDS as the single-buffered
// 64-K version (2 bufs x 32-K chunk).
// TM: 128 (wave grid 2x2 of 64x64) or 64 (wave grid 2x2 of 32x64; grid-x = M-tiles for XCD A-locality).
// MODE 0: plain  1: +res  2: gelu  5: fused QKV (C=Q,C2=K,C3=V, head-split [B,H,S,D])
// RESF: res f32(1)/bf16(0).  OUTF: C f32(1)/bf16(0).
template<int MODE, int RESF, int OUTF, int TM>
__global__ __launch_bounds__(256)
void gemm_bt(const u16* __restrict__ A, const u16* __restrict__ Bt,
             const float* __restrict__ bias, const float* __restrict__ bias2,
             const float* __restrict__ bias3, const void* __restrict__ res,
             void* __restrict__ C, void* __restrict__ C2, void* __restrict__ C3,
             int M, int N, int K)
{
    constexpr int MT  = (TM == 128) ? 4 : 2;        // 16-row m-tiles per wave
    constexpr int ACH = TM * 32;                    // u16 per A k-chunk
    __shared__ __align__(16) u16 Sm[(TM == 128) ? 16384 : 12288];
    u16* As = Sm;
    u16* Bs = Sm + 2*ACH;
    const int t = threadIdx.x;
    const int m0 = (TM == 128) ? blockIdx.y*128 : blockIdx.x*64;
    const int n0 = (TM == 128) ? blockIdx.x*128 : blockIdx.y*128;
    const int wave = t >> 6, lane = t & 63;
    const int wm = (wave >> 1) * (TM/2);
    const int wn = (wave & 1) * 64;
    const int lr = lane & 15, quad = lane >> 4;

    const u16* gA = A  + (size_t)(m0 + wave*16 + (lane >> 2))*K + (lane & 3)*8;
    const u16* gB = Bt + (size_t)(n0 + wave*16 + (lane >> 2))*K + (lane & 3)*8;

    f32x4 acc[MT][4];
    const f32x4 fzero = {0.f, 0.f, 0.f, 0.f};
    #pragma unroll
    for (int mt = 0; mt < MT; ++mt)
        #pragma unroll
        for (int nt = 0; nt < 4; ++nt) acc[mt][nt] = fzero;

    // stage 32-K chunk cc into buffer p
    auto STAGE = [&](int cc, int p) {
        const u16* a = gA + cc*32;
        const u16* b = gB + cc*32;
        load_lds16(a, As + p*ACH + wave*512);
        if constexpr (TM == 128)
            load_lds16(a + (size_t)64*K, As + p*ACH + wave*512 + 2048);
        load_lds16(b, Bs + p*4096 + wave*512);
        load_lds16(b + (size_t)64*K, Bs + p*4096 + wave*512 + 2048);
    };
    // consume buffer p: 8 ds_read_b128 + MT*4 MFMA
    auto COMPUTE = [&](int p) {
        bf16x8 af[MT], bf[4];
        #pragma unroll
        for (int i = 0; i < MT; ++i)
            af[i] = *(const bf16x8*)&As[p*ACH + (wm + i*16 + lr)*32 + quad*8];
        #pragma unroll
        for (int i = 0; i < 4; ++i)
            bf[i] = *(const bf16x8*)&Bs[p*4096 + (wn + i*16 + lr)*32 + quad*8];
        #pragma unroll
        for (int mt = 0; mt < MT; ++mt)
            #pragma unroll
            for (int nt = 0; nt < 4; ++nt)
                acc[mt][nt] = __builtin_amdgcn_mfma_f32_16x16x32_bf16(af[mt], bf[nt], acc[mt][nt], 0, 0, 0);
    };

    const int NC = K >> 5;                // 32-K chunks
    STAGE(0, 0);
    __syncthreads();                      // chunk 0 landed (vmcnt(0)+barrier)
    for (int c = 0; c < NC - 1; ++c) {
        const int p = c & 1;
        STAGE(c + 1, p ^ 1);              // prefetch next chunk (other buffer)
        COMPUTE(p);                       // overlap its latency with this chunk
        __syncthreads();                  // drain+barrier: chunk c+1 ready, buf p reads done
    }
    COMPUTE((NC - 1) & 1);                // last chunk, nothing to prefetch

    // ---------------- epilogue: stage rows in LDS, store coalesced 16 B/lane rows
    u16* qkvDst = nullptr;
    if constexpr (MODE == 5) {
        int seg = n0 >> 10;
        qkvDst = (u16*)(seg == 0 ? C : (seg == 1 ? C2 : C3));
    }

    #pragma unroll
    for (int c = 0; c < (TM == 128 ? 2 : 1); ++c) {
        __syncthreads();
        if (TM == 64 || (wave >> 1) == c) {
            #pragma unroll
            for (int nt = 0; nt < 4; ++nt) {
                int colL = wn + nt*16 + lr;
                float bval;
                if constexpr (MODE == 5) {
                    int col = n0 + colL;
                    int seg = col >> 10, cs = col & 1023;
                    bval = (seg == 0 ? bias : (seg == 1 ? bias2 : bias3))[cs];
                } else {
                    bval = bias[n0 + colL];
                }
                #pragma unroll
                for (int mt = 0; mt < MT; ++mt) {
                    #pragma unroll
                    for (int r = 0; r < 4; ++r) {
                        int rowL = (TM == 128 ? mt*16 : wm + mt*16) + quad*4 + r;   // 0..63
                        float v = acc[mt][nt][r] + bval;
                        if constexpr (MODE == 2) v = gelu_f(v);
                        Sm[rowL*136 + colL] = f2b(v);
                    }
                }
            }
        }
        __syncthreads();
        #pragma unroll
        for (int i = 0; i < 4; ++i) {
            const int rowL = wave*16 + i*4 + (lane >> 4);
            const int colL = (lane & 15)*8;
            const int row  = m0 + c*64 + rowL;
            const u16* src = &Sm[rowL*136 + colL];
            if constexpr (MODE == 5) {
                int cs = (n0 + colL) & 1023;
                int h = cs >> 6, d = cs & 63;
                int b_ = row >> 11, s = row & 2047;
                u16* dst = qkvDst + ((((size_t)(b_*NH + h))*S_LEN + s) << 6) + d;
                *(uint4*)dst = *(const uint4*)src;
            } else {
                size_t base = (size_t)row*N + n0 + colL;
                if constexpr (MODE == 1 || OUTF) {
                    uint4 sv = *(const uint4*)src;
                    const u16* sp = (const u16*)&sv;
                    float f[8];
                    #pragma unroll
                    for (int j = 0; j < 8; ++j) f[j] = b2f(sp[j]);
                    if constexpr (MODE == 1) {
                        if constexpr (RESF) {
                            const float* rp = (const float*)res + base;
                            float4 r0 = *(const float4*)rp, r1 = *(const float4*)(rp+4);
                            f[0]+=r0.x; f[1]+=r0.y; f[2]+=r0.z; f[3]+=r0.w;
                            f[4]+=r1.x; f[5]+=r1.y; f[6]+=r1.z; f[7]+=r1.w;
                        } else {
                            uint4 rv = *(const uint4*)((const u16*)res + base);
                            const u16* rp = (const u16*)&rv;
                            #pragma unroll
                            for (int j = 0; j < 8; ++j) f[j] += b2f(rp[j]);
                        }
                    }
                    if constexpr (OUTF) {
                        float* op = (float*)C + base;
                        float4 o0 = {f[0],f[1],f[2],f[3]}, o1 = {f[4],f[5],f[6],f[7]};
                        *(float4*)op = o0; *(float4*)(op+4) = o1;
                    } else {
                        u16 ov[8];
                        #pragma unroll
                        for (int j = 0; j < 8; ++j) ov[j] = f2b(f[j]);
                        *(uint4*)((u16*)C + base) = *(const uint4*)ov;
                    }
                } else {
                    *(uint4*)((u16*)C + base) = *(const uint4*)src;
                }
            }
        }
    }
}

// ---------------------------------------------------------------- attention (causal)
// Grid (bh fastest): XCD-local KV. Block handles pair {pr, 31-pr}; ONE merged K-loop,
// K/V tiles double-buffered: stage kb+1 via global_load_lds BEFORE computing kb,
// single bottom __syncthreads per kb (drain overlapped with 2-tile compute).
// Q,K: [B*H][S][64]; Vt: [B*H][64][S]; O: [B][S][1024]
__global__ __launch_bounds__(256, 2)
void attn_kernel(const u16* __restrict__ Q, const u16* __restrict__ Kg,
                 const u16* __restrict__ Vt, u16* __restrict__ O)
{
    const int bh = blockIdx.x;            // fastest -> XCD = bh % 8
    const int pr = blockIdx.y;            // 0..15
    const int qta = pr, qtb = 31 - pr;
    const int t = threadIdx.x, wave = t >> 6, lane = t & 63;
    const int lr = lane & 15, quad = lane >> 4;

    __shared__ __align__(16) u16 Ks[8192];        // [2 buf][2 k-half][64][32]
    __shared__ __align__(16) u16 Vs[8192];        // [2 buf][2 k-half][64][32]
    __shared__ __align__(16) u16 Ps[4][16*72];    // wave-private P round-trip

    const size_t qkbase = (size_t)bh * (S_LEN*HD);
    const int b = bh >> 4, h = bh & 15;
    u16* Pw = Ps[wave];
    const f32x4 fzero = {0.f, 0.f, 0.f, 0.f};

    const u16* qpa = Q + qkbase + (size_t)(qta*64 + wave*16 + lr)*HD + quad*8;
    const u16* qpb = Q + qkbase + (size_t)(qtb*64 + wave*16 + lr)*HD + quad*8;
    bf16x8 qa0 = *(const bf16x8*)qpa, qa1 = *(const bf16x8*)(qpa + 32);
    bf16x8 qb0 = *(const bf16x8*)qpb, qb1 = *(const bf16x8*)(qpb + 32);

    f32x4 oa[4], ob[4];
    float la[4], lb[4];
    #pragma unroll
    for (int dt = 0; dt < 4; ++dt) { oa[dt] = fzero; ob[dt] = fzero; }
    #pragma unroll
    for (int r = 0; r < 4; ++r) { la[r] = 0.f; lb[r] = 0.f; }

    const u16* gK = Kg + qkbase + (size_t)(wave*16 + (lane>>2))*HD + (lane&3)*8;
    const u16* gV = Vt + qkbase + (size_t)(wave*16 + (lane>>2))*S_LEN + (lane&3)*8;

    const int qrow_qa = qta*64 + wave*16 + quad*4;
    const int qrow_qb = qtb*64 + wave*16 + quad*4;

    auto STAGEKV = [&](int kb, int p) {
        load_lds16(gK + (size_t)kb*4096,      Ks + p*4096 + wave*512);
        load_lds16(gK + (size_t)kb*4096 + 32, Ks + p*4096 + wave*512 + 2048);
        load_lds16(gV + kb*64,                Vs + p*4096 + wave*512);
        load_lds16(gV + kb*64 + 32,           Vs + p*4096 + wave*512 + 2048);
    };

    STAGEKV(0, 0);
    __syncthreads();
    for (int kb = 0; kb <= qtb; ++kb) {
        const int p = kb & 1;
        if (kb < qtb) STAGEKV(kb + 1, p ^ 1);   // prefetch next K/V tile

        #pragma unroll
        for (int tile = 0; tile < 2; ++tile) {
            const int qt = tile ? qta : qtb;
            if (tile && kb > qta) break;
            bf16x8 qf0 = tile ? qa0 : qb0;
            bf16x8 qf1 = tile ? qa1 : qb1;
            f32x4* oacc = tile ? oa : ob;
            float* lp   = tile ? la : lb;
            const int qrowq = tile ? qrow_qa : qrow_qb;

            f32x4 sc[4];
            #pragma unroll
            for (int kt2 = 0; kt2 < 4; ++kt2) {
                bf16x8 kf0 = *(const bf16x8*)&Ks[p*4096 + (kt2*16 + lr)*32 + quad*8];
                bf16x8 kf1 = *(const bf16x8*)&Ks[p*4096 + 2048 + (kt2*16 + lr)*32 + quad*8];
                sc[kt2] = __builtin_amdgcn_mfma_f32_16x16x32_bf16(qf0, kf0, fzero, 0, 0, 0);
                sc[kt2] = __builtin_amdgcn_mfma_f32_16x16x32_bf16(qf1, kf1, sc[kt2], 0, 0, 0);
            }
            const bool diag = (kb == qt);
            #pragma unroll
            for (int r = 0; r < 4; ++r) {
                #pragma unroll
                for (int kt2 = 0; kt2 < 4; ++kt2) {
                    int kcol = kb*64 + kt2*16 + lr;
                    float pv = (!diag || kcol <= qrowq + r) ? __expf(fminf(sc[kt2][r]*0.125f, 30.f)) : 0.f;
                    lp[r] += pv;
                    Pw[(quad*4 + r)*72 + kt2*16 + lr] = f2b(pv);
                }
            }
            bf16x8 pf0 = *(const bf16x8*)&Pw[lr*72 + quad*8];
            bf16x8 pf1 = *(const bf16x8*)&Pw[lr*72 + 32 + quad*8];
            #pragma unroll
            for (int dt = 0; dt < 4; ++dt) {
                bf16x8 vf0 = *(const bf16x8*)&Vs[p*4096 + (dt*16 + lr)*32 + quad*8];
                bf16x8 vf1 = *(const bf16x8*)&Vs[p*4096 + 2048 + (dt*16 + lr)*32 + quad*8];
                oacc[dt] = __builtin_amdgcn_mfma_f32_16x16x32_bf16(pf0, vf0, oacc[dt], 0, 0, 0);
                oacc[dt] = __builtin_amdgcn_mfma_f32_16x16x32_bf16(pf1, vf1, oacc[dt], 0, 0, 0);
            }
        }
        __syncthreads();    // drain: kb+1 staged, buf p reads complete
    }

    #pragma unroll
    for (int tile = 0; tile < 2; ++tile) {
        const int qt = tile ? qta : qtb;
        f32x4* oacc = tile ? oa : ob;
        float* lp   = tile ? la : lb;
        #pragma unroll
        for (int r = 0; r < 4; ++r) {
            float v = lp[r];
            v += __shfl_xor(v, 1, 64); v += __shfl_xor(v, 2, 64);
            v += __shfl_xor(v, 4, 64); v += __shfl_xor(v, 8, 64);
            lp[r] = 1.0f / fmaxf(v, 1e-20f);
        }
        #pragma unroll
        for (int dt = 0; dt < 4; ++dt)
            #pragma unroll
            for (int r = 0; r < 4; ++r)
                Pw[(quad*4 + r)*64 + dt*16 + lr] = f2b(oacc[dt][r] * lp[r]);

        const int q = lane >> 2, d0 = (lane & 3)*16;
        u16* dst = O + ((size_t)(b*S_LEN + qt*64 + wave*16 + q))*EMB + h*HD + d0;
        *(uint4*)(dst)     = *(uint4*)&Pw[q*64 + d0];
        *(uint4*)(dst + 8) = *(uint4*)&Pw[q*64 + d0 + 8];
    }
}

// ---------------------------------------------------------------- launch
extern "C" void kernel_launch(void* const* d_in, const int* in_sizes, int n_in,
                              void* d_out, int out_size, void* d_ws, size_t ws_size,
                              hipStream_t stream)
{
    (void)in_sizes; (void)n_in; (void)out_size; (void)ws_size;
    const float* x    = (const float*)d_in[0];
    // d_in[1] = mask: causal tril, handled analytically
    const float* ln1g = (const float*)d_in[2];
    const float* ln1b = (const float*)d_in[3];
    const float* wq = (const float*)d_in[4];  const float* bq = (const float*)d_in[5];
    const float* wk = (const float*)d_in[6];  const float* bk = (const float*)d_in[7];
    const float* wv = (const float*)d_in[8];  const float* bv = (const float*)d_in[9];
    const float* wo = (const float*)d_in[10]; const float* bo = (const float*)d_in[11];
    const float* ln2g = (const float*)d_in[12]; const float* ln2b = (const float*)d_in[13];
    const float* w1 = (const float*)d_in[14]; const float* b1 = (const float*)d_in[15];
    const float* w2 = (const float*)d_in[16]; const float* b2 = (const float*)d_in[17];

    u16* ws = (u16*)d_ws;
    const size_t M1 = 1u << 20;             // 1M u16 elements (2 MB)
    u16* wqkvT = ws + 0*M1;                 // bf16 [3072][1024] = wqT|wkT|wvT contiguous
    u16* wqT = ws + 0*M1;
    u16* wkT = ws + 1*M1;
    u16* wvT = ws + 2*M1;
    u16* woT = ws + 3*M1;
    u16* w2T = ws + 0*M1;                   // bf16 [1024][4096], transposed AFTER wo-gemm
    u16* w1T = ws + 4*M1;                   // bf16 [4096][1024]
    u16* h0  = ws + 8*M1;                   // bf16 ln out (reused for ln2 out)
    u16* qb  = ws + 12*M1;                  // bf16 [B,H,S,D]
    u16* kb  = ws + 16*M1;                  // bf16 [B,H,S,D]
    u16* vT  = ws + 20*M1;                  // bf16 [B,H,D,S]
    u16* ao  = ws + 24*M1;                  // bf16 attn out [B,S,E]
    u16* vb  = ws + 24*M1;                  // bf16 V [B,H,S,D] (dead before attn writes ao)
    u16* x1  = ws + 28*M1;                  // bf16 residual-1 out
    u16* fb  = ws + 12*M1;                  // bf16 MLP hidden, overlays q/k/v/ao (dead)

    dim3 blk(256);
    transpose_k<<<dim3(16,16), blk, 0, stream>>>(wq, wqT, EMB, EMB);
    transpose_k<<<dim3(16,16), blk, 0, stream>>>(wk, wkT, EMB, EMB);
    transpose_k<<<dim3(16,16), blk, 0, stream>>>(wv, wvT, EMB, EMB);
    transpose_k<<<dim3(16,16), blk, 0, stream>>>(wo, woT, EMB, EMB);
    transpose_k<<<dim3(64,16), blk, 0, stream>>>(w1, w1T, EMB, FF_DIM);

    ln_kernel<1><<<NROWS, blk, 0, stream>>>(x, ln1g, ln1b, h0);

    gemm_bt<5,0,0,128><<<dim3(24,32), blk, 0, stream>>>(h0, wqkvT, bq, bk, bv, nullptr,
                                                        qb, kb, vb, NROWS, 3072, EMB);

    vtrans<<<dim3(32,32), blk, 0, stream>>>(vb, vT);

    attn_kernel<<<dim3(32,16), blk, 0, stream>>>(qb, kb, vT, ao);

    gemm_bt<1,1,0,64><<<dim3(64,8), blk, 0, stream>>>(ao, woT, bo, nullptr, nullptr, x,
                                                      x1, nullptr, nullptr, NROWS, EMB, EMB);

    transpose_k<<<dim3(16,64), blk, 0, stream>>>(w2, w2T, FF_DIM, EMB);

    ln_kernel<0><<<NROWS, blk, 0, stream>>>(x1, ln2g, ln2b, h0);

    gemm_bt<2,0,0,128><<<dim3(32,32), blk, 0, stream>>>(h0, w1T, b1, nullptr, nullptr, nullptr,
                                                        fb, nullptr, nullptr, NROWS, FF_DIM, EMB);
    gemm_bt<1,0,1,64><<<dim3(64,8), blk, 0, stream>>>(fb, w2T, b2, nullptr, nullptr, x1,
                                                      d_out, nullptr, nullptr, NROWS, EMB, FF_DIM);
}

// Round 3
// 374.592 us; speedup vs baseline: 1.1206x; 1.1206x over previous
//
#include <hip/hip_runtime.h>

typedef unsigned short u16;
typedef unsigned int   u32;
typedef __attribute__((ext_vector_type(8))) short bf16x8;   // 8 bf16 in 4 VGPRs
typedef __attribute__((ext_vector_type(4))) float f32x4;

#define S_LEN 2048
#define EMB   1024
#define NH    16
#define HD    64
#define FF_DIM 4096
#define NROWS 4096   // B*S

__device__ __forceinline__ float b2f(u16 u){ union{u32 i; float f;} c; c.i = ((u32)u)<<16; return c.f; }
// round-half-up bf16 pack: 2 VALU ops (vs 5 for RNE); differs from RNE only on exact ties
__device__ __forceinline__ u16 f2b(float f){ union{float f; u32 u;} c; c.f=f; return (u16)((c.u + 0x8000u)>>16); }
// fast erf-based gelu: A&S 7.1.26 poly, |eps_erf| ~1.5e-7 (invisible after bf16 round)
__device__ __forceinline__ float gelu_f(float x){
    float z  = x * 0.70710678118f;
    float az = fabsf(z);
    float t  = 1.0f / (1.0f + 0.3275911f * az);
    float p  = ((((1.061405429f*t - 1.453152027f)*t + 1.421413741f)*t - 0.284496736f)*t + 0.254829592f)*t;
    float e  = __expf(-az*az);
    float erfv = 1.0f - p*e;
    erfv = (z < 0.f) ? -erfv : erfv;
    return 0.5f*x*(1.0f + erfv);
}

// async global->LDS, 16B per lane; lds dest = wave-uniform base + lane*16 (m97/m104)
__device__ __forceinline__ void load_lds16(const u16* g, u16* l) {
    __builtin_amdgcn_global_load_lds((const __attribute__((address_space(1))) u32*)g,
                                     (__attribute__((address_space(3))) u32*)l, 16, 0, 0);
}

// ---------------------------------------------------------------- LayerNorm
template<int XF32>
__global__ __launch_bounds__(256)
void ln_kernel(const void* __restrict__ Xv, const float* __restrict__ G,
               const float* __restrict__ Bv, u16* __restrict__ Y)
{
    const int row = blockIdx.x, t = threadIdx.x;
    float v0, v1, v2, v3;
    if constexpr (XF32) {
        float4 r4 = ((const float4*)((const float*)Xv + (size_t)row*EMB))[t];
        v0 = r4.x; v1 = r4.y; v2 = r4.z; v3 = r4.w;
    } else {
        const u16* xr = (const u16*)Xv + (size_t)row*EMB;
        uint2 raw = *(const uint2*)(xr + t*4);
        v0 = b2f(raw.x & 0xffff); v1 = b2f(raw.x >> 16);
        v2 = b2f(raw.y & 0xffff); v3 = b2f(raw.y >> 16);
    }
    float s  = v0+v1+v2+v3;
    float s2 = v0*v0+v1*v1+v2*v2+v3*v3;
    #pragma unroll
    for (int off = 1; off < 64; off <<= 1) {
        s  += __shfl_xor(s,  off, 64);
        s2 += __shfl_xor(s2, off, 64);
    }
    __shared__ float ps[4], ps2[4];
    const int w = t >> 6, lane = t & 63;
    if (lane == 0) { ps[w] = s; ps2[w] = s2; }
    __syncthreads();
    s  = ps[0]+ps[1]+ps[2]+ps[3];
    s2 = ps2[0]+ps2[1]+ps2[2]+ps2[3];
    const float mu   = s * (1.0f/EMB);
    const float rstd = rsqrtf(fmaxf(s2*(1.0f/EMB) - mu*mu, 0.f) + 1e-5f);
    float4 g4 = ((const float4*)G)[t];
    float4 c4 = ((const float4*)Bv)[t];
    u32 lo = (u32)f2b((v0-mu)*rstd*g4.x + c4.x) | ((u32)f2b((v1-mu)*rstd*g4.y + c4.y) << 16);
    u32 hi = (u32)f2b((v2-mu)*rstd*g4.z + c4.z) | ((u32)f2b((v3-mu)*rstd*g4.w + c4.w) << 16);
    uint2 o; o.x = lo; o.y = hi;
    *(uint2*)(Y + (size_t)row*EMB + t*4) = o;
}

// ---------------------------------------------------------------- transpose+downconvert (f32 [K][N] -> bf16 [N][K])
__global__ __launch_bounds__(256)
void transpose_k(const float* __restrict__ in, u16* __restrict__ out, int K, int N)
{
    __shared__ __align__(16) u16 T[64*72];
    const int k0 = blockIdx.y*64, n0 = blockIdx.x*64, t = threadIdx.x;
    #pragma unroll
    for (int c = 0; c < 4; ++c) {
        int e = t*4 + c*1024, ki = e >> 6, nj = e & 63;
        float4 f = *(const float4*)(in + (size_t)(k0+ki)*N + n0 + nj);
        ushort4 s4; s4.x = f2b(f.x); s4.y = f2b(f.y); s4.z = f2b(f.z); s4.w = f2b(f.w);
        *(ushort4*)&T[ki*72 + nj] = s4;
    }
    __syncthreads();
    #pragma unroll
    for (int c = 0; c < 2; ++c) {
        int e = t*8 + c*2048, ni = e >> 6, kj = e & 63;
        uint4 v; u16* pv = (u16*)&v;
        #pragma unroll
        for (int j = 0; j < 8; ++j) pv[j] = T[(kj+j)*72 + ni];
        *(uint4*)(out + (size_t)(n0+ni)*K + k0 + kj) = v;
    }
}

// ---------------------------------------------------------------- bf16 transpose: V [B*H][S][64] -> V^T [B*H][64][S]
__global__ __launch_bounds__(256)
void vtrans(const u16* __restrict__ in, u16* __restrict__ out)
{
    __shared__ __align__(16) u16 T[64*72];
    const int bh = blockIdx.y, s0 = blockIdx.x*64, t = threadIdx.x;
    const size_t base = (size_t)bh * (S_LEN*HD);
    #pragma unroll
    for (int c = 0; c < 2; ++c) {
        int e = t*8 + c*2048, r = e >> 6, d = e & 63;
        *(uint4*)&T[r*72 + d] = *(const uint4*)(in + base + (size_t)(s0 + r)*HD + d);
    }
    __syncthreads();
    #pragma unroll
    for (int c = 0; c < 2; ++c) {
        int e = t*8 + c*2048, d = e >> 6, sj = e & 63;
        uint4 v; u16* pv = (u16*)&v;
        #pragma unroll
        for (int j = 0; j < 8; ++j) pv[j] = T[(sj + j)*72 + d];
        *(uint4*)(out + base + (size_t)d*S_LEN + s0 + sj) = v;
    }
}

// ================================================================ 256x256 8-phase GEMM
// T2+T3+T4+T5 (m194-m201 template, plain HIP): 512 thr = 8 waves (2M x 4N), BK=64,
// LDS 128 KiB = 2 buf x {A,B} x 2 k-halves x [256 rows][32 k] bf16.
// Bank swizzle (T2): involution on u16 offset  off ^= (off>>3)&0x18  (chunk bits 0..1 ^= chunk
//   bits 3..4, self-inverse) -> 16-lane fragment reads spread 2 lanes/bank (free, m136).
//   Applied on BOTH sides (rule 21): pre-swizzled per-lane GLOBAL source for global_load_lds
//   (linear LDS dest, m173) and on the ds_read byte offset.
// Schedule (T3+T4): 8 phases / 2 K-tiles per iter; per phase {10 ds_read_b128, 2 global_load_lds,
//   s_barrier, setprio(1), 16 MFMA, setprio(0), [vmcnt(8) on even phases], s_barrier}.
//   Stage stream runs 4-6 phases ahead; per-wave outstanding-load trace (2 loads/stage2):
//   steady state 8..12 in flight, vmcnt(8) retires exactly the half-tile pair read 1 phase later.
//   Slot-reuse: a slot's restage is issued >=1 barrier after its last reader's MFMA (lgkm drain)
//   and lands >=2 phases before its next read.
// MODE 2: gelu -> bf16 C.   MODE 5: fused QKV head-split scatter (C=Q, C2=K, C3=V).
__device__ __forceinline__ void stage2(const u16* s0, const u16* s1, int koff, u16* dst, int wave){
    load_lds16(s0 + koff, dst + wave*512);
    load_lds16(s1 + koff, dst + 4096 + wave*512);
}

template<int CBUF, int KS, int NHH, int TAILVM>
__device__ __forceinline__ void phase256(u16* Ls, f32x4 (&acc)[8][4],
    int wm, int wn, int lr, int quad, int wave,
    const u16* s0, const u16* s1, int koff, u16* dst)
{
    const u16* ak = Ls + CBUF*32768 + KS*8192;
    const u16* bk = Ls + CBUF*32768 + 16384 + KS*8192;
    bf16x8 af[8], bf[2];
    #pragma unroll
    for (int mf = 0; mf < 8; ++mf) {
        int off = (wm*128 + mf*16 + lr)*32 + quad*8;
        af[mf] = *(const bf16x8*)(ak + (off ^ ((off>>3)&0x18)));
    }
    #pragma unroll
    for (int nf = 0; nf < 2; ++nf) {
        int off = (wn*64 + NHH*32 + nf*16 + lr)*32 + quad*8;
        bf[nf] = *(const bf16x8*)(bk + (off ^ ((off>>3)&0x18)));
    }
    stage2(s0, s1, koff, dst, wave);
    __builtin_amdgcn_s_barrier();
    __builtin_amdgcn_s_setprio(1);
    #pragma unroll
    for (int mf = 0; mf < 8; ++mf) {
        acc[mf][NHH*2+0] = __builtin_amdgcn_mfma_f32_16x16x32_bf16(af[mf], bf[0], acc[mf][NHH*2+0], 0, 0, 0);
        acc[mf][NHH*2+1] = __builtin_amdgcn_mfma_f32_16x16x32_bf16(af[mf], bf[1], acc[mf][NHH*2+1], 0, 0, 0);
    }
    __builtin_amdgcn_s_setprio(0);
    if constexpr (TAILVM) asm volatile("s_waitcnt vmcnt(8)" ::: "memory");
    __builtin_amdgcn_s_barrier();
}

template<int MODE>
__global__ __launch_bounds__(512, 2)
void gemm256(const u16* __restrict__ A, const u16* __restrict__ Bt,
             const float* __restrict__ bias, const float* __restrict__ bias2,
             const float* __restrict__ bias3,
             void* __restrict__ C, void* __restrict__ C2, void* __restrict__ C3,
             int M, int N, int K)
{
    (void)M;
    __shared__ __align__(16) u16 Ls[65536];     // 128 KiB
    const int t = threadIdx.x;
    const int wave = t >> 6, lane = t & 63;
    const int wm = wave >> 2, wn = wave & 3;    // 2 x 4 wave grid
    const int lr = lane & 15, quad = lane >> 4;
    const int n0 = blockIdx.x*256, m0 = blockIdx.y*256;

    // per-lane pre-swizzled global sources: phys chunk c (16B) <- logical chunk c^((c>>3)&3)
    const int c0 = wave*64 + lane, c1 = 512 + wave*64 + lane;
    const int l0 = c0 ^ ((c0 >> 3) & 3), l1 = c1 ^ ((c1 >> 3) & 3);
    const int r0 = l0 >> 2, g0 = l0 & 3;
    const int r1 = l1 >> 2, g1 = l1 & 3;
    const u16* srcA0 = A  + (size_t)(m0 + r0)*K + g0*8;
    const u16* srcA1 = A  + (size_t)(m0 + r1)*K + g1*8;
    const u16* srcB0 = Bt + (size_t)(n0 + r0)*K + g0*8;
    const u16* srcB1 = Bt + (size_t)(n0 + r1)*K + g1*8;

    // LDS slot bases (u16 units)
    u16* A00 = Ls + 0;               // buf0 A kh0
    u16* A01 = Ls + 8192;            // buf0 A kh1
    u16* B00 = Ls + 16384;           // buf0 B kh0
    u16* B01 = Ls + 16384 + 8192;    // buf0 B kh1
    u16* A10 = Ls + 32768;           // buf1 A kh0
    u16* A11 = Ls + 32768 + 8192;    // buf1 A kh1
    u16* B10 = Ls + 32768 + 16384;   // buf1 B kh0
    u16* B11 = Ls + 32768 + 16384 + 8192;

    f32x4 acc[8][4];
    const f32x4 fzero = {0.f, 0.f, 0.f, 0.f};
    #pragma unroll
    for (int i = 0; i < 8; ++i)
        #pragma unroll
        for (int j = 0; j < 4; ++j) acc[i][j] = fzero;

    const int NT = K >> 6;   // K-tiles of 64 (power of 2: 16 or 64)

    // prologue: tile0 {Akh0,Bkh0,Akh1,Bkh1}, tile1 {Akh0,Bkh0}  (6 halves, 12 loads/wave)
    stage2(srcA0, srcA1, 0,   A00, wave);
    stage2(srcB0, srcB1, 0,   B00, wave);
    stage2(srcA0, srcA1, 32,  A01, wave);
    stage2(srcB0, srcB1, 32,  B01, wave);
    stage2(srcA0, srcA1, 64,  A10, wave);
    stage2(srcB0, srcB1, 64,  B10, wave);
    asm volatile("s_waitcnt vmcnt(8)" ::: "memory");   // tile0 kh0 (A,B) landed, all waves
    __builtin_amdgcn_s_barrier();

    for (int U = 0; U < NT; U += 2) {
        const int k1 = ((U+1) & (NT-1))*64;
        const int k2 = ((U+2) & (NT-1))*64;   // wraps at tail: redundant-but-safe reload
        const int k3 = ((U+3) & (NT-1))*64;
        // compute tile U (buf0)            stage target (slot free'd 1+ phases earlier)
        phase256<0,0,0,0>(Ls, acc, wm, wn, lr, quad, wave, srcA0, srcA1, k1+32, A11);
        phase256<0,0,1,1>(Ls, acc, wm, wn, lr, quad, wave, srcB0, srcB1, k1+32, B11);
        phase256<0,1,0,0>(Ls, acc, wm, wn, lr, quad, wave, srcA0, srcA1, k2,    A00);
        phase256<0,1,1,1>(Ls, acc, wm, wn, lr, quad, wave, srcB0, srcB1, k2,    B00);
        // compute tile U+1 (buf1)
        phase256<1,0,0,0>(Ls, acc, wm, wn, lr, quad, wave, srcA0, srcA1, k2+32, A01);
        phase256<1,0,1,1>(Ls, acc, wm, wn, lr, quad, wave, srcB0, srcB1, k2+32, B01);
        phase256<1,1,0,0>(Ls, acc, wm, wn, lr, quad, wave, srcA0, srcA1, k3,    A10);
        phase256<1,1,1,1>(Ls, acc, wm, wn, lr, quad, wave, srcB0, srcB1, k3,    B10);
    }

    // drain ALL DMAs (incl. wrapped tail stages) before repurposing LDS
    asm volatile("s_waitcnt vmcnt(0)" ::: "memory");
    __syncthreads();

    // ---------------- epilogue: bias(+gelu), stage [256][256] bf16 in LDS, coalesced stores
    float bv[4];
    #pragma unroll
    for (int nf = 0; nf < 4; ++nf) {
        const int col = n0 + wn*64 + nf*16 + lr;
        if constexpr (MODE == 5) {
            const int seg = n0 >> 10;    // 256 | 1024: no straddle
            bv[nf] = (seg == 0 ? bias : (seg == 1 ? bias2 : bias3))[col & 1023];
        } else {
            bv[nf] = bias[col];
        }
    }
    #pragma unroll
    for (int mf = 0; mf < 8; ++mf)
        #pragma unroll
        for (int nf = 0; nf < 4; ++nf)
            #pragma unroll
            for (int r = 0; r < 4; ++r) {
                float v = acc[mf][nf][r] + bv[nf];
                if constexpr (MODE == 2) v = gelu_f(v);
                Ls[(wm*128 + mf*16 + quad*4 + r)*256 + wn*64 + nf*16 + lr] = f2b(v);
            }
    __syncthreads();
    // 256x256 u16 = 8192 16B-chunks; 512 threads x 16 iters  (BUGFIX r2: was 8 -> half tile)
    #pragma unroll
    for (int j = 0; j < 16; ++j) {
        const int idx = j*512 + t;
        const int rr = idx >> 5, ck = idx & 31;
        const u16* src = Ls + rr*256 + ck*8;
        const int row = m0 + rr, col = n0 + ck*8;
        if constexpr (MODE == 5) {
            const int seg = n0 >> 10;
            u16* dstb = (u16*)(seg == 0 ? C : (seg == 1 ? C2 : C3));
            const int cs = col & 1023;
            const int h = cs >> 6, d = cs & 63;
            const int b_ = row >> 11, s = row & 2047;
            *(uint4*)(dstb + ((((size_t)(b_*NH + h))*S_LEN + s) << 6) + d) = *(const uint4*)src;
        } else {
            *(uint4*)((u16*)C + (size_t)row*N + col) = *(const uint4*)src;
        }
    }
}

// ---------------------------------------------------------------- GEMM: C = A @ Bt^T + bias  (m97-structure, round-0 form)
// TM: 128 (wave grid 2x2 of 64x64) or 64 (wave grid 2x2 of 32x64; grid-x = M-tiles for XCD A-locality).
// MODE 0: plain  1: +res  2: gelu  5: fused QKV (C=Q,C2=K,C3=V, head-split [B,H,S,D])
// RESF: res f32(1)/bf16(0).  OUTF: C f32(1)/bf16(0).
template<int MODE, int RESF, int OUTF, int TM>
__global__ __launch_bounds__(256)
void gemm_bt(const u16* __restrict__ A, const u16* __restrict__ Bt,
             const float* __restrict__ bias, const float* __restrict__ bias2,
             const float* __restrict__ bias3, const void* __restrict__ res,
             void* __restrict__ C, void* __restrict__ C2, void* __restrict__ C3,
             int M, int N, int K)
{
    constexpr int MT  = (TM == 128) ? 4 : 2;        // 16-row m-tiles per wave
    constexpr int ACH = TM * 32;                    // u16 per A k-chunk
    __shared__ __align__(16) u16 Sm[(TM == 128) ? 16384 : 12288];
    u16* As = Sm;
    u16* Bs = Sm + 2*ACH;
    const int t = threadIdx.x;
    const int m0 = (TM == 128) ? blockIdx.y*128 : blockIdx.x*64;
    const int n0 = (TM == 128) ? blockIdx.x*128 : blockIdx.y*128;
    const int wave = t >> 6, lane = t & 63;
    const int wm = (wave >> 1) * (TM/2);
    const int wn = (wave & 1) * 64;
    const int lr = lane & 15, quad = lane >> 4;

    const u16* gA = A  + (size_t)(m0 + wave*16 + (lane >> 2))*K + (lane & 3)*8;
    const u16* gB = Bt + (size_t)(n0 + wave*16 + (lane >> 2))*K + (lane & 3)*8;
    u16* lA = As + wave*512;
    u16* lB = Bs + wave*512;

    f32x4 acc[MT][4];
    const f32x4 fzero = {0.f, 0.f, 0.f, 0.f};
    #pragma unroll
    for (int mt = 0; mt < MT; ++mt)
        #pragma unroll
        for (int nt = 0; nt < 4; ++nt) acc[mt][nt] = fzero;

    for (int kt = 0; kt < K; kt += 64) {
        __syncthreads();
        #pragma unroll
        for (int c = 0; c < 2; ++c) {
            load_lds16(gA + c*32, lA + c*ACH);
            if constexpr (TM == 128)
                load_lds16(gA + (size_t)64*K + c*32, lA + c*ACH + 2048);
            load_lds16(gB + c*32, lB + c*4096);
            load_lds16(gB + (size_t)64*K + c*32, lB + c*4096 + 2048);
        }
        gA += 64; gB += 64;
        __syncthreads();
        #pragma unroll
        for (int ks = 0; ks < 2; ++ks) {
            bf16x8 af[MT], bf[4];
            #pragma unroll
            for (int i = 0; i < MT; ++i)
                af[i] = *(const bf16x8*)&As[ks*ACH + (wm + i*16 + lr)*32 + quad*8];
            #pragma unroll
            for (int i = 0; i < 4; ++i)
                bf[i] = *(const bf16x8*)&Bs[ks*4096 + (wn + i*16 + lr)*32 + quad*8];
            #pragma unroll
            for (int mt = 0; mt < MT; ++mt)
                #pragma unroll
                for (int nt = 0; nt < 4; ++nt)
                    acc[mt][nt] = __builtin_amdgcn_mfma_f32_16x16x32_bf16(af[mt], bf[nt], acc[mt][nt], 0, 0, 0);
        }
    }

    // ---------------- epilogue: stage rows in LDS, store coalesced 16 B/lane rows
    u16* qkvDst = nullptr;
    if constexpr (MODE == 5) {
        int seg = n0 >> 10;
        qkvDst = (u16*)(seg == 0 ? C : (seg == 1 ? C2 : C3));
    }

    #pragma unroll
    for (int c = 0; c < (TM == 128 ? 2 : 1); ++c) {
        __syncthreads();
        if (TM == 64 || (wave >> 1) == c) {
            #pragma unroll
            for (int nt = 0; nt < 4; ++nt) {
                int colL = wn + nt*16 + lr;
                float bval;
                if constexpr (MODE == 5) {
                    int col = n0 + colL;
                    int seg = col >> 10, cs = col & 1023;
                    bval = (seg == 0 ? bias : (seg == 1 ? bias2 : bias3))[cs];
                } else {
                    bval = bias[n0 + colL];
                }
                #pragma unroll
                for (int mt = 0; mt < MT; ++mt) {
                    #pragma unroll
                    for (int r = 0; r < 4; ++r) {
                        int rowL = (TM == 128 ? mt*16 : wm + mt*16) + quad*4 + r;   // 0..63
                        float v = acc[mt][nt][r] + bval;
                        if constexpr (MODE == 2) v = gelu_f(v);
                        Sm[rowL*136 + colL] = f2b(v);
                    }
                }
            }
        }
        __syncthreads();
        #pragma unroll
        for (int i = 0; i < 4; ++i) {
            const int rowL = wave*16 + i*4 + (lane >> 4);
            const int colL = (lane & 15)*8;
            const int row  = m0 + c*64 + rowL;
            const u16* src = &Sm[rowL*136 + colL];
            if constexpr (MODE == 5) {
                int cs = (n0 + colL) & 1023;
                int h = cs >> 6, d = cs & 63;
                int b_ = row >> 11, s = row & 2047;
                u16* dst = qkvDst + ((((size_t)(b_*NH + h))*S_LEN + s) << 6) + d;
                *(uint4*)dst = *(const uint4*)src;
            } else {
                size_t base = (size_t)row*N + n0 + colL;
                if constexpr (MODE == 1 || OUTF) {
                    uint4 sv = *(const uint4*)src;
                    const u16* sp = (const u16*)&sv;
                    float f[8];
                    #pragma unroll
                    for (int j = 0; j < 8; ++j) f[j] = b2f(sp[j]);
                    if constexpr (MODE == 1) {
                        if constexpr (RESF) {
                            const float* rp = (const float*)res + base;
                            float4 r0 = *(const float4*)rp, r1 = *(const float4*)(rp+4);
                            f[0]+=r0.x; f[1]+=r0.y; f[2]+=r0.z; f[3]+=r0.w;
                            f[4]+=r1.x; f[5]+=r1.y; f[6]+=r1.z; f[7]+=r1.w;
                        } else {
                            uint4 rv = *(const uint4*)((const u16*)res + base);
                            const u16* rp = (const u16*)&rv;
                            #pragma unroll
                            for (int j = 0; j < 8; ++j) f[j] += b2f(rp[j]);
                        }
                    }
                    if constexpr (OUTF) {
                        float* op = (float*)C + base;
                        float4 o0 = {f[0],f[1],f[2],f[3]}, o1 = {f[4],f[5],f[6],f[7]};
                        *(float4*)op = o0; *(float4*)(op+4) = o1;
                    } else {
                        u16 ov[8];
                        #pragma unroll
                        for (int j = 0; j < 8; ++j) ov[j] = f2b(f[j]);
                        *(uint4*)((u16*)C + base) = *(const uint4*)ov;
                    }
                } else {
                    *(uint4*)((u16*)C + base) = *(const uint4*)src;
                }
            }
        }
    }
}

// ---------------------------------------------------------------- attention (causal, round-0 form)
// Grid (bh fastest): XCD-local KV. Block handles pair {pr, 31-pr}; ONE merged K-loop
// stages each K/V tile once via global_load_lds (shared by 4 waves) and feeds up to
// two Q-tiles. LDS layout [k-half][row][32] keeps the m97 64-B-stride fragment reads.
// Q,K: [B*H][S][64]; Vt: [B*H][64][S]; O: [B][S][1024]
__global__ __launch_bounds__(256, 2)
void attn_kernel(const u16* __restrict__ Q, const u16* __restrict__ Kg,
                 const u16* __restrict__ Vt, u16* __restrict__ O)
{
    const int bh = blockIdx.x;            // fastest -> XCD = bh % 8
    const int pr = blockIdx.y;            // 0..15
    const int qta = pr, qtb = 31 - pr;
    const int t = threadIdx.x, wave = t >> 6, lane = t & 63;
    const int lr = lane & 15, quad = lane >> 4;

    __shared__ __align__(16) u16 Ks[4096];        // [2][64][32]
    __shared__ __align__(16) u16 Vs[4096];        // [2][64][32]
    __shared__ __align__(16) u16 Ps[4][16*72];    // wave-private P round-trip

    const size_t qkbase = (size_t)bh * (S_LEN*HD);
    const int b = bh >> 4, h = bh & 15;
    u16* Pw = Ps[wave];
    const f32x4 fzero = {0.f, 0.f, 0.f, 0.f};

    const u16* qpa = Q + qkbase + (size_t)(qta*64 + wave*16 + lr)*HD + quad*8;
    const u16* qpb = Q + qkbase + (size_t)(qtb*64 + wave*16 + lr)*HD + quad*8;
    bf16x8 qa0 = *(const bf16x8*)qpa, qa1 = *(const bf16x8*)(qpa + 32);
    bf16x8 qb0 = *(const bf16x8*)qpb, qb1 = *(const bf16x8*)(qpb + 32);

    f32x4 oa[4], ob[4];
    float la[4], lb[4];
    #pragma unroll
    for (int dt = 0; dt < 4; ++dt) { oa[dt] = fzero; ob[dt] = fzero; }
    #pragma unroll
    for (int r = 0; r < 4; ++r) { la[r] = 0.f; lb[r] = 0.f; }

    const u16* gK = Kg + qkbase + (size_t)(wave*16 + (lane>>2))*HD + (lane&3)*8;
    const u16* gV = Vt + qkbase + (size_t)(wave*16 + (lane>>2))*S_LEN + (lane&3)*8;
    u16* lK = Ks + wave*512;
    u16* lV = Vs + wave*512;

    const int qrow_qa = qta*64 + wave*16 + quad*4;
    const int qrow_qb = qtb*64 + wave*16 + quad*4;

    for (int kb = 0; kb <= qtb; ++kb) {
        __syncthreads();
        load_lds16(gK + (size_t)kb*4096,      lK);
        load_lds16(gK + (size_t)kb*4096 + 32, lK + 2048);
        load_lds16(gV + kb*64,                lV);
        load_lds16(gV + kb*64 + 32,           lV + 2048);
        __syncthreads();

        #pragma unroll
        for (int tile = 0; tile < 2; ++tile) {
            const int qt = tile ? qta : qtb;
            if (tile && kb > qta) break;
            bf16x8 qf0 = tile ? qa0 : qb0;
            bf16x8 qf1 = tile ? qa1 : qb1;
            f32x4* oacc = tile ? oa : ob;
            float* lp   = tile ? la : lb;
            const int qrowq = tile ? qrow_qa : qrow_qb;

            f32x4 sc[4];
            #pragma unroll
            for (int kt2 = 0; kt2 < 4; ++kt2) {
                bf16x8 kf0 = *(const bf16x8*)&Ks[(kt2*16 + lr)*32 + quad*8];
                bf16x8 kf1 = *(const bf16x8*)&Ks[2048 + (kt2*16 + lr)*32 + quad*8];
                sc[kt2] = __builtin_amdgcn_mfma_f32_16x16x32_bf16(qf0, kf0, fzero, 0, 0, 0);
                sc[kt2] = __builtin_amdgcn_mfma_f32_16x16x32_bf16(qf1, kf1, sc[kt2], 0, 0, 0);
            }
            const bool diag = (kb == qt);
            #pragma unroll
            for (int r = 0; r < 4; ++r) {
                #pragma unroll
                for (int kt2 = 0; kt2 < 4; ++kt2) {
                    int kcol = kb*64 + kt2*16 + lr;
                    float p = (!diag || kcol <= qrowq + r) ? __expf(fminf(sc[kt2][r]*0.125f, 30.f)) : 0.f;
                    lp[r] += p;
                    Pw[(quad*4 + r)*72 + kt2*16 + lr] = f2b(p);
                }
            }
            bf16x8 pf0 = *(const bf16x8*)&Pw[lr*72 + quad*8];
            bf16x8 pf1 = *(const bf16x8*)&Pw[lr*72 + 32 + quad*8];
            #pragma unroll
            for (int dt = 0; dt < 4; ++dt) {
                bf16x8 vf0 = *(const bf16x8*)&Vs[(dt*16 + lr)*32 + quad*8];
                bf16x8 vf1 = *(const bf16x8*)&Vs[2048 + (dt*16 + lr)*32 + quad*8];
                oacc[dt] = __builtin_amdgcn_mfma_f32_16x16x32_bf16(pf0, vf0, oacc[dt], 0, 0, 0);
                oacc[dt] = __builtin_amdgcn_mfma_f32_16x16x32_bf16(pf1, vf1, oacc[dt], 0, 0, 0);
            }
        }
    }

    #pragma unroll
    for (int tile = 0; tile < 2; ++tile) {
        const int qt = tile ? qta : qtb;
        f32x4* oacc = tile ? oa : ob;
        float* lp   = tile ? la : lb;
        #pragma unroll
        for (int r = 0; r < 4; ++r) {
            float v = lp[r];
            v += __shfl_xor(v, 1, 64); v += __shfl_xor(v, 2, 64);
            v += __shfl_xor(v, 4, 64); v += __shfl_xor(v, 8, 64);
            lp[r] = 1.0f / fmaxf(v, 1e-20f);
        }
        #pragma unroll
        for (int dt = 0; dt < 4; ++dt)
            #pragma unroll
            for (int r = 0; r < 4; ++r)
                Pw[(quad*4 + r)*64 + dt*16 + lr] = f2b(oacc[dt][r] * lp[r]);

        const int q = lane >> 2, d0 = (lane & 3)*16;
        u16* dst = O + ((size_t)(b*S_LEN + qt*64 + wave*16 + q))*EMB + h*HD + d0;
        *(uint4*)(dst)     = *(uint4*)&Pw[q*64 + d0];
        *(uint4*)(dst + 8) = *(uint4*)&Pw[q*64 + d0 + 8];
    }
}

// ---------------------------------------------------------------- launch
extern "C" void kernel_launch(void* const* d_in, const int* in_sizes, int n_in,
                              void* d_out, int out_size, void* d_ws, size_t ws_size,
                              hipStream_t stream)
{
    (void)in_sizes; (void)n_in; (void)out_size; (void)ws_size;
    const float* x    = (const float*)d_in[0];
    // d_in[1] = mask: causal tril, handled analytically
    const float* ln1g = (const float*)d_in[2];
    const float* ln1b = (const float*)d_in[3];
    const float* wq = (const float*)d_in[4];  const float* bq = (const float*)d_in[5];
    const float* wk = (const float*)d_in[6];  const float* bk = (const float*)d_in[7];
    const float* wv = (const float*)d_in[8];  const float* bv = (const float*)d_in[9];
    const float* wo = (const float*)d_in[10]; const float* bo = (const float*)d_in[11];
    const float* ln2g = (const float*)d_in[12]; const float* ln2b = (const float*)d_in[13];
    const float* w1 = (const float*)d_in[14]; const float* b1 = (const float*)d_in[15];
    const float* w2 = (const float*)d_in[16]; const float* b2 = (const float*)d_in[17];

    u16* ws = (u16*)d_ws;
    const size_t M1 = 1u << 20;             // 1M u16 elements (2 MB)
    u16* wqkvT = ws + 0*M1;                 // bf16 [3072][1024] = wqT|wkT|wvT contiguous
    u16* wqT = ws + 0*M1;
    u16* wkT = ws + 1*M1;
    u16* wvT = ws + 2*M1;
    u16* woT = ws + 3*M1;
    u16* w2T = ws + 0*M1;                   // bf16 [1024][4096], transposed AFTER wo-gemm
    u16* w1T = ws + 4*M1;                   // bf16 [4096][1024]
    u16* h0  = ws + 8*M1;                   // bf16 ln out (reused for ln2 out)
    u16* qb  = ws + 12*M1;                  // bf16 [B,H,S,D]
    u16* kb  = ws + 16*M1;                  // bf16 [B,H,S,D]
    u16* vT  = ws + 20*M1;                  // bf16 [B,H,D,S]
    u16* ao  = ws + 24*M1;                  // bf16 attn out [B,S,E]
    u16* vb  = ws + 24*M1;                  // bf16 V [B,H,S,D] (dead before attn writes ao)
    u16* x1  = ws + 28*M1;                  // bf16 residual-1 out
    u16* fb  = ws + 12*M1;                  // bf16 MLP hidden, overlays q/k/v/ao (dead)

    dim3 blk(256);
    transpose_k<<<dim3(16,16), blk, 0, stream>>>(wq, wqT, EMB, EMB);
    transpose_k<<<dim3(16,16), blk, 0, stream>>>(wk, wkT, EMB, EMB);
    transpose_k<<<dim3(16,16), blk, 0, stream>>>(wv, wvT, EMB, EMB);
    transpose_k<<<dim3(16,16), blk, 0, stream>>>(wo, woT, EMB, EMB);
    transpose_k<<<dim3(64,16), blk, 0, stream>>>(w1, w1T, EMB, FF_DIM);

    ln_kernel<1><<<NROWS, blk, 0, stream>>>(x, ln1g, ln1b, h0);

    // fused QKV: 256^2 8-phase kernel, grid = (3072/256, 4096/256)
    gemm256<5><<<dim3(12,16), dim3(512), 0, stream>>>(h0, wqkvT, bq, bk, bv,
                                                      qb, kb, vb, NROWS, 3072, EMB);

    vtrans<<<dim3(32,32), blk, 0, stream>>>(vb, vT);

    attn_kernel<<<dim3(32,16), blk, 0, stream>>>(qb, kb, vT, ao);

    gemm_bt<1,1,0,64><<<dim3(64,8), blk, 0, stream>>>(ao, woT, bo, nullptr, nullptr, x,
                                                      x1, nullptr, nullptr, NROWS, EMB, EMB);

    transpose_k<<<dim3(16,64), blk, 0, stream>>>(w2, w2T, FF_DIM, EMB);

    ln_kernel<0><<<NROWS, blk, 0, stream>>>(x1, ln2g, ln2b, h0);

    // FF1 (gelu): 256^2 8-phase kernel, grid = (4096/256, 4096/256)
    gemm256<2><<<dim3(16,16), dim3(512), 0, stream>>>(h0, w1T, b1, nullptr, nullptr,
                                                      fb, nullptr, nullptr, NROWS, FF_DIM, EMB);

    gemm_bt<1,0,1,64><<<dim3(64,8), blk, 0, stream>>>(fb, w2T, b2, nullptr, nullptr, x1,
                                                      d_out, nullptr, nullptr, NROWS, EMB, FF_DIM);
}

// Round 4
// 373.334 us; speedup vs baseline: 1.1244x; 1.0034x over previous
//
#include <hip/hip_runtime.h>

typedef unsigned short u16;
typedef unsigned int   u32;
typedef __attribute__((ext_vector_type(8))) short bf16x8;   // 8 bf16 in 4 VGPRs
typedef __attribute__((ext_vector_type(4))) float f32x4;

#define S_LEN 2048
#define EMB   1024
#define NH    16
#define HD    64
#define FF_DIM 4096
#define NROWS 4096   // B*S

__device__ __forceinline__ float b2f(u16 u){ union{u32 i; float f;} c; c.i = ((u32)u)<<16; return c.f; }
// round-half-up bf16 pack: 2 VALU ops (vs 5 for RNE); differs from RNE only on exact ties
__device__ __forceinline__ u16 f2b(float f){ union{float f; u32 u;} c; c.f=f; return (u16)((c.u + 0x8000u)>>16); }
// fast erf-based gelu: A&S 7.1.26 poly, |eps_erf| ~1.5e-7 (invisible after bf16 round)
__device__ __forceinline__ float gelu_f(float x){
    float z  = x * 0.70710678118f;
    float az = fabsf(z);
    float t  = 1.0f / (1.0f + 0.3275911f * az);
    float p  = ((((1.061405429f*t - 1.453152027f)*t + 1.421413741f)*t - 0.284496736f)*t + 0.254829592f)*t;
    float e  = __expf(-az*az);
    float erfv = 1.0f - p*e;
    erfv = (z < 0.f) ? -erfv : erfv;
    return 0.5f*x*(1.0f + erfv);
}

// async global->LDS, 16B per lane; lds dest = wave-uniform base + lane*16 (m97/m104)
__device__ __forceinline__ void load_lds16(const u16* g, u16* l) {
    __builtin_amdgcn_global_load_lds((const __attribute__((address_space(1))) u32*)g,
                                     (__attribute__((address_space(3))) u32*)l, 16, 0, 0);
}

// ---------------------------------------------------------------- LayerNorm
template<int XF32>
__global__ __launch_bounds__(256)
void ln_kernel(const void* __restrict__ Xv, const float* __restrict__ G,
               const float* __restrict__ Bv, u16* __restrict__ Y)
{
    const int row = blockIdx.x, t = threadIdx.x;
    float v0, v1, v2, v3;
    if constexpr (XF32) {
        float4 r4 = ((const float4*)((const float*)Xv + (size_t)row*EMB))[t];
        v0 = r4.x; v1 = r4.y; v2 = r4.z; v3 = r4.w;
    } else {
        const u16* xr = (const u16*)Xv + (size_t)row*EMB;
        uint2 raw = *(const uint2*)(xr + t*4);
        v0 = b2f(raw.x & 0xffff); v1 = b2f(raw.x >> 16);
        v2 = b2f(raw.y & 0xffff); v3 = b2f(raw.y >> 16);
    }
    float s  = v0+v1+v2+v3;
    float s2 = v0*v0+v1*v1+v2*v2+v3*v3;
    #pragma unroll
    for (int off = 1; off < 64; off <<= 1) {
        s  += __shfl_xor(s,  off, 64);
        s2 += __shfl_xor(s2, off, 64);
    }
    __shared__ float ps[4], ps2[4];
    const int w = t >> 6, lane = t & 63;
    if (lane == 0) { ps[w] = s; ps2[w] = s2; }
    __syncthreads();
    s  = ps[0]+ps[1]+ps[2]+ps[3];
    s2 = ps2[0]+ps2[1]+ps2[2]+ps2[3];
    const float mu   = s * (1.0f/EMB);
    const float rstd = rsqrtf(fmaxf(s2*(1.0f/EMB) - mu*mu, 0.f) + 1e-5f);
    float4 g4 = ((const float4*)G)[t];
    float4 c4 = ((const float4*)Bv)[t];
    u32 lo = (u32)f2b((v0-mu)*rstd*g4.x + c4.x) | ((u32)f2b((v1-mu)*rstd*g4.y + c4.y) << 16);
    u32 hi = (u32)f2b((v2-mu)*rstd*g4.z + c4.z) | ((u32)f2b((v3-mu)*rstd*g4.w + c4.w) << 16);
    uint2 o; o.x = lo; o.y = hi;
    *(uint2*)(Y + (size_t)row*EMB + t*4) = o;
}

// ---------------------------------------------------------------- transpose+downconvert (f32 [K][N] -> bf16 [N][K])
__global__ __launch_bounds__(256)
void transpose_k(const float* __restrict__ in, u16* __restrict__ out, int K, int N)
{
    __shared__ __align__(16) u16 T[64*72];
    const int k0 = blockIdx.y*64, n0 = blockIdx.x*64, t = threadIdx.x;
    #pragma unroll
    for (int c = 0; c < 4; ++c) {
        int e = t*4 + c*1024, ki = e >> 6, nj = e & 63;
        float4 f = *(const float4*)(in + (size_t)(k0+ki)*N + n0 + nj);
        ushort4 s4; s4.x = f2b(f.x); s4.y = f2b(f.y); s4.z = f2b(f.z); s4.w = f2b(f.w);
        *(ushort4*)&T[ki*72 + nj] = s4;
    }
    __syncthreads();
    #pragma unroll
    for (int c = 0; c < 2; ++c) {
        int e = t*8 + c*2048, ni = e >> 6, kj = e & 63;
        uint4 v; u16* pv = (u16*)&v;
        #pragma unroll
        for (int j = 0; j < 8; ++j) pv[j] = T[(kj+j)*72 + ni];
        *(uint4*)(out + (size_t)(n0+ni)*K + k0 + kj) = v;
    }
}

// ---------------------------------------------------------------- bf16 transpose: V [B*H][S][64] -> V^T [B*H][64][S]
__global__ __launch_bounds__(256)
void vtrans(const u16* __restrict__ in, u16* __restrict__ out)
{
    __shared__ __align__(16) u16 T[64*72];
    const int bh = blockIdx.y, s0 = blockIdx.x*64, t = threadIdx.x;
    const size_t base = (size_t)bh * (S_LEN*HD);
    #pragma unroll
    for (int c = 0; c < 2; ++c) {
        int e = t*8 + c*2048, r = e >> 6, d = e & 63;
        *(uint4*)&T[r*72 + d] = *(const uint4*)(in + base + (size_t)(s0 + r)*HD + d);
    }
    __syncthreads();
    #pragma unroll
    for (int c = 0; c < 2; ++c) {
        int e = t*8 + c*2048, d = e >> 6, sj = e & 63;
        uint4 v; u16* pv = (u16*)&v;
        #pragma unroll
        for (int j = 0; j < 8; ++j) pv[j] = T[(sj + j)*72 + d];
        *(uint4*)(out + base + (size_t)d*S_LEN + s0 + sj) = v;
    }
}

// ================================================================ 256x256 8-phase GEMM
// T2+T3+T4+T5 (m194-m201 template, plain HIP): 512 thr = 8 waves (2M x 4N), BK=64,
// LDS 128 KiB = 2 buf x {A,B} x 2 k-halves x [256 rows][32 k] bf16.
// Bank swizzle (T2): involution on u16 offset  off ^= (off>>3)&0x18  (chunk bits 0..1 ^= chunk
//   bits 3..4, self-inverse) -> applied on BOTH sides (rule 21): pre-swizzled per-lane GLOBAL
//   source for global_load_lds (linear LDS dest, m173) and on the ds_read byte offset.
// Schedule (T3+T4): 8 phases / 2 K-tiles per iter; per phase {10 ds_read_b128, 2 global_load_lds,
//   s_barrier, setprio(1), 16 MFMA, setprio(0), [vmcnt(8) on even phases], s_barrier}.
//   vmcnt(8) retires exactly the half-tile pair read one phase later (slot trace r2/r3).
__device__ __forceinline__ void stage2(const u16* s0, const u16* s1, int koff, u16* dst, int wave){
    load_lds16(s0 + koff, dst + wave*512);
    load_lds16(s1 + koff, dst + 4096 + wave*512);
}

template<int CBUF, int KS, int NHH, int TAILVM>
__device__ __forceinline__ void phase256(u16* Ls, f32x4 (&acc)[8][4],
    int wm, int wn, int lr, int quad, int wave,
    const u16* s0, const u16* s1, int koff, u16* dst)
{
    const u16* ak = Ls + CBUF*32768 + KS*8192;
    const u16* bk = Ls + CBUF*32768 + 16384 + KS*8192;
    bf16x8 af[8], bf[2];
    #pragma unroll
    for (int mf = 0; mf < 8; ++mf) {
        int off = (wm*128 + mf*16 + lr)*32 + quad*8;
        af[mf] = *(const bf16x8*)(ak + (off ^ ((off>>3)&0x18)));
    }
    #pragma unroll
    for (int nf = 0; nf < 2; ++nf) {
        int off = (wn*64 + NHH*32 + nf*16 + lr)*32 + quad*8;
        bf[nf] = *(const bf16x8*)(bk + (off ^ ((off>>3)&0x18)));
    }
    stage2(s0, s1, koff, dst, wave);
    __builtin_amdgcn_s_barrier();
    __builtin_amdgcn_s_setprio(1);
    #pragma unroll
    for (int mf = 0; mf < 8; ++mf) {
        acc[mf][NHH*2+0] = __builtin_amdgcn_mfma_f32_16x16x32_bf16(af[mf], bf[0], acc[mf][NHH*2+0], 0, 0, 0);
        acc[mf][NHH*2+1] = __builtin_amdgcn_mfma_f32_16x16x32_bf16(af[mf], bf[1], acc[mf][NHH*2+1], 0, 0, 0);
    }
    __builtin_amdgcn_s_setprio(0);
    if constexpr (TAILVM) asm volatile("s_waitcnt vmcnt(8)" ::: "memory");
    __builtin_amdgcn_s_barrier();
}

// shared main loop: runs the 8-phase pipeline over NT K-tiles starting at srcA/B (already K-offset)
__device__ __forceinline__ void gemm256_main(u16* Ls, f32x4 (&acc)[8][4],
    int wm, int wn, int lr, int quad, int wave, int NT,
    const u16* srcA0, const u16* srcA1, const u16* srcB0, const u16* srcB1)
{
    u16* A00 = Ls + 0;
    u16* A01 = Ls + 8192;
    u16* B00 = Ls + 16384;
    u16* B01 = Ls + 16384 + 8192;
    u16* A10 = Ls + 32768;
    u16* A11 = Ls + 32768 + 8192;
    u16* B10 = Ls + 32768 + 16384;
    u16* B11 = Ls + 32768 + 16384 + 8192;

    // prologue: tile0 {Akh0,Bkh0,Akh1,Bkh1}, tile1 {Akh0,Bkh0}
    stage2(srcA0, srcA1, 0,   A00, wave);
    stage2(srcB0, srcB1, 0,   B00, wave);
    stage2(srcA0, srcA1, 32,  A01, wave);
    stage2(srcB0, srcB1, 32,  B01, wave);
    stage2(srcA0, srcA1, 64,  A10, wave);
    stage2(srcB0, srcB1, 64,  B10, wave);
    asm volatile("s_waitcnt vmcnt(8)" ::: "memory");   // tile0 kh0 (A,B) landed, all waves
    __builtin_amdgcn_s_barrier();

    for (int U = 0; U < NT; U += 2) {
        const int k1 = ((U+1) & (NT-1))*64;
        const int k2 = ((U+2) & (NT-1))*64;   // wraps at tail: redundant-but-safe reload
        const int k3 = ((U+3) & (NT-1))*64;
        phase256<0,0,0,0>(Ls, acc, wm, wn, lr, quad, wave, srcA0, srcA1, k1+32, A11);
        phase256<0,0,1,1>(Ls, acc, wm, wn, lr, quad, wave, srcB0, srcB1, k1+32, B11);
        phase256<0,1,0,0>(Ls, acc, wm, wn, lr, quad, wave, srcA0, srcA1, k2,    A00);
        phase256<0,1,1,1>(Ls, acc, wm, wn, lr, quad, wave, srcB0, srcB1, k2,    B00);
        phase256<1,0,0,0>(Ls, acc, wm, wn, lr, quad, wave, srcA0, srcA1, k2+32, A01);
        phase256<1,0,1,1>(Ls, acc, wm, wn, lr, quad, wave, srcB0, srcB1, k2+32, B01);
        phase256<1,1,0,0>(Ls, acc, wm, wn, lr, quad, wave, srcA0, srcA1, k3,    A10);
        phase256<1,1,1,1>(Ls, acc, wm, wn, lr, quad, wave, srcB0, srcB1, k3,    B10);
    }

    // drain ALL DMAs (incl. wrapped tail stages) before repurposing LDS
    asm volatile("s_waitcnt vmcnt(0)" ::: "memory");
    __syncthreads();
}

// MODE 2: gelu -> bf16 C.   MODE 5: fused QKV head-split scatter (C=Q, C2=K, C3=V).
template<int MODE>
__global__ __launch_bounds__(512, 2)
void gemm256(const u16* __restrict__ A, const u16* __restrict__ Bt,
             const float* __restrict__ bias, const float* __restrict__ bias2,
             const float* __restrict__ bias3,
             void* __restrict__ C, void* __restrict__ C2, void* __restrict__ C3,
             int M, int N, int K)
{
    (void)M;
    __shared__ __align__(16) u16 Ls[65536];     // 128 KiB
    const int t = threadIdx.x;
    const int wave = t >> 6, lane = t & 63;
    const int wm = wave >> 2, wn = wave & 3;    // 2 x 4 wave grid
    const int lr = lane & 15, quad = lane >> 4;
    const int n0 = blockIdx.x*256, m0 = blockIdx.y*256;

    // per-lane pre-swizzled global sources: phys chunk c (16B) <- logical chunk c^((c>>3)&3)
    const int c0 = wave*64 + lane, c1 = 512 + wave*64 + lane;
    const int l0 = c0 ^ ((c0 >> 3) & 3), l1 = c1 ^ ((c1 >> 3) & 3);
    const int r0 = l0 >> 2, g0 = l0 & 3;
    const int r1 = l1 >> 2, g1 = l1 & 3;
    const u16* srcA0 = A  + (size_t)(m0 + r0)*K + g0*8;
    const u16* srcA1 = A  + (size_t)(m0 + r1)*K + g1*8;
    const u16* srcB0 = Bt + (size_t)(n0 + r0)*K + g0*8;
    const u16* srcB1 = Bt + (size_t)(n0 + r1)*K + g1*8;

    f32x4 acc[8][4];
    const f32x4 fzero = {0.f, 0.f, 0.f, 0.f};
    #pragma unroll
    for (int i = 0; i < 8; ++i)
        #pragma unroll
        for (int j = 0; j < 4; ++j) acc[i][j] = fzero;

    gemm256_main(Ls, acc, wm, wn, lr, quad, wave, K >> 6, srcA0, srcA1, srcB0, srcB1);

    // ---------------- epilogue: bias(+gelu), stage [256][256] bf16 in LDS, coalesced stores
    float bv[4];
    #pragma unroll
    for (int nf = 0; nf < 4; ++nf) {
        const int col = n0 + wn*64 + nf*16 + lr;
        if constexpr (MODE == 5) {
            const int seg = n0 >> 10;    // 256 | 1024: no straddle
            bv[nf] = (seg == 0 ? bias : (seg == 1 ? bias2 : bias3))[col & 1023];
        } else {
            bv[nf] = bias[col];
        }
    }
    #pragma unroll
    for (int mf = 0; mf < 8; ++mf)
        #pragma unroll
        for (int nf = 0; nf < 4; ++nf)
            #pragma unroll
            for (int r = 0; r < 4; ++r) {
                float v = acc[mf][nf][r] + bv[nf];
                if constexpr (MODE == 2) v = gelu_f(v);
                Ls[(wm*128 + mf*16 + quad*4 + r)*256 + wn*64 + nf*16 + lr] = f2b(v);
            }
    __syncthreads();
    // 256x256 u16 = 8192 16B-chunks; 512 threads x 16 iters
    #pragma unroll
    for (int j = 0; j < 16; ++j) {
        const int idx = j*512 + t;
        const int rr = idx >> 5, ck = idx & 31;
        const u16* src = Ls + rr*256 + ck*8;
        const int row = m0 + rr, col = n0 + ck*8;
        if constexpr (MODE == 5) {
            const int seg = n0 >> 10;
            u16* dstb = (u16*)(seg == 0 ? C : (seg == 1 ? C2 : C3));
            const int cs = col & 1023;
            const int h = cs >> 6, d = cs & 63;
            const int b_ = row >> 11, s = row & 2047;
            *(uint4*)(dstb + ((((size_t)(b_*NH + h))*S_LEN + s) << 6) + d) = *(const uint4*)src;
        } else {
            *(uint4*)((u16*)C + (size_t)row*N + col) = *(const uint4*)src;
        }
    }
}

// ================================================================ split-K=4 variant
// grid (N/256, M/256, 4): z = K-split. Writes RAW bf16 partial (no bias) to slab
// (z<2 ? Cl : Ch) + (z&1)*M*N. Fills all 256 CUs for narrow-N deep-K GEMMs (wo, FF2).
__global__ __launch_bounds__(512, 2)
void gemm256sk(const u16* __restrict__ A, const u16* __restrict__ Bt,
               u16* __restrict__ Cl, u16* __restrict__ Ch, int N, int K)
{
    __shared__ __align__(16) u16 Ls[65536];
    const int t = threadIdx.x;
    const int wave = t >> 6, lane = t & 63;
    const int wm = wave >> 2, wn = wave & 3;
    const int lr = lane & 15, quad = lane >> 4;
    const int n0 = blockIdx.x*256, m0 = blockIdx.y*256;
    const int z  = blockIdx.z;
    const int Ks = K >> 2;                       // K-slice per split

    const int c0 = wave*64 + lane, c1 = 512 + wave*64 + lane;
    const int l0 = c0 ^ ((c0 >> 3) & 3), l1 = c1 ^ ((c1 >> 3) & 3);
    const int r0 = l0 >> 2, g0 = l0 & 3;
    const int r1 = l1 >> 2, g1 = l1 & 3;
    const u16* srcA0 = A  + (size_t)(m0 + r0)*K + g0*8 + z*Ks;
    const u16* srcA1 = A  + (size_t)(m0 + r1)*K + g1*8 + z*Ks;
    const u16* srcB0 = Bt + (size_t)(n0 + r0)*K + g0*8 + z*Ks;
    const u16* srcB1 = Bt + (size_t)(n0 + r1)*K + g1*8 + z*Ks;

    f32x4 acc[8][4];
    const f32x4 fzero = {0.f, 0.f, 0.f, 0.f};
    #pragma unroll
    for (int i = 0; i < 8; ++i)
        #pragma unroll
        for (int j = 0; j < 4; ++j) acc[i][j] = fzero;

    gemm256_main(Ls, acc, wm, wn, lr, quad, wave, Ks >> 6, srcA0, srcA1, srcB0, srcB1);

    // epilogue: raw bf16 partial, linear [M][N]
    #pragma unroll
    for (int mf = 0; mf < 8; ++mf)
        #pragma unroll
        for (int nf = 0; nf < 4; ++nf)
            #pragma unroll
            for (int r = 0; r < 4; ++r)
                Ls[(wm*128 + mf*16 + quad*4 + r)*256 + wn*64 + nf*16 + lr] = f2b(acc[mf][nf][r]);
    __syncthreads();
    u16* dst = (z < 2 ? Cl : Ch) + (size_t)(z & 1)*(1u<<22);   // slab stride M*N = 2^22
    #pragma unroll
    for (int j = 0; j < 16; ++j) {
        const int idx = j*512 + t;
        const int rr = idx >> 5, ck = idx & 31;
        *(uint4*)(dst + (size_t)(m0 + rr)*N + n0 + ck*8) = *(const uint4*)(Ls + rr*256 + ck*8);
    }
}

// ---------------------------------------------------------------- split-K reduces (elementwise, 8/thread)
// wo: y_bf16 = p0+p1+p2+p3 + bias[col] + xres_f32   (4 contiguous-by-pair slabs)
__global__ __launch_bounds__(256)
void reduce_wo(const u16* __restrict__ pl, const u16* __restrict__ ph,
               const float* __restrict__ xres, const float* __restrict__ bias,
               u16* __restrict__ y)
{
    const int i0 = (blockIdx.x*256 + threadIdx.x)*8;
    uint4 a0 = *(const uint4*)(pl + i0);
    uint4 a1 = *(const uint4*)(pl + (1u<<22) + i0);
    uint4 a2 = *(const uint4*)(ph + i0);
    uint4 a3 = *(const uint4*)(ph + (1u<<22) + i0);
    const int col = i0 & 1023;
    float4 b0 = *(const float4*)(bias + col);
    float4 b1 = *(const float4*)(bias + col + 4);
    float4 x0 = *(const float4*)(xres + i0);
    float4 x1 = *(const float4*)(xres + i0 + 4);
    const u16 *s0=(const u16*)&a0, *s1=(const u16*)&a1, *s2=(const u16*)&a2, *s3=(const u16*)&a3;
    const float bb[8] = {b0.x,b0.y,b0.z,b0.w,b1.x,b1.y,b1.z,b1.w};
    const float xx[8] = {x0.x,x0.y,x0.z,x0.w,x1.x,x1.y,x1.z,x1.w};
    u16 out[8];
    #pragma unroll
    for (int j = 0; j < 8; ++j)
        out[j] = f2b(b2f(s0[j]) + b2f(s1[j]) + b2f(s2[j]) + b2f(s3[j]) + bb[j] + xx[j]);
    *(uint4*)(y + i0) = *(const uint4*)out;
}

// ff2 stage 1: s_bf16 = p0+p1+p2+p3, written in-place over p0 (same-element RMW, race-free)
__global__ __launch_bounds__(256)
void reduce_sum4(u16* __restrict__ pl, const u16* __restrict__ ph)
{
    const int i0 = (blockIdx.x*256 + threadIdx.x)*8;
    uint4 a0 = *(const uint4*)(pl + i0);
    uint4 a1 = *(const uint4*)(pl + (1u<<22) + i0);
    uint4 a2 = *(const uint4*)(ph + i0);
    uint4 a3 = *(const uint4*)(ph + (1u<<22) + i0);
    const u16 *s0=(const u16*)&a0, *s1=(const u16*)&a1, *s2=(const u16*)&a2, *s3=(const u16*)&a3;
    u16 out[8];
    #pragma unroll
    for (int j = 0; j < 8; ++j)
        out[j] = f2b(b2f(s0[j]) + b2f(s1[j]) + b2f(s2[j]) + b2f(s3[j]));
    *(uint4*)(pl + i0) = *(const uint4*)out;
}

// ff2 stage 2: out_f32 = s + bias[col] + x1_bf16   (reads ws only, writes d_out fresh)
__global__ __launch_bounds__(256)
void final_ff2(const u16* __restrict__ s, const u16* __restrict__ x1b,
               const float* __restrict__ bias, float* __restrict__ out)
{
    const int i0 = (blockIdx.x*256 + threadIdx.x)*8;
    uint4 a = *(const uint4*)(s + i0);
    uint4 xr = *(const uint4*)(x1b + i0);
    const int col = i0 & 1023;
    float4 b0 = *(const float4*)(bias + col);
    float4 b1 = *(const float4*)(bias + col + 4);
    const u16 *sp=(const u16*)&a, *xp=(const u16*)&xr;
    const float bb[8] = {b0.x,b0.y,b0.z,b0.w,b1.x,b1.y,b1.z,b1.w};
    float f[8];
    #pragma unroll
    for (int j = 0; j < 8; ++j) f[j] = b2f(sp[j]) + b2f(xp[j]) + bb[j];
    float4 o0 = {f[0],f[1],f[2],f[3]}, o1 = {f[4],f[5],f[6],f[7]};
    *(float4*)(out + i0) = o0;
    *(float4*)(out + i0 + 4) = o1;
}

// ---------------------------------------------------------------- attention (causal, round-0 form)
// Grid (bh fastest): XCD-local KV. Block handles pair {pr, 31-pr}; ONE merged K-loop
// stages each K/V tile once via global_load_lds (shared by 4 waves) and feeds up to
// two Q-tiles. LDS layout [k-half][row][32] keeps the m97 64-B-stride fragment reads.
// Q,K: [B*H][S][64]; Vt: [B*H][64][S]; O: [B][S][1024]
__global__ __launch_bounds__(256, 2)
void attn_kernel(const u16* __restrict__ Q, const u16* __restrict__ Kg,
                 const u16* __restrict__ Vt, u16* __restrict__ O)
{
    const int bh = blockIdx.x;            // fastest -> XCD = bh % 8
    const int pr = blockIdx.y;            // 0..15
    const int qta = pr, qtb = 31 - pr;
    const int t = threadIdx.x, wave = t >> 6, lane = t & 63;
    const int lr = lane & 15, quad = lane >> 4;

    __shared__ __align__(16) u16 Ks[4096];        // [2][64][32]
    __shared__ __align__(16) u16 Vs[4096];        // [2][64][32]
    __shared__ __align__(16) u16 Ps[4][16*72];    // wave-private P round-trip

    const size_t qkbase = (size_t)bh * (S_LEN*HD);
    const int b = bh >> 4, h = bh & 15;
    u16* Pw = Ps[wave];
    const f32x4 fzero = {0.f, 0.f, 0.f, 0.f};

    const u16* qpa = Q + qkbase + (size_t)(qta*64 + wave*16 + lr)*HD + quad*8;
    const u16* qpb = Q + qkbase + (size_t)(qtb*64 + wave*16 + lr)*HD + quad*8;
    bf16x8 qa0 = *(const bf16x8*)qpa, qa1 = *(const bf16x8*)(qpa + 32);
    bf16x8 qb0 = *(const bf16x8*)qpb, qb1 = *(const bf16x8*)(qpb + 32);

    f32x4 oa[4], ob[4];
    float la[4], lb[4];
    #pragma unroll
    for (int dt = 0; dt < 4; ++dt) { oa[dt] = fzero; ob[dt] = fzero; }
    #pragma unroll
    for (int r = 0; r < 4; ++r) { la[r] = 0.f; lb[r] = 0.f; }

    const u16* gK = Kg + qkbase + (size_t)(wave*16 + (lane>>2))*HD + (lane&3)*8;
    const u16* gV = Vt + qkbase + (size_t)(wave*16 + (lane>>2))*S_LEN + (lane&3)*8;
    u16* lK = Ks + wave*512;
    u16* lV = Vs + wave*512;

    const int qrow_qa = qta*64 + wave*16 + quad*4;
    const int qrow_qb = qtb*64 + wave*16 + quad*4;

    for (int kb = 0; kb <= qtb; ++kb) {
        __syncthreads();
        load_lds16(gK + (size_t)kb*4096,      lK);
        load_lds16(gK + (size_t)kb*4096 + 32, lK + 2048);
        load_lds16(gV + kb*64,                lV);
        load_lds16(gV + kb*64 + 32,           lV + 2048);
        __syncthreads();

        #pragma unroll
        for (int tile = 0; tile < 2; ++tile) {
            const int qt = tile ? qta : qtb;
            if (tile && kb > qta) break;
            bf16x8 qf0 = tile ? qa0 : qb0;
            bf16x8 qf1 = tile ? qa1 : qb1;
            f32x4* oacc = tile ? oa : ob;
            float* lp   = tile ? la : lb;
            const int qrowq = tile ? qrow_qa : qrow_qb;

            f32x4 sc[4];
            #pragma unroll
            for (int kt2 = 0; kt2 < 4; ++kt2) {
                bf16x8 kf0 = *(const bf16x8*)&Ks[(kt2*16 + lr)*32 + quad*8];
                bf16x8 kf1 = *(const bf16x8*)&Ks[2048 + (kt2*16 + lr)*32 + quad*8];
                sc[kt2] = __builtin_amdgcn_mfma_f32_16x16x32_bf16(qf0, kf0, fzero, 0, 0, 0);
                sc[kt2] = __builtin_amdgcn_mfma_f32_16x16x32_bf16(qf1, kf1, sc[kt2], 0, 0, 0);
            }
            const bool diag = (kb == qt);
            #pragma unroll
            for (int r = 0; r < 4; ++r) {
                #pragma unroll
                for (int kt2 = 0; kt2 < 4; ++kt2) {
                    int kcol = kb*64 + kt2*16 + lr;
                    float p = (!diag || kcol <= qrowq + r) ? __expf(fminf(sc[kt2][r]*0.125f, 30.f)) : 0.f;
                    lp[r] += p;
                    Pw[(quad*4 + r)*72 + kt2*16 + lr] = f2b(p);
                }
            }
            bf16x8 pf0 = *(const bf16x8*)&Pw[lr*72 + quad*8];
            bf16x8 pf1 = *(const bf16x8*)&Pw[lr*72 + 32 + quad*8];
            #pragma unroll
            for (int dt = 0; dt < 4; ++dt) {
                bf16x8 vf0 = *(const bf16x8*)&Vs[(dt*16 + lr)*32 + quad*8];
                bf16x8 vf1 = *(const bf16x8*)&Vs[2048 + (dt*16 + lr)*32 + quad*8];
                oacc[dt] = __builtin_amdgcn_mfma_f32_16x16x32_bf16(pf0, vf0, oacc[dt], 0, 0, 0);
                oacc[dt] = __builtin_amdgcn_mfma_f32_16x16x32_bf16(pf1, vf1, oacc[dt], 0, 0, 0);
            }
        }
    }

    #pragma unroll
    for (int tile = 0; tile < 2; ++tile) {
        const int qt = tile ? qta : qtb;
        f32x4* oacc = tile ? oa : ob;
        float* lp   = tile ? la : lb;
        #pragma unroll
        for (int r = 0; r < 4; ++r) {
            float v = lp[r];
            v += __shfl_xor(v, 1, 64); v += __shfl_xor(v, 2, 64);
            v += __shfl_xor(v, 4, 64); v += __shfl_xor(v, 8, 64);
            lp[r] = 1.0f / fmaxf(v, 1e-20f);
        }
        #pragma unroll
        for (int dt = 0; dt < 4; ++dt)
            #pragma unroll
            for (int r = 0; r < 4; ++r)
                Pw[(quad*4 + r)*64 + dt*16 + lr] = f2b(oacc[dt][r] * lp[r]);

        const int q = lane >> 2, d0 = (lane & 3)*16;
        u16* dst = O + ((size_t)(b*S_LEN + qt*64 + wave*16 + q))*EMB + h*HD + d0;
        *(uint4*)(dst)     = *(uint4*)&Pw[q*64 + d0];
        *(uint4*)(dst + 8) = *(uint4*)&Pw[q*64 + d0 + 8];
    }
}

// ---------------------------------------------------------------- launch
extern "C" void kernel_launch(void* const* d_in, const int* in_sizes, int n_in,
                              void* d_out, int out_size, void* d_ws, size_t ws_size,
                              hipStream_t stream)
{
    (void)in_sizes; (void)n_in; (void)out_size; (void)ws_size;
    const float* x    = (const float*)d_in[0];
    // d_in[1] = mask: causal tril, handled analytically
    const float* ln1g = (const float*)d_in[2];
    const float* ln1b = (const float*)d_in[3];
    const float* wq = (const float*)d_in[4];  const float* bq = (const float*)d_in[5];
    const float* wk = (const float*)d_in[6];  const float* bk = (const float*)d_in[7];
    const float* wv = (const float*)d_in[8];  const float* bv = (const float*)d_in[9];
    const float* wo = (const float*)d_in[10]; const float* bo = (const float*)d_in[11];
    const float* ln2g = (const float*)d_in[12]; const float* ln2b = (const float*)d_in[13];
    const float* w1 = (const float*)d_in[14]; const float* b1 = (const float*)d_in[15];
    const float* w2 = (const float*)d_in[16]; const float* b2 = (const float*)d_in[17];

    u16* ws = (u16*)d_ws;
    const size_t M1 = 1u << 20;             // 1M u16 elements (2 MB)
    u16* wqkvT = ws + 0*M1;                 // bf16 [3072][1024] = wqT|wkT|wvT contiguous
    u16* wqT = ws + 0*M1;
    u16* wkT = ws + 1*M1;
    u16* wvT = ws + 2*M1;
    u16* woT = ws + 3*M1;
    u16* w2T = ws + 0*M1;                   // bf16 [1024][4096], transposed AFTER wo-gemm
    u16* w1T = ws + 4*M1;                   // bf16 [4096][1024]
    u16* h0  = ws + 8*M1;                   // bf16 ln out (reused for ln2 out)
    u16* qb  = ws + 12*M1;                  // bf16 [B,H,S,D]
    u16* kb  = ws + 16*M1;                  // bf16 [B,H,S,D]
    u16* vT  = ws + 20*M1;                  // bf16 [B,H,D,S]
    u16* ao  = ws + 24*M1;                  // bf16 attn out [B,S,E]
    u16* vb  = ws + 24*M1;                  // bf16 V [B,H,S,D] (dead before attn writes ao)
    u16* x1  = ws + 28*M1;                  // bf16 residual-1 out
    u16* fb  = ws + 12*M1;                  // bf16 MLP hidden, overlays q/k/v/ao (dead)
    u16* wosl = ws + 8*M1;                  // wo split-K: 4 bf16 slabs over dead h0/qb/kb/vT (8..24M1)
    u16* ffsl = ws + 4*M1;                  // ff2 split-K: slabs 0,1 over dead w1T/h0 (4..12M1)

    dim3 blk(256);
    transpose_k<<<dim3(16,16), blk, 0, stream>>>(wq, wqT, EMB, EMB);
    transpose_k<<<dim3(16,16), blk, 0, stream>>>(wk, wkT, EMB, EMB);
    transpose_k<<<dim3(16,16), blk, 0, stream>>>(wv, wvT, EMB, EMB);
    transpose_k<<<dim3(16,16), blk, 0, stream>>>(wo, woT, EMB, EMB);
    transpose_k<<<dim3(64,16), blk, 0, stream>>>(w1, w1T, EMB, FF_DIM);

    ln_kernel<1><<<NROWS, blk, 0, stream>>>(x, ln1g, ln1b, h0);

    // fused QKV: 256^2 8-phase kernel, grid = (3072/256, 4096/256)
    gemm256<5><<<dim3(12,16), dim3(512), 0, stream>>>(h0, wqkvT, bq, bk, bv,
                                                      qb, kb, vb, NROWS, 3072, EMB);

    vtrans<<<dim3(32,32), blk, 0, stream>>>(vb, vT);

    attn_kernel<<<dim3(32,16), blk, 0, stream>>>(qb, kb, vT, ao);

    // wo projection: split-K=4 gemm256 (256 blocks = 1/CU), partials in dead 8..24M1
    gemm256sk<<<dim3(4,16,4), dim3(512), 0, stream>>>(ao, woT, wosl, wosl + 8*M1, EMB, EMB);
    reduce_wo<<<2048, blk, 0, stream>>>(wosl, wosl + 8*M1, x, bo, x1);

    transpose_k<<<dim3(16,64), blk, 0, stream>>>(w2, w2T, FF_DIM, EMB);

    ln_kernel<0><<<NROWS, blk, 0, stream>>>(x1, ln2g, ln2b, h0);

    // FF1 (gelu): 256^2 8-phase kernel, grid = (4096/256, 4096/256)
    gemm256<2><<<dim3(16,16), dim3(512), 0, stream>>>(h0, w1T, b1, nullptr, nullptr,
                                                      fb, nullptr, nullptr, NROWS, FF_DIM, EMB);

    // FF2: split-K=4; slabs 0,1 in ws (4..12M1, dead w1T/h0), slabs 2,3 in d_out (scratch)
    gemm256sk<<<dim3(4,16,4), dim3(512), 0, stream>>>(fb, w2T, ffsl, (u16*)d_out, EMB, FF_DIM);
    reduce_sum4<<<2048, blk, 0, stream>>>(ffsl, (u16*)d_out);        // s -> over slab0 (in-place safe)
    final_ff2<<<2048, blk, 0, stream>>>(ffsl, x1, b2, (float*)d_out);
}

// Round 5
// 370.188 us; speedup vs baseline: 1.1339x; 1.0085x over previous
//
#include <hip/hip_runtime.h>

typedef unsigned short u16;
typedef unsigned int   u32;
typedef __attribute__((ext_vector_type(8))) short bf16x8;   // 8 bf16 in 4 VGPRs
typedef __attribute__((ext_vector_type(4))) float f32x4;

#define S_LEN 2048
#define EMB   1024
#define NH    16
#define HD    64
#define FF_DIM 4096
#define NROWS 4096   // B*S

__device__ __forceinline__ float b2f(u16 u){ union{u32 i; float f;} c; c.i = ((u32)u)<<16; return c.f; }
// round-half-up bf16 pack: 2 VALU ops (vs 5 for RNE); differs from RNE only on exact ties
__device__ __forceinline__ u16 f2b(float f){ union{float f; u32 u;} c; c.f=f; return (u16)((c.u + 0x8000u)>>16); }
// fast erf-based gelu: A&S 7.1.26 poly, |eps_erf| ~1.5e-7 (invisible after bf16 round)
__device__ __forceinline__ float gelu_f(float x){
    float z  = x * 0.70710678118f;
    float az = fabsf(z);
    float t  = 1.0f / (1.0f + 0.3275911f * az);
    float p  = ((((1.061405429f*t - 1.453152027f)*t + 1.421413741f)*t - 0.284496736f)*t + 0.254829592f)*t;
    float e  = __expf(-az*az);
    float erfv = 1.0f - p*e;
    erfv = (z < 0.f) ? -erfv : erfv;
    return 0.5f*x*(1.0f + erfv);
}

// async global->LDS, 16B per lane; lds dest = wave-uniform base + lane*16 (m97/m104)
__device__ __forceinline__ void load_lds16(const u16* g, u16* l) {
    __builtin_amdgcn_global_load_lds((const __attribute__((address_space(1))) u32*)g,
                                     (__attribute__((address_space(3))) u32*)l, 16, 0, 0);
}

// ---------------------------------------------------------------- LayerNorm
template<int XF32>
__global__ __launch_bounds__(256)
void ln_kernel(const void* __restrict__ Xv, const float* __restrict__ G,
               const float* __restrict__ Bv, u16* __restrict__ Y)
{
    const int row = blockIdx.x, t = threadIdx.x;
    float v0, v1, v2, v3;
    if constexpr (XF32) {
        float4 r4 = ((const float4*)((const float*)Xv + (size_t)row*EMB))[t];
        v0 = r4.x; v1 = r4.y; v2 = r4.z; v3 = r4.w;
    } else {
        const u16* xr = (const u16*)Xv + (size_t)row*EMB;
        uint2 raw = *(const uint2*)(xr + t*4);
        v0 = b2f(raw.x & 0xffff); v1 = b2f(raw.x >> 16);
        v2 = b2f(raw.y & 0xffff); v3 = b2f(raw.y >> 16);
    }
    float s  = v0+v1+v2+v3;
    float s2 = v0*v0+v1*v1+v2*v2+v3*v3;
    #pragma unroll
    for (int off = 1; off < 64; off <<= 1) {
        s  += __shfl_xor(s,  off, 64);
        s2 += __shfl_xor(s2, off, 64);
    }
    __shared__ float ps[4], ps2[4];
    const int w = t >> 6, lane = t & 63;
    if (lane == 0) { ps[w] = s; ps2[w] = s2; }
    __syncthreads();
    s  = ps[0]+ps[1]+ps[2]+ps[3];
    s2 = ps2[0]+ps2[1]+ps2[2]+ps2[3];
    const float mu   = s * (1.0f/EMB);
    const float rstd = rsqrtf(fmaxf(s2*(1.0f/EMB) - mu*mu, 0.f) + 1e-5f);
    float4 g4 = ((const float4*)G)[t];
    float4 c4 = ((const float4*)Bv)[t];
    u32 lo = (u32)f2b((v0-mu)*rstd*g4.x + c4.x) | ((u32)f2b((v1-mu)*rstd*g4.y + c4.y) << 16);
    u32 hi = (u32)f2b((v2-mu)*rstd*g4.z + c4.z) | ((u32)f2b((v3-mu)*rstd*g4.w + c4.w) << 16);
    uint2 o; o.x = lo; o.y = hi;
    *(uint2*)(Y + (size_t)row*EMB + t*4) = o;
}

// ---------------------------------------------------------------- transpose+downconvert (f32 [K][N] -> bf16 [N][K])
__global__ __launch_bounds__(256)
void transpose_k(const float* __restrict__ in, u16* __restrict__ out, int K, int N)
{
    __shared__ __align__(16) u16 T[64*72];
    const int k0 = blockIdx.y*64, n0 = blockIdx.x*64, t = threadIdx.x;
    #pragma unroll
    for (int c = 0; c < 4; ++c) {
        int e = t*4 + c*1024, ki = e >> 6, nj = e & 63;
        float4 f = *(const float4*)(in + (size_t)(k0+ki)*N + n0 + nj);
        ushort4 s4; s4.x = f2b(f.x); s4.y = f2b(f.y); s4.z = f2b(f.z); s4.w = f2b(f.w);
        *(ushort4*)&T[ki*72 + nj] = s4;
    }
    __syncthreads();
    #pragma unroll
    for (int c = 0; c < 2; ++c) {
        int e = t*8 + c*2048, ni = e >> 6, kj = e & 63;
        uint4 v; u16* pv = (u16*)&v;
        #pragma unroll
        for (int j = 0; j < 8; ++j) pv[j] = T[(kj+j)*72 + ni];
        *(uint4*)(out + (size_t)(n0+ni)*K + k0 + kj) = v;
    }
}

// ---------------------------------------------------------------- bf16 transpose: V [B*H][S][64] -> V^T [B*H][64][S]
__global__ __launch_bounds__(256)
void vtrans(const u16* __restrict__ in, u16* __restrict__ out)
{
    __shared__ __align__(16) u16 T[64*72];
    const int bh = blockIdx.y, s0 = blockIdx.x*64, t = threadIdx.x;
    const size_t base = (size_t)bh * (S_LEN*HD);
    #pragma unroll
    for (int c = 0; c < 2; ++c) {
        int e = t*8 + c*2048, r = e >> 6, d = e & 63;
        *(uint4*)&T[r*72 + d] = *(const uint4*)(in + base + (size_t)(s0 + r)*HD + d);
    }
    __syncthreads();
    #pragma unroll
    for (int c = 0; c < 2; ++c) {
        int e = t*8 + c*2048, d = e >> 6, sj = e & 63;
        uint4 v; u16* pv = (u16*)&v;
        #pragma unroll
        for (int j = 0; j < 8; ++j) pv[j] = T[(sj + j)*72 + d];
        *(uint4*)(out + base + (size_t)d*S_LEN + s0 + sj) = v;
    }
}

// ================================================================ 256x256 8-phase GEMM
// T2+T3+T4+T5 (m194-m201 template, plain HIP): 512 thr = 8 waves (2M x 4N), BK=64,
// LDS 128 KiB = 2 buf x {A,B} x 2 k-halves x [256 rows][32 k] bf16.
// Bank swizzle (T2): involution on u16 offset  off ^= (off>>3)&0x18  (self-inverse), applied
//   on BOTH sides (rule 21): pre-swizzled per-lane GLOBAL source for global_load_lds (linear
//   LDS dest, m173) and on the ds_read byte offset.
// Phase quadrants (r4 fix): (k-half x MF-half), NOT (k-half x B-half) -> every fragment is
//   ds_read ONCE per K-tile (24 reads vs 40): per phase 4 A-frag reads + (mfh==0: 4 B-frag
//   reads, held in regs for the mfh==1 phase). Per-CU LDS/phase 375 cyc < MFMA 621 cyc.
// Schedule (T3+T4): per phase {ds_reads, 1 stage2, s_barrier, lgkmcnt(0), setprio(1),
//   16 MFMA, setprio(0), [vmcnt(8) on odd phases], s_barrier}. vmcnt(8) retires exactly the
//   half-tile pair read one phase later (slot trace r2/r3; stage skeleton unchanged).
__device__ __forceinline__ void stage2(const u16* s0, const u16* s1, int koff, u16* dst, int wave){
    load_lds16(s0 + koff, dst + wave*512);
    load_lds16(s1 + koff, dst + 4096 + wave*512);
}

template<int CBUF, int KS, int MFH, int TAILVM>
__device__ __forceinline__ void phase256(u16* Ls, f32x4 (&acc)[8][4], bf16x8 (&bf)[4],
    int wm, int wn, int lr, int quad, int wave,
    const u16* s0, const u16* s1, int koff, u16* dst)
{
    const u16* ak = Ls + CBUF*32768 + KS*8192;
    const u16* bk = Ls + CBUF*32768 + 16384 + KS*8192;
    bf16x8 af[4];
    #pragma unroll
    for (int i = 0; i < 4; ++i) {
        int off = (wm*128 + (MFH*4 + i)*16 + lr)*32 + quad*8;
        af[i] = *(const bf16x8*)(ak + (off ^ ((off>>3)&0x18)));
    }
    if constexpr (MFH == 0) {
        #pragma unroll
        for (int nf = 0; nf < 4; ++nf) {
            int off = (wn*64 + nf*16 + lr)*32 + quad*8;
            bf[nf] = *(const bf16x8*)(bk + (off ^ ((off>>3)&0x18)));
        }
    }
    stage2(s0, s1, koff, dst, wave);
    __builtin_amdgcn_s_barrier();
    asm volatile("s_waitcnt lgkmcnt(0)" ::: "memory");
    __builtin_amdgcn_s_setprio(1);
    #pragma unroll
    for (int i = 0; i < 4; ++i)
        #pragma unroll
        for (int nf = 0; nf < 4; ++nf)
            acc[MFH*4 + i][nf] = __builtin_amdgcn_mfma_f32_16x16x32_bf16(af[i], bf[nf], acc[MFH*4 + i][nf], 0, 0, 0);
    __builtin_amdgcn_s_setprio(0);
    if constexpr (TAILVM) asm volatile("s_waitcnt vmcnt(8)" ::: "memory");
    __builtin_amdgcn_s_barrier();
}

// shared main loop: runs the 8-phase pipeline over NT K-tiles starting at srcA/B (already K-offset)
__device__ __forceinline__ void gemm256_main(u16* Ls, f32x4 (&acc)[8][4],
    int wm, int wn, int lr, int quad, int wave, int NT,
    const u16* srcA0, const u16* srcA1, const u16* srcB0, const u16* srcB1)
{
    u16* A00 = Ls + 0;
    u16* A01 = Ls + 8192;
    u16* B00 = Ls + 16384;
    u16* B01 = Ls + 16384 + 8192;
    u16* A10 = Ls + 32768;
    u16* A11 = Ls + 32768 + 8192;
    u16* B10 = Ls + 32768 + 16384;
    u16* B11 = Ls + 32768 + 16384 + 8192;

    // prologue: tile0 {Akh0,Bkh0,Akh1,Bkh1}, tile1 {Akh0,Bkh0}
    stage2(srcA0, srcA1, 0,   A00, wave);
    stage2(srcB0, srcB1, 0,   B00, wave);
    stage2(srcA0, srcA1, 32,  A01, wave);
    stage2(srcB0, srcB1, 32,  B01, wave);
    stage2(srcA0, srcA1, 64,  A10, wave);
    stage2(srcB0, srcB1, 64,  B10, wave);
    asm volatile("s_waitcnt vmcnt(8)" ::: "memory");   // tile0 kh0 (A,B) landed, all waves
    __builtin_amdgcn_s_barrier();

    bf16x8 bf[4];
    for (int U = 0; U < NT; U += 2) {
        const int k1 = ((U+1) & (NT-1))*64;
        const int k2 = ((U+2) & (NT-1))*64;   // wraps at tail: redundant-but-safe reload
        const int k3 = ((U+3) & (NT-1))*64;
        // compute tile U (buf0); stage skeleton identical to r3 (slots free'd 1+ phases earlier)
        phase256<0,0,0,0>(Ls, acc, bf, wm, wn, lr, quad, wave, srcA0, srcA1, k1+32, A11);
        phase256<0,0,1,1>(Ls, acc, bf, wm, wn, lr, quad, wave, srcB0, srcB1, k1+32, B11);
        phase256<0,1,0,0>(Ls, acc, bf, wm, wn, lr, quad, wave, srcA0, srcA1, k2,    A00);
        phase256<0,1,1,1>(Ls, acc, bf, wm, wn, lr, quad, wave, srcB0, srcB1, k2,    B00);
        // compute tile U+1 (buf1)
        phase256<1,0,0,0>(Ls, acc, bf, wm, wn, lr, quad, wave, srcA0, srcA1, k2+32, A01);
        phase256<1,0,1,1>(Ls, acc, bf, wm, wn, lr, quad, wave, srcB0, srcB1, k2+32, B01);
        phase256<1,1,0,0>(Ls, acc, bf, wm, wn, lr, quad, wave, srcA0, srcA1, k3,    A10);
        phase256<1,1,1,1>(Ls, acc, bf, wm, wn, lr, quad, wave, srcB0, srcB1, k3,    B10);
    }

    // drain ALL DMAs (incl. wrapped tail stages) before repurposing LDS
    asm volatile("s_waitcnt vmcnt(0)" ::: "memory");
    __syncthreads();
}

// MODE 2: gelu -> bf16 C.   MODE 5: fused QKV head-split scatter (C=Q, C2=K, C3=V).
template<int MODE>
__global__ __launch_bounds__(512, 2)
void gemm256(const u16* __restrict__ A, const u16* __restrict__ Bt,
             const float* __restrict__ bias, const float* __restrict__ bias2,
             const float* __restrict__ bias3,
             void* __restrict__ C, void* __restrict__ C2, void* __restrict__ C3,
             int M, int N, int K)
{
    (void)M;
    __shared__ __align__(16) u16 Ls[65536];     // 128 KiB
    const int t = threadIdx.x;
    const int wave = t >> 6, lane = t & 63;
    const int wm = wave >> 2, wn = wave & 3;    // 2 x 4 wave grid
    const int lr = lane & 15, quad = lane >> 4;
    const int n0 = blockIdx.x*256, m0 = blockIdx.y*256;

    // per-lane pre-swizzled global sources: phys chunk c (16B) <- logical chunk c^((c>>3)&3)
    const int c0 = wave*64 + lane, c1 = 512 + wave*64 + lane;
    const int l0 = c0 ^ ((c0 >> 3) & 3), l1 = c1 ^ ((c1 >> 3) & 3);
    const int r0 = l0 >> 2, g0 = l0 & 3;
    const int r1 = l1 >> 2, g1 = l1 & 3;
    const u16* srcA0 = A  + (size_t)(m0 + r0)*K + g0*8;
    const u16* srcA1 = A  + (size_t)(m0 + r1)*K + g1*8;
    const u16* srcB0 = Bt + (size_t)(n0 + r0)*K + g0*8;
    const u16* srcB1 = Bt + (size_t)(n0 + r1)*K + g1*8;

    f32x4 acc[8][4];
    const f32x4 fzero = {0.f, 0.f, 0.f, 0.f};
    #pragma unroll
    for (int i = 0; i < 8; ++i)
        #pragma unroll
        for (int j = 0; j < 4; ++j) acc[i][j] = fzero;

    gemm256_main(Ls, acc, wm, wn, lr, quad, wave, K >> 6, srcA0, srcA1, srcB0, srcB1);

    // ---------------- epilogue: bias(+gelu), stage [256][256] bf16 in LDS, coalesced stores
    float bv[4];
    #pragma unroll
    for (int nf = 0; nf < 4; ++nf) {
        const int col = n0 + wn*64 + nf*16 + lr;
        if constexpr (MODE == 5) {
            const int seg = n0 >> 10;    // 256 | 1024: no straddle
            bv[nf] = (seg == 0 ? bias : (seg == 1 ? bias2 : bias3))[col & 1023];
        } else {
            bv[nf] = bias[col];
        }
    }
    #pragma unroll
    for (int mf = 0; mf < 8; ++mf)
        #pragma unroll
        for (int nf = 0; nf < 4; ++nf)
            #pragma unroll
            for (int r = 0; r < 4; ++r) {
                float v = acc[mf][nf][r] + bv[nf];
                if constexpr (MODE == 2) v = gelu_f(v);
                Ls[(wm*128 + mf*16 + quad*4 + r)*256 + wn*64 + nf*16 + lr] = f2b(v);
            }
    __syncthreads();
    // 256x256 u16 = 8192 16B-chunks; 512 threads x 16 iters
    #pragma unroll
    for (int j = 0; j < 16; ++j) {
        const int idx = j*512 + t;
        const int rr = idx >> 5, ck = idx & 31;
        const u16* src = Ls + rr*256 + ck*8;
        const int row = m0 + rr, col = n0 + ck*8;
        if constexpr (MODE == 5) {
            const int seg = n0 >> 10;
            u16* dstb = (u16*)(seg == 0 ? C : (seg == 1 ? C2 : C3));
            const int cs = col & 1023;
            const int h = cs >> 6, d = cs & 63;
            const int b_ = row >> 11, s = row & 2047;
            *(uint4*)(dstb + ((((size_t)(b_*NH + h))*S_LEN + s) << 6) + d) = *(const uint4*)src;
        } else {
            *(uint4*)((u16*)C + (size_t)row*N + col) = *(const uint4*)src;
        }
    }
}

// ================================================================ split-K=4 variant
// grid (N/256, M/256, 4): z = K-split. Writes RAW bf16 partial (no bias) to slab
// (z<2 ? Cl : Ch) + (z&1)*M*N. Fills all 256 CUs for narrow-N deep-K GEMMs (wo, FF2).
__global__ __launch_bounds__(512, 2)
void gemm256sk(const u16* __restrict__ A, const u16* __restrict__ Bt,
               u16* __restrict__ Cl, u16* __restrict__ Ch, int N, int K)
{
    __shared__ __align__(16) u16 Ls[65536];
    const int t = threadIdx.x;
    const int wave = t >> 6, lane = t & 63;
    const int wm = wave >> 2, wn = wave & 3;
    const int lr = lane & 15, quad = lane >> 4;
    const int n0 = blockIdx.x*256, m0 = blockIdx.y*256;
    const int z  = blockIdx.z;
    const int Ks = K >> 2;                       // K-slice per split

    const int c0 = wave*64 + lane, c1 = 512 + wave*64 + lane;
    const int l0 = c0 ^ ((c0 >> 3) & 3), l1 = c1 ^ ((c1 >> 3) & 3);
    const int r0 = l0 >> 2, g0 = l0 & 3;
    const int r1 = l1 >> 2, g1 = l1 & 3;
    const u16* srcA0 = A  + (size_t)(m0 + r0)*K + g0*8 + z*Ks;
    const u16* srcA1 = A  + (size_t)(m0 + r1)*K + g1*8 + z*Ks;
    const u16* srcB0 = Bt + (size_t)(n0 + r0)*K + g0*8 + z*Ks;
    const u16* srcB1 = Bt + (size_t)(n0 + r1)*K + g1*8 + z*Ks;

    f32x4 acc[8][4];
    const f32x4 fzero = {0.f, 0.f, 0.f, 0.f};
    #pragma unroll
    for (int i = 0; i < 8; ++i)
        #pragma unroll
        for (int j = 0; j < 4; ++j) acc[i][j] = fzero;

    gemm256_main(Ls, acc, wm, wn, lr, quad, wave, Ks >> 6, srcA0, srcA1, srcB0, srcB1);

    // epilogue: raw bf16 partial, linear [M][N]
    #pragma unroll
    for (int mf = 0; mf < 8; ++mf)
        #pragma unroll
        for (int nf = 0; nf < 4; ++nf)
            #pragma unroll
            for (int r = 0; r < 4; ++r)
                Ls[(wm*128 + mf*16 + quad*4 + r)*256 + wn*64 + nf*16 + lr] = f2b(acc[mf][nf][r]);
    __syncthreads();
    u16* dst = (z < 2 ? Cl : Ch) + (size_t)(z & 1)*(1u<<22);   // slab stride M*N = 2^22
    #pragma unroll
    for (int j = 0; j < 16; ++j) {
        const int idx = j*512 + t;
        const int rr = idx >> 5, ck = idx & 31;
        *(uint4*)(dst + (size_t)(m0 + rr)*N + n0 + ck*8) = *(const uint4*)(Ls + rr*256 + ck*8);
    }
}

// ---------------------------------------------------------------- split-K reduces (elementwise, 8/thread)
// wo: y_bf16 = p0+p1+p2+p3 + bias[col] + xres_f32   (4 contiguous-by-pair slabs)
__global__ __launch_bounds__(256)
void reduce_wo(const u16* __restrict__ pl, const u16* __restrict__ ph,
               const float* __restrict__ xres, const float* __restrict__ bias,
               u16* __restrict__ y)
{
    const int i0 = (blockIdx.x*256 + threadIdx.x)*8;
    uint4 a0 = *(const uint4*)(pl + i0);
    uint4 a1 = *(const uint4*)(pl + (1u<<22) + i0);
    uint4 a2 = *(const uint4*)(ph + i0);
    uint4 a3 = *(const uint4*)(ph + (1u<<22) + i0);
    const int col = i0 & 1023;
    float4 b0 = *(const float4*)(bias + col);
    float4 b1 = *(const float4*)(bias + col + 4);
    float4 x0 = *(const float4*)(xres + i0);
    float4 x1 = *(const float4*)(xres + i0 + 4);
    const u16 *s0=(const u16*)&a0, *s1=(const u16*)&a1, *s2=(const u16*)&a2, *s3=(const u16*)&a3;
    const float bb[8] = {b0.x,b0.y,b0.z,b0.w,b1.x,b1.y,b1.z,b1.w};
    const float xx[8] = {x0.x,x0.y,x0.z,x0.w,x1.x,x1.y,x1.z,x1.w};
    u16 out[8];
    #pragma unroll
    for (int j = 0; j < 8; ++j)
        out[j] = f2b(b2f(s0[j]) + b2f(s1[j]) + b2f(s2[j]) + b2f(s3[j]) + bb[j] + xx[j]);
    *(uint4*)(y + i0) = *(const uint4*)out;
}

// ff2 stage 1: s_bf16 = p0+p1+p2+p3, written in-place over p0 (same-element RMW, race-free)
__global__ __launch_bounds__(256)
void reduce_sum4(u16* __restrict__ pl, const u16* __restrict__ ph)
{
    const int i0 = (blockIdx.x*256 + threadIdx.x)*8;
    uint4 a0 = *(const uint4*)(pl + i0);
    uint4 a1 = *(const uint4*)(pl + (1u<<22) + i0);
    uint4 a2 = *(const uint4*)(ph + i0);
    uint4 a3 = *(const uint4*)(ph + (1u<<22) + i0);
    const u16 *s0=(const u16*)&a0, *s1=(const u16*)&a1, *s2=(const u16*)&a2, *s3=(const u16*)&a3;
    u16 out[8];
    #pragma unroll
    for (int j = 0; j < 8; ++j)
        out[j] = f2b(b2f(s0[j]) + b2f(s1[j]) + b2f(s2[j]) + b2f(s3[j]));
    *(uint4*)(pl + i0) = *(const uint4*)out;
}

// ff2 stage 2: out_f32 = s + bias[col] + x1_bf16   (reads ws only, writes d_out fresh)
__global__ __launch_bounds__(256)
void final_ff2(const u16* __restrict__ s, const u16* __restrict__ x1b,
               const float* __restrict__ bias, float* __restrict__ out)
{
    const int i0 = (blockIdx.x*256 + threadIdx.x)*8;
    uint4 a = *(const uint4*)(s + i0);
    uint4 xr = *(const uint4*)(x1b + i0);
    const int col = i0 & 1023;
    float4 b0 = *(const float4*)(bias + col);
    float4 b1 = *(const float4*)(bias + col + 4);
    const u16 *sp=(const u16*)&a, *xp=(const u16*)&xr;
    const float bb[8] = {b0.x,b0.y,b0.z,b0.w,b1.x,b1.y,b1.z,b1.w};
    float f[8];
    #pragma unroll
    for (int j = 0; j < 8; ++j) f[j] = b2f(sp[j]) + b2f(xp[j]) + bb[j];
    float4 o0 = {f[0],f[1],f[2],f[3]}, o1 = {f[4],f[5],f[6],f[7]};
    *(float4*)(out + i0) = o0;
    *(float4*)(out + i0 + 4) = o1;
}

// ---------------------------------------------------------------- attention (causal)
// Grid (bh fastest): XCD-local KV. Block handles pair {pr, 31-pr}; ONE merged K-loop
// stages each K/V tile once via global_load_lds (shared by 4 waves) and feeds up to
// two Q-tiles. LDS layout [k-half][row][32] keeps the m97 64-B-stride fragment reads.
// Q,K: [B*H][S][64]; Vt: [B*H][64][S]; O: [B][S][1024]
__global__ __launch_bounds__(256, 2)
void attn_kernel(const u16* __restrict__ Q, const u16* __restrict__ Kg,
                 const u16* __restrict__ Vt, u16* __restrict__ O)
{
    const int bh = blockIdx.x;            // fastest -> XCD = bh % 8
    const int pr = blockIdx.y;            // 0..15
    const int qta = pr, qtb = 31 - pr;
    const int t = threadIdx.x, wave = t >> 6, lane = t & 63;
    const int lr = lane & 15, quad = lane >> 4;

    __shared__ __align__(16) u16 Ks[4096];        // [2][64][32]
    __shared__ __align__(16) u16 Vs[4096];        // [2][64][32]
    __shared__ __align__(16) u16 Ps[4][16*72];    // wave-private P round-trip

    const size_t qkbase = (size_t)bh * (S_LEN*HD);
    const int b = bh >> 4, h = bh & 15;
    u16* Pw = Ps[wave];
    const f32x4 fzero = {0.f, 0.f, 0.f, 0.f};

    const u16* qpa = Q + qkbase + (size_t)(qta*64 + wave*16 + lr)*HD + quad*8;
    const u16* qpb = Q + qkbase + (size_t)(qtb*64 + wave*16 + lr)*HD + quad*8;
    bf16x8 qa0 = *(const bf16x8*)qpa, qa1 = *(const bf16x8*)(qpa + 32);
    bf16x8 qb0 = *(const bf16x8*)qpb, qb1 = *(const bf16x8*)(qpb + 32);

    f32x4 oa[4], ob[4];
    float la[4], lb[4];
    #pragma unroll
    for (int dt = 0; dt < 4; ++dt) { oa[dt] = fzero; ob[dt] = fzero; }
    #pragma unroll
    for (int r = 0; r < 4; ++r) { la[r] = 0.f; lb[r] = 0.f; }

    const u16* gK = Kg + qkbase + (size_t)(wave*16 + (lane>>2))*HD + (lane&3)*8;
    const u16* gV = Vt + qkbase + (size_t)(wave*16 + (lane>>2))*S_LEN + (lane&3)*8;
    u16* lK = Ks + wave*512;
    u16* lV = Vs + wave*512;

    const int qrow_qa = qta*64 + wave*16 + quad*4;
    const int qrow_qb = qtb*64 + wave*16 + quad*4;

    for (int kb = 0; kb <= qtb; ++kb) {
        __syncthreads();
        load_lds16(gK + (size_t)kb*4096,      lK);
        load_lds16(gK + (size_t)kb*4096 + 32, lK + 2048);
        load_lds16(gV + kb*64,                lV);
        load_lds16(gV + kb*64 + 32,           lV + 2048);
        __syncthreads();

        #pragma unroll
        for (int tile = 0; tile < 2; ++tile) {
            const int qt = tile ? qta : qtb;
            if (tile && kb > qta) break;
            bf16x8 qf0 = tile ? qa0 : qb0;
            bf16x8 qf1 = tile ? qa1 : qb1;
            f32x4* oacc = tile ? oa : ob;
            float* lp   = tile ? la : lb;
            const int qrowq = tile ? qrow_qa : qrow_qb;

            f32x4 sc[4];
            #pragma unroll
            for (int kt2 = 0; kt2 < 4; ++kt2) {
                bf16x8 kf0 = *(const bf16x8*)&Ks[(kt2*16 + lr)*32 + quad*8];
                bf16x8 kf1 = *(const bf16x8*)&Ks[2048 + (kt2*16 + lr)*32 + quad*8];
                sc[kt2] = __builtin_amdgcn_mfma_f32_16x16x32_bf16(qf0, kf0, fzero, 0, 0, 0);
                sc[kt2] = __builtin_amdgcn_mfma_f32_16x16x32_bf16(qf1, kf1, sc[kt2], 0, 0, 0);
            }
            const bool diag = (kb == qt);
            #pragma unroll
            for (int r = 0; r < 4; ++r) {
                #pragma unroll
                for (int kt2 = 0; kt2 < 4; ++kt2) {
                    int kcol = kb*64 + kt2*16 + lr;
                    float p = (!diag || kcol <= qrowq + r) ? __expf(fminf(sc[kt2][r]*0.125f, 30.f)) : 0.f;
                    lp[r] += p;
                    Pw[(quad*4 + r)*72 + kt2*16 + lr] = f2b(p);
                }
            }
            bf16x8 pf0 = *(const bf16x8*)&Pw[lr*72 + quad*8];
            bf16x8 pf1 = *(const bf16x8*)&Pw[lr*72 + 32 + quad*8];
            #pragma unroll
            for (int dt = 0; dt < 4; ++dt) {
                bf16x8 vf0 = *(const bf16x8*)&Vs[(dt*16 + lr)*32 + quad*8];
                bf16x8 vf1 = *(const bf16x8*)&Vs[2048 + (dt*16 + lr)*32 + quad*8];
                oacc[dt] = __builtin_amdgcn_mfma_f32_16x16x32_bf16(pf0, vf0, oacc[dt], 0, 0, 0);
                oacc[dt] = __builtin_amdgcn_mfma_f32_16x16x32_bf16(pf1, vf1, oacc[dt], 0, 0, 0);
            }
        }
    }

    #pragma unroll
    for (int tile = 0; tile < 2; ++tile) {
        const int qt = tile ? qta : qtb;
        f32x4* oacc = tile ? oa : ob;
        float* lp   = tile ? la : lb;
        #pragma unroll
        for (int r = 0; r < 4; ++r) {
            float v = lp[r];
            v += __shfl_xor(v, 1, 64); v += __shfl_xor(v, 2, 64);
            v += __shfl_xor(v, 4, 64); v += __shfl_xor(v, 8, 64);
            lp[r] = 1.0f / fmaxf(v, 1e-20f);
        }
        #pragma unroll
        for (int dt = 0; dt < 4; ++dt)
            #pragma unroll
            for (int r = 0; r < 4; ++r)
                Pw[(quad*4 + r)*64 + dt*16 + lr] = f2b(oacc[dt][r] * lp[r]);

        const int q = lane >> 2, d0 = (lane & 3)*16;
        u16* dst = O + ((size_t)(b*S_LEN + qt*64 + wave*16 + q))*EMB + h*HD + d0;
        *(uint4*)(dst)     = *(uint4*)&Pw[q*64 + d0];
        *(uint4*)(dst + 8) = *(uint4*)&Pw[q*64 + d0 + 8];
    }
}

// ---------------------------------------------------------------- launch
extern "C" void kernel_launch(void* const* d_in, const int* in_sizes, int n_in,
                              void* d_out, int out_size, void* d_ws, size_t ws_size,
                              hipStream_t stream)
{
    (void)in_sizes; (void)n_in; (void)out_size; (void)ws_size;
    const float* x    = (const float*)d_in[0];
    // d_in[1] = mask: causal tril, handled analytically
    const float* ln1g = (const float*)d_in[2];
    const float* ln1b = (const float*)d_in[3];
    const float* wq = (const float*)d_in[4];  const float* bq = (const float*)d_in[5];
    const float* wk = (const float*)d_in[6];  const float* bk = (const float*)d_in[7];
    const float* wv = (const float*)d_in[8];  const float* bv = (const float*)d_in[9];
    const float* wo = (const float*)d_in[10]; const float* bo = (const float*)d_in[11];
    const float* ln2g = (const float*)d_in[12]; const float* ln2b = (const float*)d_in[13];
    const float* w1 = (const float*)d_in[14]; const float* b1 = (const float*)d_in[15];
    const float* w2 = (const float*)d_in[16]; const float* b2 = (const float*)d_in[17];

    u16* ws = (u16*)d_ws;
    const size_t M1 = 1u << 20;             // 1M u16 elements (2 MB)
    u16* wqkvT = ws + 0*M1;                 // bf16 [3072][1024] = wqT|wkT|wvT contiguous
    u16* wqT = ws + 0*M1;
    u16* wkT = ws + 1*M1;
    u16* wvT = ws + 2*M1;
    u16* woT = ws + 3*M1;
    u16* w2T = ws + 0*M1;                   // bf16 [1024][4096], transposed AFTER wo-gemm
    u16* w1T = ws + 4*M1;                   // bf16 [4096][1024]
    u16* h0  = ws + 8*M1;                   // bf16 ln out (reused for ln2 out)
    u16* qb  = ws + 12*M1;                  // bf16 [B,H,S,D]
    u16* kb  = ws + 16*M1;                  // bf16 [B,H,S,D]
    u16* vT  = ws + 20*M1;                  // bf16 [B,H,D,S]
    u16* ao  = ws + 24*M1;                  // bf16 attn out [B,S,E]
    u16* vb  = ws + 24*M1;                  // bf16 V [B,H,S,D] (dead before attn writes ao)
    u16* x1  = ws + 28*M1;                  // bf16 residual-1 out
    u16* fb  = ws + 12*M1;                  // bf16 MLP hidden, overlays q/k/v/ao (dead)
    u16* wosl = ws + 8*M1;                  // wo split-K: 4 bf16 slabs over dead h0/qb/kb/vT (8..24M1)
    u16* ffsl = ws + 4*M1;                  // ff2 split-K: slabs 0,1 over dead w1T/h0 (4..12M1)

    dim3 blk(256);
    transpose_k<<<dim3(16,16), blk, 0, stream>>>(wq, wqT, EMB, EMB);
    transpose_k<<<dim3(16,16), blk, 0, stream>>>(wk, wkT, EMB, EMB);
    transpose_k<<<dim3(16,16), blk, 0, stream>>>(wv, wvT, EMB, EMB);
    transpose_k<<<dim3(16,16), blk, 0, stream>>>(wo, woT, EMB, EMB);
    transpose_k<<<dim3(64,16), blk, 0, stream>>>(w1, w1T, EMB, FF_DIM);

    ln_kernel<1><<<NROWS, blk, 0, stream>>>(x, ln1g, ln1b, h0);

    // fused QKV: 256^2 8-phase kernel, grid = (3072/256, 4096/256)
    gemm256<5><<<dim3(12,16), dim3(512), 0, stream>>>(h0, wqkvT, bq, bk, bv,
                                                      qb, kb, vb, NROWS, 3072, EMB);

    vtrans<<<dim3(32,32), blk, 0, stream>>>(vb, vT);

    attn_kernel<<<dim3(32,16), blk, 0, stream>>>(qb, kb, vT, ao);

    // wo projection: split-K=4 gemm256 (256 blocks = 1/CU), partials in dead 8..24M1
    gemm256sk<<<dim3(4,16,4), dim3(512), 0, stream>>>(ao, woT, wosl, wosl + 8*M1, EMB, EMB);
    reduce_wo<<<2048, blk, 0, stream>>>(wosl, wosl + 8*M1, x, bo, x1);

    transpose_k<<<dim3(16,64), blk, 0, stream>>>(w2, w2T, FF_DIM, EMB);

    ln_kernel<0><<<NROWS, blk, 0, stream>>>(x1, ln2g, ln2b, h0);

    // FF1 (gelu): 256^2 8-phase kernel, grid = (4096/256, 4096/256)
    gemm256<2><<<dim3(16,16), dim3(512), 0, stream>>>(h0, w1T, b1, nullptr, nullptr,
                                                      fb, nullptr, nullptr, NROWS, FF_DIM, EMB);

    // FF2: split-K=4; slabs 0,1 in ws (4..12M1, dead w1T/h0), slabs 2,3 in d_out (scratch)
    gemm256sk<<<dim3(4,16,4), dim3(512), 0, stream>>>(fb, w2T, ffsl, (u16*)d_out, EMB, FF_DIM);
    reduce_sum4<<<2048, blk, 0, stream>>>(ffsl, (u16*)d_out);        // s -> over slab0 (in-place safe)
    final_ff2<<<2048, blk, 0, stream>>>(ffsl, x1, b2, (float*)d_out);
}

// Round 6
// 364.411 us; speedup vs baseline: 1.1519x; 1.0159x over previous
//
#include <hip/hip_runtime.h>

typedef unsigned short u16;
typedef unsigned int   u32;
typedef __attribute__((ext_vector_type(8))) short bf16x8;   // 8 bf16 in 4 VGPRs
typedef __attribute__((ext_vector_type(4))) float f32x4;

#define S_LEN 2048
#define EMB   1024
#define NH    16
#define HD    64
#define FF_DIM 4096
#define NROWS 4096   // B*S

__device__ __forceinline__ float b2f(u16 u){ union{u32 i; float f;} c; c.i = ((u32)u)<<16; return c.f; }
// round-half-up bf16 pack: 2 VALU ops (vs 5 for RNE); differs from RNE only on exact ties
__device__ __forceinline__ u16 f2b(float f){ union{float f; u32 u;} c; c.f=f; return (u16)((c.u + 0x8000u)>>16); }
// fast erf-based gelu: A&S 7.1.26 poly, |eps_erf| ~1.5e-7 (invisible after bf16 round)
__device__ __forceinline__ float gelu_f(float x){
    float z  = x * 0.70710678118f;
    float az = fabsf(z);
    float t  = 1.0f / (1.0f + 0.3275911f * az);
    float p  = ((((1.061405429f*t - 1.453152027f)*t + 1.421413741f)*t - 0.284496736f)*t + 0.254829592f)*t;
    float e  = __expf(-az*az);
    float erfv = 1.0f - p*e;
    erfv = (z < 0.f) ? -erfv : erfv;
    return 0.5f*x*(1.0f + erfv);
}

// async global->LDS, 16B per lane; lds dest = wave-uniform base + lane*16 (m97/m104)
__device__ __forceinline__ void load_lds16(const u16* g, u16* l) {
    __builtin_amdgcn_global_load_lds((const __attribute__((address_space(1))) u32*)g,
                                     (__attribute__((address_space(3))) u32*)l, 16, 0, 0);
}

// ---------------------------------------------------------------- LayerNorm
template<int XF32>
__global__ __launch_bounds__(256)
void ln_kernel(const void* __restrict__ Xv, const float* __restrict__ G,
               const float* __restrict__ Bv, u16* __restrict__ Y)
{
    const int row = blockIdx.x, t = threadIdx.x;
    float v0, v1, v2, v3;
    if constexpr (XF32) {
        float4 r4 = ((const float4*)((const float*)Xv + (size_t)row*EMB))[t];
        v0 = r4.x; v1 = r4.y; v2 = r4.z; v3 = r4.w;
    } else {
        const u16* xr = (const u16*)Xv + (size_t)row*EMB;
        uint2 raw = *(const uint2*)(xr + t*4);
        v0 = b2f(raw.x & 0xffff); v1 = b2f(raw.x >> 16);
        v2 = b2f(raw.y & 0xffff); v3 = b2f(raw.y >> 16);
    }
    float s  = v0+v1+v2+v3;
    float s2 = v0*v0+v1*v1+v2*v2+v3*v3;
    #pragma unroll
    for (int off = 1; off < 64; off <<= 1) {
        s  += __shfl_xor(s,  off, 64);
        s2 += __shfl_xor(s2, off, 64);
    }
    __shared__ float ps[4], ps2[4];
    const int w = t >> 6, lane = t & 63;
    if (lane == 0) { ps[w] = s; ps2[w] = s2; }
    __syncthreads();
    s  = ps[0]+ps[1]+ps[2]+ps[3];
    s2 = ps2[0]+ps2[1]+ps2[2]+ps2[3];
    const float mu   = s * (1.0f/EMB);
    const float rstd = rsqrtf(fmaxf(s2*(1.0f/EMB) - mu*mu, 0.f) + 1e-5f);
    float4 g4 = ((const float4*)G)[t];
    float4 c4 = ((const float4*)Bv)[t];
    u32 lo = (u32)f2b((v0-mu)*rstd*g4.x + c4.x) | ((u32)f2b((v1-mu)*rstd*g4.y + c4.y) << 16);
    u32 hi = (u32)f2b((v2-mu)*rstd*g4.z + c4.z) | ((u32)f2b((v3-mu)*rstd*g4.w + c4.w) << 16);
    uint2 o; o.x = lo; o.y = hi;
    *(uint2*)(Y + (size_t)row*EMB + t*4) = o;
}

// ---------------------------------------------------------------- transpose+downconvert (f32 [K][N] -> bf16 [N][K])
__global__ __launch_bounds__(256)
void transpose_k(const float* __restrict__ in, u16* __restrict__ out, int K, int N)
{
    __shared__ __align__(16) u16 T[64*72];
    const int k0 = blockIdx.y*64, n0 = blockIdx.x*64, t = threadIdx.x;
    #pragma unroll
    for (int c = 0; c < 4; ++c) {
        int e = t*4 + c*1024, ki = e >> 6, nj = e & 63;
        float4 f = *(const float4*)(in + (size_t)(k0+ki)*N + n0 + nj);
        ushort4 s4; s4.x = f2b(f.x); s4.y = f2b(f.y); s4.z = f2b(f.z); s4.w = f2b(f.w);
        *(ushort4*)&T[ki*72 + nj] = s4;
    }
    __syncthreads();
    #pragma unroll
    for (int c = 0; c < 2; ++c) {
        int e = t*8 + c*2048, ni = e >> 6, kj = e & 63;
        uint4 v; u16* pv = (u16*)&v;
        #pragma unroll
        for (int j = 0; j < 8; ++j) pv[j] = T[(kj+j)*72 + ni];
        *(uint4*)(out + (size_t)(n0+ni)*K + k0 + kj) = v;
    }
}

// ---------------------------------------------------------------- bf16 transpose: V [B*H][S][64] -> V^T [B*H][64][S]
__global__ __launch_bounds__(256)
void vtrans(const u16* __restrict__ in, u16* __restrict__ out)
{
    __shared__ __align__(16) u16 T[64*72];
    const int bh = blockIdx.y, s0 = blockIdx.x*64, t = threadIdx.x;
    const size_t base = (size_t)bh * (S_LEN*HD);
    #pragma unroll
    for (int c = 0; c < 2; ++c) {
        int e = t*8 + c*2048, r = e >> 6, d = e & 63;
        *(uint4*)&T[r*72 + d] = *(const uint4*)(in + base + (size_t)(s0 + r)*HD + d);
    }
    __syncthreads();
    #pragma unroll
    for (int c = 0; c < 2; ++c) {
        int e = t*8 + c*2048, d = e >> 6, sj = e & 63;
        uint4 v; u16* pv = (u16*)&v;
        #pragma unroll
        for (int j = 0; j < 8; ++j) pv[j] = T[(sj + j)*72 + d];
        *(uint4*)(out + base + (size_t)d*S_LEN + s0 + sj) = v;
    }
}

// ================================================================ 256x256 8-phase GEMM
// T2+T3+T4+T5 (m194-m201 template, plain HIP): 512 thr = 8 waves (2M x 4N), BK=64,
// LDS 128 KiB = 2 buf x {A,B} x 2 k-halves x [256 rows][32 k] bf16.
// Bank swizzle (T2): involution on u16 offset  off ^= (off>>3)&0x18, BOTH sides (rule 21).
// Read-once quadrants (k-half x MF-half): 24 ds_read/K-tile (minimum).
// vmcnt discipline (r6, m201-faithful): ONE vmcnt(4) per K-tile at its LAST phase.
//   Trace invariant: at each tile-end vmcnt(4), the ENTIRE next tile's 4 half-tiles are
//   forced-landed; every stage has >=4 phases (~2000cy >> 900cy HBM) issue->forced-land.
//   (r5 regression theory: 2 waits/tile with 1-phase slack stalled on HBM latency.)
__device__ __forceinline__ void stage2(const u16* s0, const u16* s1, int koff, u16* dst, int wave){
    load_lds16(s0 + koff, dst + wave*512);
    load_lds16(s1 + koff, dst + 4096 + wave*512);
}

template<int CBUF, int KS, int MFH, int TAILVM>
__device__ __forceinline__ void phase256(u16* Ls, f32x4 (&acc)[8][4], bf16x8 (&bf)[4],
    int wm, int wn, int lr, int quad, int wave,
    const u16* s0, const u16* s1, int koff, u16* dst)
{
    const u16* ak = Ls + CBUF*32768 + KS*8192;
    const u16* bk = Ls + CBUF*32768 + 16384 + KS*8192;
    bf16x8 af[4];
    #pragma unroll
    for (int i = 0; i < 4; ++i) {
        int off = (wm*128 + (MFH*4 + i)*16 + lr)*32 + quad*8;
        af[i] = *(const bf16x8*)(ak + (off ^ ((off>>3)&0x18)));
    }
    if constexpr (MFH == 0) {
        #pragma unroll
        for (int nf = 0; nf < 4; ++nf) {
            int off = (wn*64 + nf*16 + lr)*32 + quad*8;
            bf[nf] = *(const bf16x8*)(bk + (off ^ ((off>>3)&0x18)));
        }
    }
    stage2(s0, s1, koff, dst, wave);
    __builtin_amdgcn_s_barrier();
    asm volatile("s_waitcnt lgkmcnt(0)" ::: "memory");
    __builtin_amdgcn_s_setprio(1);
    #pragma unroll
    for (int i = 0; i < 4; ++i)
        #pragma unroll
        for (int nf = 0; nf < 4; ++nf)
            acc[MFH*4 + i][nf] = __builtin_amdgcn_mfma_f32_16x16x32_bf16(af[i], bf[nf], acc[MFH*4 + i][nf], 0, 0, 0);
    __builtin_amdgcn_s_setprio(0);
    if constexpr (TAILVM) asm volatile("s_waitcnt vmcnt(4)" ::: "memory");
    __builtin_amdgcn_s_barrier();
}

// shared main loop: runs the 8-phase pipeline over NT K-tiles starting at srcA/B (already K-offset)
__device__ __forceinline__ void gemm256_main(u16* Ls, f32x4 (&acc)[8][4],
    int wm, int wn, int lr, int quad, int wave, int NT,
    const u16* srcA0, const u16* srcA1, const u16* srcB0, const u16* srcB1)
{
    u16* A00 = Ls + 0;
    u16* A01 = Ls + 8192;
    u16* B00 = Ls + 16384;
    u16* B01 = Ls + 16384 + 8192;
    u16* A10 = Ls + 32768;
    u16* A11 = Ls + 32768 + 8192;
    u16* B10 = Ls + 32768 + 16384;
    u16* B11 = Ls + 32768 + 16384 + 8192;

    // prologue: tile0 {Akh0,Bkh0,Akh1,Bkh1}, tile1 {Akh0,Bkh0} = loads 1..12 (2/stage)
    stage2(srcA0, srcA1, 0,   A00, wave);
    stage2(srcB0, srcB1, 0,   B00, wave);
    stage2(srcA0, srcA1, 32,  A01, wave);
    stage2(srcB0, srcB1, 32,  B01, wave);
    stage2(srcA0, srcA1, 64,  A10, wave);
    stage2(srcB0, srcB1, 64,  B10, wave);
    asm volatile("s_waitcnt vmcnt(4)" ::: "memory");   // loads 1-8 landed: tile0 fully resident
    __builtin_amdgcn_s_barrier();

    bf16x8 bf[4];
    for (int U = 0; U < NT; U += 2) {
        const int k1 = ((U+1) & (NT-1))*64;
        const int k2 = ((U+2) & (NT-1))*64;   // wraps at tail: redundant-but-safe reload
        const int k3 = ((U+3) & (NT-1))*64;
        // tile U (buf0): stage targets free'd >=1 barrier earlier (per-slot WAR audit r6)
        phase256<0,0,0,0>(Ls, acc, bf, wm, wn, lr, quad, wave, srcA0, srcA1, k1+32, A11);
        phase256<0,0,1,0>(Ls, acc, bf, wm, wn, lr, quad, wave, srcB0, srcB1, k1+32, B11);
        phase256<0,1,0,0>(Ls, acc, bf, wm, wn, lr, quad, wave, srcA0, srcA1, k2,    A00);
        phase256<0,1,1,1>(Ls, acc, bf, wm, wn, lr, quad, wave, srcB0, srcB1, k2,    B00);
        // tile U+1 (buf1)
        phase256<1,0,0,0>(Ls, acc, bf, wm, wn, lr, quad, wave, srcA0, srcA1, k2+32, A01);
        phase256<1,0,1,0>(Ls, acc, bf, wm, wn, lr, quad, wave, srcB0, srcB1, k2+32, B01);
        phase256<1,1,0,0>(Ls, acc, bf, wm, wn, lr, quad, wave, srcA0, srcA1, k3,    A10);
        phase256<1,1,1,1>(Ls, acc, bf, wm, wn, lr, quad, wave, srcB0, srcB1, k3,    B10);
    }

    // drain ALL DMAs (incl. wrapped tail stages) before repurposing LDS
    asm volatile("s_waitcnt vmcnt(0)" ::: "memory");
    __syncthreads();
}

// MODE 2: gelu -> bf16 C.   MODE 5: fused QKV head-split scatter (C=Q, C2=K, C3=V).
template<int MODE>
__global__ __launch_bounds__(512, 2)
void gemm256(const u16* __restrict__ A, const u16* __restrict__ Bt,
             const float* __restrict__ bias, const float* __restrict__ bias2,
             const float* __restrict__ bias3,
             void* __restrict__ C, void* __restrict__ C2, void* __restrict__ C3,
             int M, int N, int K)
{
    (void)M;
    __shared__ __align__(16) u16 Ls[65536];     // 128 KiB
    const int t = threadIdx.x;
    const int wave = t >> 6, lane = t & 63;
    const int wm = wave >> 2, wn = wave & 3;    // 2 x 4 wave grid
    const int lr = lane & 15, quad = lane >> 4;
    const int n0 = blockIdx.x*256, m0 = blockIdx.y*256;

    // per-lane pre-swizzled global sources: phys chunk c (16B) <- logical chunk c^((c>>3)&3)
    const int c0 = wave*64 + lane, c1 = 512 + wave*64 + lane;
    const int l0 = c0 ^ ((c0 >> 3) & 3), l1 = c1 ^ ((c1 >> 3) & 3);
    const int r0 = l0 >> 2, g0 = l0 & 3;
    const int r1 = l1 >> 2, g1 = l1 & 3;
    const u16* srcA0 = A  + (size_t)(m0 + r0)*K + g0*8;
    const u16* srcA1 = A  + (size_t)(m0 + r1)*K + g1*8;
    const u16* srcB0 = Bt + (size_t)(n0 + r0)*K + g0*8;
    const u16* srcB1 = Bt + (size_t)(n0 + r1)*K + g1*8;

    f32x4 acc[8][4];
    const f32x4 fzero = {0.f, 0.f, 0.f, 0.f};
    #pragma unroll
    for (int i = 0; i < 8; ++i)
        #pragma unroll
        for (int j = 0; j < 4; ++j) acc[i][j] = fzero;

    gemm256_main(Ls, acc, wm, wn, lr, quad, wave, K >> 6, srcA0, srcA1, srcB0, srcB1);

    // ---------------- epilogue: bias(+gelu), stage [256][256] bf16 in LDS, coalesced stores
    float bv[4];
    #pragma unroll
    for (int nf = 0; nf < 4; ++nf) {
        const int col = n0 + wn*64 + nf*16 + lr;
        if constexpr (MODE == 5) {
            const int seg = n0 >> 10;    // 256 | 1024: no straddle
            bv[nf] = (seg == 0 ? bias : (seg == 1 ? bias2 : bias3))[col & 1023];
        } else {
            bv[nf] = bias[col];
        }
    }
    #pragma unroll
    for (int mf = 0; mf < 8; ++mf)
        #pragma unroll
        for (int nf = 0; nf < 4; ++nf)
            #pragma unroll
            for (int r = 0; r < 4; ++r) {
                float v = acc[mf][nf][r] + bv[nf];
                if constexpr (MODE == 2) v = gelu_f(v);
                Ls[(wm*128 + mf*16 + quad*4 + r)*256 + wn*64 + nf*16 + lr] = f2b(v);
            }
    __syncthreads();
    // 256x256 u16 = 8192 16B-chunks; 512 threads x 16 iters
    #pragma unroll
    for (int j = 0; j < 16; ++j) {
        const int idx = j*512 + t;
        const int rr = idx >> 5, ck = idx & 31;
        const u16* src = Ls + rr*256 + ck*8;
        const int row = m0 + rr, col = n0 + ck*8;
        if constexpr (MODE == 5) {
            const int seg = n0 >> 10;
            u16* dstb = (u16*)(seg == 0 ? C : (seg == 1 ? C2 : C3));
            const int cs = col & 1023;
            const int h = cs >> 6, d = cs & 63;
            const int b_ = row >> 11, s = row & 2047;
            *(uint4*)(dstb + ((((size_t)(b_*NH + h))*S_LEN + s) << 6) + d) = *(const uint4*)src;
        } else {
            *(uint4*)((u16*)C + (size_t)row*N + col) = *(const uint4*)src;
        }
    }
}

// ================================================================ split-K=4 variant
// grid (N/256, M/256, 4): z = K-split. Writes RAW bf16 partial (no bias) to slab
// (z<2 ? Cl : Ch) + (z&1)*M*N. Fills all 256 CUs for narrow-N deep-K GEMMs (wo, FF2).
__global__ __launch_bounds__(512, 2)
void gemm256sk(const u16* __restrict__ A, const u16* __restrict__ Bt,
               u16* __restrict__ Cl, u16* __restrict__ Ch, int N, int K)
{
    __shared__ __align__(16) u16 Ls[65536];
    const int t = threadIdx.x;
    const int wave = t >> 6, lane = t & 63;
    const int wm = wave >> 2, wn = wave & 3;
    const int lr = lane & 15, quad = lane >> 4;
    const int n0 = blockIdx.x*256, m0 = blockIdx.y*256;
    const int z  = blockIdx.z;
    const int Ks = K >> 2;                       // K-slice per split

    const int c0 = wave*64 + lane, c1 = 512 + wave*64 + lane;
    const int l0 = c0 ^ ((c0 >> 3) & 3), l1 = c1 ^ ((c1 >> 3) & 3);
    const int r0 = l0 >> 2, g0 = l0 & 3;
    const int r1 = l1 >> 2, g1 = l1 & 3;
    const u16* srcA0 = A  + (size_t)(m0 + r0)*K + g0*8 + z*Ks;
    const u16* srcA1 = A  + (size_t)(m0 + r1)*K + g1*8 + z*Ks;
    const u16* srcB0 = Bt + (size_t)(n0 + r0)*K + g0*8 + z*Ks;
    const u16* srcB1 = Bt + (size_t)(n0 + r1)*K + g1*8 + z*Ks;

    f32x4 acc[8][4];
    const f32x4 fzero = {0.f, 0.f, 0.f, 0.f};
    #pragma unroll
    for (int i = 0; i < 8; ++i)
        #pragma unroll
        for (int j = 0; j < 4; ++j) acc[i][j] = fzero;

    gemm256_main(Ls, acc, wm, wn, lr, quad, wave, Ks >> 6, srcA0, srcA1, srcB0, srcB1);

    // epilogue: raw bf16 partial, linear [M][N]
    #pragma unroll
    for (int mf = 0; mf < 8; ++mf)
        #pragma unroll
        for (int nf = 0; nf < 4; ++nf)
            #pragma unroll
            for (int r = 0; r < 4; ++r)
                Ls[(wm*128 + mf*16 + quad*4 + r)*256 + wn*64 + nf*16 + lr] = f2b(acc[mf][nf][r]);
    __syncthreads();
    u16* dst = (z < 2 ? Cl : Ch) + (size_t)(z & 1)*(1u<<22);   // slab stride M*N = 2^22
    #pragma unroll
    for (int j = 0; j < 16; ++j) {
        const int idx = j*512 + t;
        const int rr = idx >> 5, ck = idx & 31;
        *(uint4*)(dst + (size_t)(m0 + rr)*N + n0 + ck*8) = *(const uint4*)(Ls + rr*256 + ck*8);
    }
}

// ---------------------------------------------------------------- split-K reduces (elementwise, 8/thread)
// wo: y_bf16 = p0+p1+p2+p3 + bias[col] + xres_f32   (4 contiguous-by-pair slabs)
__global__ __launch_bounds__(256)
void reduce_wo(const u16* __restrict__ pl, const u16* __restrict__ ph,
               const float* __restrict__ xres, const float* __restrict__ bias,
               u16* __restrict__ y)
{
    const int i0 = (blockIdx.x*256 + threadIdx.x)*8;
    uint4 a0 = *(const uint4*)(pl + i0);
    uint4 a1 = *(const uint4*)(pl + (1u<<22) + i0);
    uint4 a2 = *(const uint4*)(ph + i0);
    uint4 a3 = *(const uint4*)(ph + (1u<<22) + i0);
    const int col = i0 & 1023;
    float4 b0 = *(const float4*)(bias + col);
    float4 b1 = *(const float4*)(bias + col + 4);
    float4 x0 = *(const float4*)(xres + i0);
    float4 x1 = *(const float4*)(xres + i0 + 4);
    const u16 *s0=(const u16*)&a0, *s1=(const u16*)&a1, *s2=(const u16*)&a2, *s3=(const u16*)&a3;
    const float bb[8] = {b0.x,b0.y,b0.z,b0.w,b1.x,b1.y,b1.z,b1.w};
    const float xx[8] = {x0.x,x0.y,x0.z,x0.w,x1.x,x1.y,x1.z,x1.w};
    u16 out[8];
    #pragma unroll
    for (int j = 0; j < 8; ++j)
        out[j] = f2b(b2f(s0[j]) + b2f(s1[j]) + b2f(s2[j]) + b2f(s3[j]) + bb[j] + xx[j]);
    *(uint4*)(y + i0) = *(const uint4*)out;
}

// ff2 fused reduce (r6): out_f32 = (p0+p1+p2+p3) + bias[col] + x1_bf16.
// All 4 slabs live in ws (dead regions), d_out written fresh -> race-free single pass.
__global__ __launch_bounds__(256)
void reduce_ff2(const u16* __restrict__ pl, const u16* __restrict__ ph,
                const u16* __restrict__ x1b, const float* __restrict__ bias,
                float* __restrict__ out)
{
    const int i0 = (blockIdx.x*256 + threadIdx.x)*8;
    uint4 a0 = *(const uint4*)(pl + i0);
    uint4 a1 = *(const uint4*)(pl + (1u<<22) + i0);
    uint4 a2 = *(const uint4*)(ph + i0);
    uint4 a3 = *(const uint4*)(ph + (1u<<22) + i0);
    uint4 xr = *(const uint4*)(x1b + i0);
    const int col = i0 & 1023;
    float4 b0 = *(const float4*)(bias + col);
    float4 b1 = *(const float4*)(bias + col + 4);
    const u16 *s0=(const u16*)&a0, *s1=(const u16*)&a1, *s2=(const u16*)&a2, *s3=(const u16*)&a3;
    const u16 *xp=(const u16*)&xr;
    const float bb[8] = {b0.x,b0.y,b0.z,b0.w,b1.x,b1.y,b1.z,b1.w};
    float f[8];
    #pragma unroll
    for (int j = 0; j < 8; ++j)
        f[j] = b2f(s0[j]) + b2f(s1[j]) + b2f(s2[j]) + b2f(s3[j]) + b2f(xp[j]) + bb[j];
    float4 o0 = {f[0],f[1],f[2],f[3]}, o1 = {f[4],f[5],f[6],f[7]};
    *(float4*)(out + i0) = o0;
    *(float4*)(out + i0 + 4) = o1;
}

// ---------------------------------------------------------------- attention (causal)
// Grid (bh fastest): XCD-local KV. Block handles pair {pr, 31-pr}; ONE merged K-loop
// stages each K/V tile once via global_load_lds (shared by 4 waves) and feeds up to
// two Q-tiles. LDS layout [k-half][row][32] keeps the m97 64-B-stride fragment reads.
// Q,K: [B*H][S][64]; Vt: [B*H][64][S]; O: [B][S][1024]
__global__ __launch_bounds__(256, 2)
void attn_kernel(const u16* __restrict__ Q, const u16* __restrict__ Kg,
                 const u16* __restrict__ Vt, u16* __restrict__ O)
{
    const int bh = blockIdx.x;            // fastest -> XCD = bh % 8
    const int pr = blockIdx.y;            // 0..15
    const int qta = pr, qtb = 31 - pr;
    const int t = threadIdx.x, wave = t >> 6, lane = t & 63;
    const int lr = lane & 15, quad = lane >> 4;

    __shared__ __align__(16) u16 Ks[4096];        // [2][64][32]
    __shared__ __align__(16) u16 Vs[4096];        // [2][64][32]
    __shared__ __align__(16) u16 Ps[4][16*72];    // wave-private P round-trip

    const size_t qkbase = (size_t)bh * (S_LEN*HD);
    const int b = bh >> 4, h = bh & 15;
    u16* Pw = Ps[wave];
    const f32x4 fzero = {0.f, 0.f, 0.f, 0.f};

    const u16* qpa = Q + qkbase + (size_t)(qta*64 + wave*16 + lr)*HD + quad*8;
    const u16* qpb = Q + qkbase + (size_t)(qtb*64 + wave*16 + lr)*HD + quad*8;
    bf16x8 qa0 = *(const bf16x8*)qpa, qa1 = *(const bf16x8*)(qpa + 32);
    bf16x8 qb0 = *(const bf16x8*)qpb, qb1 = *(const bf16x8*)(qpb + 32);

    f32x4 oa[4], ob[4];
    float la[4], lb[4];
    #pragma unroll
    for (int dt = 0; dt < 4; ++dt) { oa[dt] = fzero; ob[dt] = fzero; }
    #pragma unroll
    for (int r = 0; r < 4; ++r) { la[r] = 0.f; lb[r] = 0.f; }

    const u16* gK = Kg + qkbase + (size_t)(wave*16 + (lane>>2))*HD + (lane&3)*8;
    const u16* gV = Vt + qkbase + (size_t)(wave*16 + (lane>>2))*S_LEN + (lane&3)*8;
    u16* lK = Ks + wave*512;
    u16* lV = Vs + wave*512;

    const int qrow_qa = qta*64 + wave*16 + quad*4;
    const int qrow_qb = qtb*64 + wave*16 + quad*4;

    for (int kb = 0; kb <= qtb; ++kb) {
        __syncthreads();
        load_lds16(gK + (size_t)kb*4096,      lK);
        load_lds16(gK + (size_t)kb*4096 + 32, lK + 2048);
        load_lds16(gV + kb*64,                lV);
        load_lds16(gV + kb*64 + 32,           lV + 2048);
        __syncthreads();

        #pragma unroll
        for (int tile = 0; tile < 2; ++tile) {
            const int qt = tile ? qta : qtb;
            if (tile && kb > qta) break;
            bf16x8 qf0 = tile ? qa0 : qb0;
            bf16x8 qf1 = tile ? qa1 : qb1;
            f32x4* oacc = tile ? oa : ob;
            float* lp   = tile ? la : lb;
            const int qrowq = tile ? qrow_qa : qrow_qb;

            f32x4 sc[4];
            #pragma unroll
            for (int kt2 = 0; kt2 < 4; ++kt2) {
                bf16x8 kf0 = *(const bf16x8*)&Ks[(kt2*16 + lr)*32 + quad*8];
                bf16x8 kf1 = *(const bf16x8*)&Ks[2048 + (kt2*16 + lr)*32 + quad*8];
                sc[kt2] = __builtin_amdgcn_mfma_f32_16x16x32_bf16(qf0, kf0, fzero, 0, 0, 0);
                sc[kt2] = __builtin_amdgcn_mfma_f32_16x16x32_bf16(qf1, kf1, sc[kt2], 0, 0, 0);
            }
            const bool diag = (kb == qt);
            #pragma unroll
            for (int r = 0; r < 4; ++r) {
                #pragma unroll
                for (int kt2 = 0; kt2 < 4; ++kt2) {
                    int kcol = kb*64 + kt2*16 + lr;
                    float p = (!diag || kcol <= qrowq + r) ? __expf(fminf(sc[kt2][r]*0.125f, 30.f)) : 0.f;
                    lp[r] += p;
                    Pw[(quad*4 + r)*72 + kt2*16 + lr] = f2b(p);
                }
            }
            bf16x8 pf0 = *(const bf16x8*)&Pw[lr*72 + quad*8];
            bf16x8 pf1 = *(const bf16x8*)&Pw[lr*72 + 32 + quad*8];
            #pragma unroll
            for (int dt = 0; dt < 4; ++dt) {
                bf16x8 vf0 = *(const bf16x8*)&Vs[(dt*16 + lr)*32 + quad*8];
                bf16x8 vf1 = *(const bf16x8*)&Vs[2048 + (dt*16 + lr)*32 + quad*8];
                oacc[dt] = __builtin_amdgcn_mfma_f32_16x16x32_bf16(pf0, vf0, oacc[dt], 0, 0, 0);
                oacc[dt] = __builtin_amdgcn_mfma_f32_16x16x32_bf16(pf1, vf1, oacc[dt], 0, 0, 0);
            }
        }
    }

    #pragma unroll
    for (int tile = 0; tile < 2; ++tile) {
        const int qt = tile ? qta : qtb;
        f32x4* oacc = tile ? oa : ob;
        float* lp   = tile ? la : lb;
        #pragma unroll
        for (int r = 0; r < 4; ++r) {
            float v = lp[r];
            v += __shfl_xor(v, 1, 64); v += __shfl_xor(v, 2, 64);
            v += __shfl_xor(v, 4, 64); v += __shfl_xor(v, 8, 64);
            lp[r] = 1.0f / fmaxf(v, 1e-20f);
        }
        #pragma unroll
        for (int dt = 0; dt < 4; ++dt)
            #pragma unroll
            for (int r = 0; r < 4; ++r)
                Pw[(quad*4 + r)*64 + dt*16 + lr] = f2b(oacc[dt][r] * lp[r]);

        const int q = lane >> 2, d0 = (lane & 3)*16;
        u16* dst = O + ((size_t)(b*S_LEN + qt*64 + wave*16 + q))*EMB + h*HD + d0;
        *(uint4*)(dst)     = *(uint4*)&Pw[q*64 + d0];
        *(uint4*)(dst + 8) = *(uint4*)&Pw[q*64 + d0 + 8];
    }
}

// ---------------------------------------------------------------- launch
extern "C" void kernel_launch(void* const* d_in, const int* in_sizes, int n_in,
                              void* d_out, int out_size, void* d_ws, size_t ws_size,
                              hipStream_t stream)
{
    (void)in_sizes; (void)n_in; (void)out_size; (void)ws_size;
    const float* x    = (const float*)d_in[0];
    // d_in[1] = mask: causal tril, handled analytically
    const float* ln1g = (const float*)d_in[2];
    const float* ln1b = (const float*)d_in[3];
    const float* wq = (const float*)d_in[4];  const float* bq = (const float*)d_in[5];
    const float* wk = (const float*)d_in[6];  const float* bk = (const float*)d_in[7];
    const float* wv = (const float*)d_in[8];  const float* bv = (const float*)d_in[9];
    const float* wo = (const float*)d_in[10]; const float* bo = (const float*)d_in[11];
    const float* ln2g = (const float*)d_in[12]; const float* ln2b = (const float*)d_in[13];
    const float* w1 = (const float*)d_in[14]; const float* b1 = (const float*)d_in[15];
    const float* w2 = (const float*)d_in[16]; const float* b2 = (const float*)d_in[17];

    u16* ws = (u16*)d_ws;
    const size_t M1 = 1u << 20;             // 1M u16 elements (2 MB)
    u16* wqkvT = ws + 0*M1;                 // bf16 [3072][1024] = wqT|wkT|wvT contiguous
    u16* wqT = ws + 0*M1;
    u16* wkT = ws + 1*M1;
    u16* wvT = ws + 2*M1;
    u16* woT = ws + 3*M1;
    u16* w2T = ws + 0*M1;                   // bf16 [1024][4096], transposed AFTER wo-gemm
    u16* w1T = ws + 4*M1;                   // bf16 [4096][1024]
    u16* h0  = ws + 8*M1;                   // bf16 ln out (reused for ln2 out)
    u16* qb  = ws + 12*M1;                  // bf16 [B,H,S,D]
    u16* kb  = ws + 16*M1;                  // bf16 [B,H,S,D]
    u16* vT  = ws + 20*M1;                  // bf16 [B,H,D,S]
    u16* ao  = ws + 24*M1;                  // bf16 attn out [B,S,E]
    u16* vb  = ws + 24*M1;                  // bf16 V [B,H,S,D] (dead before attn writes ao)
    u16* x1  = ws + 28*M1;                  // bf16 residual-1 out
    u16* fb  = ws + 12*M1;                  // bf16 MLP hidden, overlays q/k/v/ao (dead)
    u16* wosl = ws + 8*M1;                  // wo split-K: 4 bf16 slabs over dead h0/qb/kb/vT (8..24M1)
    u16* ffsl_lo = ws + 4*M1;               // ff2 split-K slabs 0,1 over dead w1T/h0 (4..12M1)
    u16* ffsl_hi = ws + 20*M1;              // ff2 split-K slabs 2,3 over dead vT/ao (20..28M1)

    dim3 blk(256);
    transpose_k<<<dim3(16,16), blk, 0, stream>>>(wq, wqT, EMB, EMB);
    transpose_k<<<dim3(16,16), blk, 0, stream>>>(wk, wkT, EMB, EMB);
    transpose_k<<<dim3(16,16), blk, 0, stream>>>(wv, wvT, EMB, EMB);
    transpose_k<<<dim3(16,16), blk, 0, stream>>>(wo, woT, EMB, EMB);
    transpose_k<<<dim3(64,16), blk, 0, stream>>>(w1, w1T, EMB, FF_DIM);

    ln_kernel<1><<<NROWS, blk, 0, stream>>>(x, ln1g, ln1b, h0);

    // fused QKV: 256^2 8-phase kernel, grid = (3072/256, 4096/256)
    gemm256<5><<<dim3(12,16), dim3(512), 0, stream>>>(h0, wqkvT, bq, bk, bv,
                                                      qb, kb, vb, NROWS, 3072, EMB);

    vtrans<<<dim3(32,32), blk, 0, stream>>>(vb, vT);

    attn_kernel<<<dim3(32,16), blk, 0, stream>>>(qb, kb, vT, ao);

    // wo projection: split-K=4 gemm256 (256 blocks = 1/CU), partials in dead 8..24M1
    gemm256sk<<<dim3(4,16,4), dim3(512), 0, stream>>>(ao, woT, wosl, wosl + 8*M1, EMB, EMB);
    reduce_wo<<<2048, blk, 0, stream>>>(wosl, wosl + 8*M1, x, bo, x1);

    transpose_k<<<dim3(16,64), blk, 0, stream>>>(w2, w2T, FF_DIM, EMB);

    ln_kernel<0><<<NROWS, blk, 0, stream>>>(x1, ln2g, ln2b, h0);

    // FF1 (gelu): 256^2 8-phase kernel, grid = (4096/256, 4096/256)
    gemm256<2><<<dim3(16,16), dim3(512), 0, stream>>>(h0, w1T, b1, nullptr, nullptr,
                                                      fb, nullptr, nullptr, NROWS, FF_DIM, EMB);

    // FF2: split-K=4, all 4 slabs in dead ws regions; single fused reduce writes d_out
    gemm256sk<<<dim3(4,16,4), dim3(512), 0, stream>>>(fb, w2T, ffsl_lo, ffsl_hi, EMB, FF_DIM);
    reduce_ff2<<<2048, blk, 0, stream>>>(ffsl_lo, ffsl_hi, x1, b2, (float*)d_out);
}

// Round 7
// 363.686 us; speedup vs baseline: 1.1542x; 1.0020x over previous
//
#include <hip/hip_runtime.h>

typedef unsigned short u16;
typedef unsigned int   u32;
typedef __attribute__((ext_vector_type(8))) short bf16x8;   // 8 bf16 in 4 VGPRs
typedef __attribute__((ext_vector_type(4))) float f32x4;

#define S_LEN 2048
#define EMB   1024
#define NH    16
#define HD    64
#define FF_DIM 4096
#define NROWS 4096   // B*S

__device__ __forceinline__ float b2f(u16 u){ union{u32 i; float f;} c; c.i = ((u32)u)<<16; return c.f; }
// round-half-up bf16 pack: 2 VALU ops (vs 5 for RNE); differs from RNE only on exact ties
__device__ __forceinline__ u16 f2b(float f){ union{float f; u32 u;} c; c.f=f; return (u16)((c.u + 0x8000u)>>16); }
// fast erf-based gelu: A&S 7.1.26 poly, |eps_erf| ~1.5e-7 (invisible after bf16 round)
__device__ __forceinline__ float gelu_f(float x){
    float z  = x * 0.70710678118f;
    float az = fabsf(z);
    float t  = 1.0f / (1.0f + 0.3275911f * az);
    float p  = ((((1.061405429f*t - 1.453152027f)*t + 1.421413741f)*t - 0.284496736f)*t + 0.254829592f)*t;
    float e  = __expf(-az*az);
    float erfv = 1.0f - p*e;
    erfv = (z < 0.f) ? -erfv : erfv;
    return 0.5f*x*(1.0f + erfv);
}

// async global->LDS, 16B per lane; lds dest = wave-uniform base + lane*16 (m97/m104)
__device__ __forceinline__ void load_lds16(const u16* g, u16* l) {
    __builtin_amdgcn_global_load_lds((const __attribute__((address_space(1))) u32*)g,
                                     (__attribute__((address_space(3))) u32*)l, 16, 0, 0);
}

// ---------------------------------------------------------------- LayerNorm
template<int XF32>
__global__ __launch_bounds__(256)
void ln_kernel(const void* __restrict__ Xv, const float* __restrict__ G,
               const float* __restrict__ Bv, u16* __restrict__ Y)
{
    const int row = blockIdx.x, t = threadIdx.x;
    float v0, v1, v2, v3;
    if constexpr (XF32) {
        float4 r4 = ((const float4*)((const float*)Xv + (size_t)row*EMB))[t];
        v0 = r4.x; v1 = r4.y; v2 = r4.z; v3 = r4.w;
    } else {
        const u16* xr = (const u16*)Xv + (size_t)row*EMB;
        uint2 raw = *(const uint2*)(xr + t*4);
        v0 = b2f(raw.x & 0xffff); v1 = b2f(raw.x >> 16);
        v2 = b2f(raw.y & 0xffff); v3 = b2f(raw.y >> 16);
    }
    float s  = v0+v1+v2+v3;
    float s2 = v0*v0+v1*v1+v2*v2+v3*v3;
    #pragma unroll
    for (int off = 1; off < 64; off <<= 1) {
        s  += __shfl_xor(s,  off, 64);
        s2 += __shfl_xor(s2, off, 64);
    }
    __shared__ float ps[4], ps2[4];
    const int w = t >> 6, lane = t & 63;
    if (lane == 0) { ps[w] = s; ps2[w] = s2; }
    __syncthreads();
    s  = ps[0]+ps[1]+ps[2]+ps[3];
    s2 = ps2[0]+ps2[1]+ps2[2]+ps2[3];
    const float mu   = s * (1.0f/EMB);
    const float rstd = rsqrtf(fmaxf(s2*(1.0f/EMB) - mu*mu, 0.f) + 1e-5f);
    float4 g4 = ((const float4*)G)[t];
    float4 c4 = ((const float4*)Bv)[t];
    u32 lo = (u32)f2b((v0-mu)*rstd*g4.x + c4.x) | ((u32)f2b((v1-mu)*rstd*g4.y + c4.y) << 16);
    u32 hi = (u32)f2b((v2-mu)*rstd*g4.z + c4.z) | ((u32)f2b((v3-mu)*rstd*g4.w + c4.w) << 16);
    uint2 o; o.x = lo; o.y = hi;
    *(uint2*)(Y + (size_t)row*EMB + t*4) = o;
}

// ---------------------------------------------------------------- transpose+downconvert (f32 [K][N] -> bf16 [N][K])
__global__ __launch_bounds__(256)
void transpose_k(const float* __restrict__ in, u16* __restrict__ out, int K, int N)
{
    __shared__ __align__(16) u16 T[64*72];
    const int k0 = blockIdx.y*64, n0 = blockIdx.x*64, t = threadIdx.x;
    #pragma unroll
    for (int c = 0; c < 4; ++c) {
        int e = t*4 + c*1024, ki = e >> 6, nj = e & 63;
        float4 f = *(const float4*)(in + (size_t)(k0+ki)*N + n0 + nj);
        ushort4 s4; s4.x = f2b(f.x); s4.y = f2b(f.y); s4.z = f2b(f.z); s4.w = f2b(f.w);
        *(ushort4*)&T[ki*72 + nj] = s4;
    }
    __syncthreads();
    #pragma unroll
    for (int c = 0; c < 2; ++c) {
        int e = t*8 + c*2048, ni = e >> 6, kj = e & 63;
        uint4 v; u16* pv = (u16*)&v;
        #pragma unroll
        for (int j = 0; j < 8; ++j) pv[j] = T[(kj+j)*72 + ni];
        *(uint4*)(out + (size_t)(n0+ni)*K + k0 + kj) = v;
    }
}

// ---------------------------------------------------------------- bf16 transpose: V [B*H][S][64] -> V^T [B*H][64][S]
__global__ __launch_bounds__(256)
void vtrans(const u16* __restrict__ in, u16* __restrict__ out)
{
    __shared__ __align__(16) u16 T[64*72];
    const int bh = blockIdx.y, s0 = blockIdx.x*64, t = threadIdx.x;
    const size_t base = (size_t)bh * (S_LEN*HD);
    #pragma unroll
    for (int c = 0; c < 2; ++c) {
        int e = t*8 + c*2048, r = e >> 6, d = e & 63;
        *(uint4*)&T[r*72 + d] = *(const uint4*)(in + base + (size_t)(s0 + r)*HD + d);
    }
    __syncthreads();
    #pragma unroll
    for (int c = 0; c < 2; ++c) {
        int e = t*8 + c*2048, d = e >> 6, sj = e & 63;
        uint4 v; u16* pv = (u16*)&v;
        #pragma unroll
        for (int j = 0; j < 8; ++j) pv[j] = T[(sj + j)*72 + d];
        *(uint4*)(out + base + (size_t)d*S_LEN + s0 + sj) = v;
    }
}

// ================================================================ 256x256 8-phase GEMM
// T2+T3+T4+T5 (m194-m201 template) + r7 one-phase FRAGMENT PREFETCH:
//   per phase, issue the NEXT phase's ds_reads BEFORE this phase's MFMA cluster ->
//   LDS drain (437cy/CU) hides under MFMA (621cy/SIMD). No explicit lgkmcnt(0):
//   in-order DS completion + compiler per-register waits give counted lgkm
//   (read order per phase: aL, bC, aH -> MFMA operands always issued before the
//   outstanding prefetch). Tile-boundary phases 0/4 self-read (their slots are
//   forced only by the PRECEDING phase's tail vmcnt -> prefetch would race).
// Reads/K-tile: 24 (minimum). Stage skeleton + ONE vmcnt(4) per K-tile (end of
//   ph3/ph7) unchanged from r6 (slot trace: each tile-end vmcnt forces the entire
//   next tile; every stage has >=4 phases issue->forced-land).
// Bank swizzle (T2): involution off ^= (off>>3)&0x18 on BOTH sides (rule 21).
__device__ __forceinline__ void stage2(const u16* s0, const u16* s1, int koff, u16* dst, int wave){
    load_lds16(s0 + koff, dst + wave*512);
    load_lds16(s1 + koff, dst + 4096 + wave*512);
}

template<int CBUF,int KS,int H>
__device__ __forceinline__ void rdA4(const u16* Ls, int wm, int lr, int quad, bf16x8 (&d)[4]){
    const u16* ak = Ls + CBUF*32768 + KS*8192;
    #pragma unroll
    for (int i = 0; i < 4; ++i){
        int off = (wm*128 + H*64 + i*16 + lr)*32 + quad*8;
        d[i] = *(const bf16x8*)(ak + (off ^ ((off>>3)&0x18)));
    }
}
template<int CBUF,int KS>
__device__ __forceinline__ void rdB4(const u16* Ls, int wn, int lr, int quad, bf16x8 (&d)[4]){
    const u16* bk = Ls + CBUF*32768 + 16384 + KS*8192;
    #pragma unroll
    for (int nf = 0; nf < 4; ++nf){
        int off = (wn*64 + nf*16 + lr)*32 + quad*8;
        d[nf] = *(const bf16x8*)(bk + (off ^ ((off>>3)&0x18)));
    }
}
// 16-MFMA cluster for one M-half (T5 setprio wrap)
__device__ __forceinline__ void mm4(f32x4 (&acc)[8][4], int m0, const bf16x8 (&a)[4], const bf16x8 (&b)[4]){
    __builtin_amdgcn_s_setprio(1);
    #pragma unroll
    for (int i = 0; i < 4; ++i)
        #pragma unroll
        for (int nf = 0; nf < 4; ++nf)
            acc[m0+i][nf] = __builtin_amdgcn_mfma_f32_16x16x32_bf16(a[i], b[nf], acc[m0+i][nf], 0, 0, 0);
    __builtin_amdgcn_s_setprio(0);
}

// shared main loop: 8-phase pipeline over NT K-tiles starting at srcA/B (already K-offset)
__device__ __forceinline__ void gemm256_main(u16* Ls, f32x4 (&acc)[8][4],
    int wm, int wn, int lr, int quad, int wave, int NT,
    const u16* srcA0, const u16* srcA1, const u16* srcB0, const u16* srcB1)
{
    u16* A00 = Ls + 0;
    u16* A01 = Ls + 8192;
    u16* B00 = Ls + 16384;
    u16* B01 = Ls + 16384 + 8192;
    u16* A10 = Ls + 32768;
    u16* A11 = Ls + 32768 + 8192;
    u16* B10 = Ls + 32768 + 16384;
    u16* B11 = Ls + 32768 + 16384 + 8192;

    // prologue: tile0 {Akh0,Bkh0,Akh1,Bkh1}, tile1 {Akh0,Bkh0} = 12 loads (2/stage)
    stage2(srcA0, srcA1, 0,   A00, wave);
    stage2(srcB0, srcB1, 0,   B00, wave);
    stage2(srcA0, srcA1, 32,  A01, wave);
    stage2(srcB0, srcB1, 32,  B01, wave);
    stage2(srcA0, srcA1, 64,  A10, wave);
    stage2(srcB0, srcB1, 64,  B10, wave);
    asm volatile("s_waitcnt vmcnt(4)" ::: "memory");   // A00,B00,A01,B01 landed (tile0 complete)
    __builtin_amdgcn_s_barrier();

    bf16x8 aL0[4], aH0[4], bC0[4];     // KS-pair frag sets (even pair)
    bf16x8 aL1[4], aH1[4], bC1[4];     // (odd pair)
    for (int U = 0; U < NT; U += 2) {
        const int k1 = ((U+1) & (NT-1))*64;
        const int k2 = ((U+2) & (NT-1))*64;   // wraps at tail: redundant-but-safe reload
        const int k3 = ((U+3) & (NT-1))*64;
        // ---- tile U (buf0) ----
        // ph0: self-read (A00/B00 safe since prev ph7 vmcnt+barrier); order aL,bC,aH
        rdA4<0,0,0>(Ls, wm, lr, quad, aL0);
        rdB4<0,0>  (Ls, wn, lr, quad, bC0);
        rdA4<0,0,1>(Ls, wm, lr, quad, aH0);
        stage2(srcA0, srcA1, k1+32, A11, wave);
        __builtin_amdgcn_s_barrier();
        mm4(acc, 0, aL0, bC0);                       // waits aL0+bC0 (aH0 outstanding)
        __builtin_amdgcn_s_barrier();
        // ph1: prefetch ph2 (A01/B01 staged prev iter, forced prev ph7 -> safe)
        rdA4<0,1,0>(Ls, wm, lr, quad, aL1);
        rdB4<0,1>  (Ls, wn, lr, quad, bC1);
        stage2(srcB0, srcB1, k1+32, B11, wave);
        __builtin_amdgcn_s_barrier();
        mm4(acc, 4, aH0, bC0);                       // waits aH0 (ph0); aL1/bC1 outstanding
        __builtin_amdgcn_s_barrier();
        // ph2: prefetch ph3 A-high
        rdA4<0,1,1>(Ls, wm, lr, quad, aH1);
        stage2(srcA0, srcA1, k2, A00, wave);
        __builtin_amdgcn_s_barrier();
        mm4(acc, 0, aL1, bC1);                       // waits aL1/bC1 (ph1); aH1 outstanding
        __builtin_amdgcn_s_barrier();
        // ph3: no reads (ph4's slots forced only by THIS phase's vmcnt)
        stage2(srcB0, srcB1, k2, B00, wave);
        __builtin_amdgcn_s_barrier();
        mm4(acc, 4, aH1, bC1);                       // waits aH1 (ph2)
        asm volatile("s_waitcnt vmcnt(4)" ::: "memory");   // forces tile U+1 complete
        __builtin_amdgcn_s_barrier();
        // ---- tile U+1 (buf1) ----
        // ph4: self-read (A10/B10 forced by ph3 vmcnt+barrier)
        rdA4<1,0,0>(Ls, wm, lr, quad, aL0);
        rdB4<1,0>  (Ls, wn, lr, quad, bC0);
        rdA4<1,0,1>(Ls, wm, lr, quad, aH0);
        stage2(srcA0, srcA1, k2+32, A01, wave);
        __builtin_amdgcn_s_barrier();
        mm4(acc, 0, aL0, bC0);
        __builtin_amdgcn_s_barrier();
        // ph5: prefetch ph6 (A11/B11 staged ph0/ph1, forced ph3 -> safe)
        rdA4<1,1,0>(Ls, wm, lr, quad, aL1);
        rdB4<1,1>  (Ls, wn, lr, quad, bC1);
        stage2(srcB0, srcB1, k2+32, B01, wave);
        __builtin_amdgcn_s_barrier();
        mm4(acc, 4, aH0, bC0);
        __builtin_amdgcn_s_barrier();
        // ph6: prefetch ph7 A-high
        rdA4<1,1,1>(Ls, wm, lr, quad, aH1);
        stage2(srcA0, srcA1, k3, A10, wave);
        __builtin_amdgcn_s_barrier();
        mm4(acc, 0, aL1, bC1);
        __builtin_amdgcn_s_barrier();
        // ph7: no reads
        stage2(srcB0, srcB1, k3, B10, wave);
        __builtin_amdgcn_s_barrier();
        mm4(acc, 4, aH1, bC1);
        asm volatile("s_waitcnt vmcnt(4)" ::: "memory");   // forces tile U+2 complete
        __builtin_amdgcn_s_barrier();
    }

    // drain ALL DMAs (incl. wrapped tail stages) before repurposing LDS
    asm volatile("s_waitcnt vmcnt(0)" ::: "memory");
    __syncthreads();
}

// MODE 2: gelu -> bf16 C.   MODE 5: fused QKV head-split scatter (C=Q, C2=K, C3=V).
template<int MODE>
__global__ __launch_bounds__(512, 2)
void gemm256(const u16* __restrict__ A, const u16* __restrict__ Bt,
             const float* __restrict__ bias, const float* __restrict__ bias2,
             const float* __restrict__ bias3,
             void* __restrict__ C, void* __restrict__ C2, void* __restrict__ C3,
             int M, int N, int K)
{
    (void)M;
    __shared__ __align__(16) u16 Ls[65536];     // 128 KiB
    const int t = threadIdx.x;
    const int wave = t >> 6, lane = t & 63;
    const int wm = wave >> 2, wn = wave & 3;    // 2 x 4 wave grid
    const int lr = lane & 15, quad = lane >> 4;
    const int n0 = blockIdx.x*256, m0 = blockIdx.y*256;

    // per-lane pre-swizzled global sources: phys chunk c (16B) <- logical chunk c^((c>>3)&3)
    const int c0 = wave*64 + lane, c1 = 512 + wave*64 + lane;
    const int l0 = c0 ^ ((c0 >> 3) & 3), l1 = c1 ^ ((c1 >> 3) & 3);
    const int r0 = l0 >> 2, g0 = l0 & 3;
    const int r1 = l1 >> 2, g1 = l1 & 3;
    const u16* srcA0 = A  + (size_t)(m0 + r0)*K + g0*8;
    const u16* srcA1 = A  + (size_t)(m0 + r1)*K + g1*8;
    const u16* srcB0 = Bt + (size_t)(n0 + r0)*K + g0*8;
    const u16* srcB1 = Bt + (size_t)(n0 + r1)*K + g1*8;

    f32x4 acc[8][4];
    const f32x4 fzero = {0.f, 0.f, 0.f, 0.f};
    #pragma unroll
    for (int i = 0; i < 8; ++i)
        #pragma unroll
        for (int j = 0; j < 4; ++j) acc[i][j] = fzero;

    gemm256_main(Ls, acc, wm, wn, lr, quad, wave, K >> 6, srcA0, srcA1, srcB0, srcB1);

    // ---------------- epilogue: bias(+gelu), stage [256][256] bf16 in LDS, coalesced stores
    float bv[4];
    #pragma unroll
    for (int nf = 0; nf < 4; ++nf) {
        const int col = n0 + wn*64 + nf*16 + lr;
        if constexpr (MODE == 5) {
            const int seg = n0 >> 10;    // 256 | 1024: no straddle
            bv[nf] = (seg == 0 ? bias : (seg == 1 ? bias2 : bias3))[col & 1023];
        } else {
            bv[nf] = bias[col];
        }
    }
    #pragma unroll
    for (int mf = 0; mf < 8; ++mf)
        #pragma unroll
        for (int nf = 0; nf < 4; ++nf)
            #pragma unroll
            for (int r = 0; r < 4; ++r) {
                float v = acc[mf][nf][r] + bv[nf];
                if constexpr (MODE == 2) v = gelu_f(v);
                Ls[(wm*128 + mf*16 + quad*4 + r)*256 + wn*64 + nf*16 + lr] = f2b(v);
            }
    __syncthreads();
    // 256x256 u16 = 8192 16B-chunks; 512 threads x 16 iters
    #pragma unroll
    for (int j = 0; j < 16; ++j) {
        const int idx = j*512 + t;
        const int rr = idx >> 5, ck = idx & 31;
        const u16* src = Ls + rr*256 + ck*8;
        const int row = m0 + rr, col = n0 + ck*8;
        if constexpr (MODE == 5) {
            const int seg = n0 >> 10;
            u16* dstb = (u16*)(seg == 0 ? C : (seg == 1 ? C2 : C3));
            const int cs = col & 1023;
            const int h = cs >> 6, d = cs & 63;
            const int b_ = row >> 11, s = row & 2047;
            *(uint4*)(dstb + ((((size_t)(b_*NH + h))*S_LEN + s) << 6) + d) = *(const uint4*)src;
        } else {
            *(uint4*)((u16*)C + (size_t)row*N + col) = *(const uint4*)src;
        }
    }
}

// ================================================================ split-K=4 variant
// grid (N/256, M/256, 4): z = K-split. Writes RAW bf16 partial (no bias) to slab
// (z<2 ? Cl : Ch) + (z&1)*M*N. Fills all 256 CUs for narrow-N deep-K GEMMs (wo, FF2).
__global__ __launch_bounds__(512, 2)
void gemm256sk(const u16* __restrict__ A, const u16* __restrict__ Bt,
               u16* __restrict__ Cl, u16* __restrict__ Ch, int N, int K)
{
    __shared__ __align__(16) u16 Ls[65536];
    const int t = threadIdx.x;
    const int wave = t >> 6, lane = t & 63;
    const int wm = wave >> 2, wn = wave & 3;
    const int lr = lane & 15, quad = lane >> 4;
    const int n0 = blockIdx.x*256, m0 = blockIdx.y*256;
    const int z  = blockIdx.z;
    const int Ks = K >> 2;                       // K-slice per split

    const int c0 = wave*64 + lane, c1 = 512 + wave*64 + lane;
    const int l0 = c0 ^ ((c0 >> 3) & 3), l1 = c1 ^ ((c1 >> 3) & 3);
    const int r0 = l0 >> 2, g0 = l0 & 3;
    const int r1 = l1 >> 2, g1 = l1 & 3;
    const u16* srcA0 = A  + (size_t)(m0 + r0)*K + g0*8 + z*Ks;
    const u16* srcA1 = A  + (size_t)(m0 + r1)*K + g1*8 + z*Ks;
    const u16* srcB0 = Bt + (size_t)(n0 + r0)*K + g0*8 + z*Ks;
    const u16* srcB1 = Bt + (size_t)(n0 + r1)*K + g1*8 + z*Ks;

    f32x4 acc[8][4];
    const f32x4 fzero = {0.f, 0.f, 0.f, 0.f};
    #pragma unroll
    for (int i = 0; i < 8; ++i)
        #pragma unroll
        for (int j = 0; j < 4; ++j) acc[i][j] = fzero;

    gemm256_main(Ls, acc, wm, wn, lr, quad, wave, Ks >> 6, srcA0, srcA1, srcB0, srcB1);

    // epilogue: raw bf16 partial, linear [M][N]
    #pragma unroll
    for (int mf = 0; mf < 8; ++mf)
        #pragma unroll
        for (int nf = 0; nf < 4; ++nf)
            #pragma unroll
            for (int r = 0; r < 4; ++r)
                Ls[(wm*128 + mf*16 + quad*4 + r)*256 + wn*64 + nf*16 + lr] = f2b(acc[mf][nf][r]);
    __syncthreads();
    u16* dst = (z < 2 ? Cl : Ch) + (size_t)(z & 1)*(1u<<22);   // slab stride M*N = 2^22
    #pragma unroll
    for (int j = 0; j < 16; ++j) {
        const int idx = j*512 + t;
        const int rr = idx >> 5, ck = idx & 31;
        *(uint4*)(dst + (size_t)(m0 + rr)*N + n0 + ck*8) = *(const uint4*)(Ls + rr*256 + ck*8);
    }
}

// ---------------------------------------------------------------- split-K reduces (elementwise, 8/thread)
// wo: y_bf16 = p0+p1+p2+p3 + bias[col] + xres_f32   (4 contiguous-by-pair slabs)
__global__ __launch_bounds__(256)
void reduce_wo(const u16* __restrict__ pl, const u16* __restrict__ ph,
               const float* __restrict__ xres, const float* __restrict__ bias,
               u16* __restrict__ y)
{
    const int i0 = (blockIdx.x*256 + threadIdx.x)*8;
    uint4 a0 = *(const uint4*)(pl + i0);
    uint4 a1 = *(const uint4*)(pl + (1u<<22) + i0);
    uint4 a2 = *(const uint4*)(ph + i0);
    uint4 a3 = *(const uint4*)(ph + (1u<<22) + i0);
    const int col = i0 & 1023;
    float4 b0 = *(const float4*)(bias + col);
    float4 b1 = *(const float4*)(bias + col + 4);
    float4 x0 = *(const float4*)(xres + i0);
    float4 x1 = *(const float4*)(xres + i0 + 4);
    const u16 *s0=(const u16*)&a0, *s1=(const u16*)&a1, *s2=(const u16*)&a2, *s3=(const u16*)&a3;
    const float bb[8] = {b0.x,b0.y,b0.z,b0.w,b1.x,b1.y,b1.z,b1.w};
    const float xx[8] = {x0.x,x0.y,x0.z,x0.w,x1.x,x1.y,x1.z,x1.w};
    u16 out[8];
    #pragma unroll
    for (int j = 0; j < 8; ++j)
        out[j] = f2b(b2f(s0[j]) + b2f(s1[j]) + b2f(s2[j]) + b2f(s3[j]) + bb[j] + xx[j]);
    *(uint4*)(y + i0) = *(const uint4*)out;
}

// ff2 fused reduce: out_f32 = (p0+p1+p2+p3) + bias[col] + x1_bf16.
// All 4 slabs live in ws (dead regions), d_out written fresh -> race-free single pass.
__global__ __launch_bounds__(256)
void reduce_ff2(const u16* __restrict__ pl, const u16* __restrict__ ph,
                const u16* __restrict__ x1b, const float* __restrict__ bias,
                float* __restrict__ out)
{
    const int i0 = (blockIdx.x*256 + threadIdx.x)*8;
    uint4 a0 = *(const uint4*)(pl + i0);
    uint4 a1 = *(const uint4*)(pl + (1u<<22) + i0);
    uint4 a2 = *(const uint4*)(ph + i0);
    uint4 a3 = *(const uint4*)(ph + (1u<<22) + i0);
    uint4 xr = *(const uint4*)(x1b + i0);
    const int col = i0 & 1023;
    float4 b0 = *(const float4*)(bias + col);
    float4 b1 = *(const float4*)(bias + col + 4);
    const u16 *s0=(const u16*)&a0, *s1=(const u16*)&a1, *s2=(const u16*)&a2, *s3=(const u16*)&a3;
    const u16 *xp=(const u16*)&xr;
    const float bb[8] = {b0.x,b0.y,b0.z,b0.w,b1.x,b1.y,b1.z,b1.w};
    float f[8];
    #pragma unroll
    for (int j = 0; j < 8; ++j)
        f[j] = b2f(s0[j]) + b2f(s1[j]) + b2f(s2[j]) + b2f(s3[j]) + b2f(xp[j]) + bb[j];
    float4 o0 = {f[0],f[1],f[2],f[3]}, o1 = {f[4],f[5],f[6],f[7]};
    *(float4*)(out + i0) = o0;
    *(float4*)(out + i0 + 4) = o1;
}

// ---------------------------------------------------------------- attention (causal)
// Grid (bh fastest): XCD-local KV. Block handles pair {pr, 31-pr}; ONE merged K-loop
// stages each K/V tile once via global_load_lds (shared by 4 waves) and feeds up to
// two Q-tiles. LDS layout [k-half][row][32] keeps the m97 64-B-stride fragment reads.
// Q,K: [B*H][S][64]; Vt: [B*H][64][S]; O: [B][S][1024]
__global__ __launch_bounds__(256, 2)
void attn_kernel(const u16* __restrict__ Q, const u16* __restrict__ Kg,
                 const u16* __restrict__ Vt, u16* __restrict__ O)
{
    const int bh = blockIdx.x;            // fastest -> XCD = bh % 8
    const int pr = blockIdx.y;            // 0..15
    const int qta = pr, qtb = 31 - pr;
    const int t = threadIdx.x, wave = t >> 6, lane = t & 63;
    const int lr = lane & 15, quad = lane >> 4;

    __shared__ __align__(16) u16 Ks[4096];        // [2][64][32]
    __shared__ __align__(16) u16 Vs[4096];        // [2][64][32]
    __shared__ __align__(16) u16 Ps[4][16*72];    // wave-private P round-trip

    const size_t qkbase = (size_t)bh * (S_LEN*HD);
    const int b = bh >> 4, h = bh & 15;
    u16* Pw = Ps[wave];
    const f32x4 fzero = {0.f, 0.f, 0.f, 0.f};

    const u16* qpa = Q + qkbase + (size_t)(qta*64 + wave*16 + lr)*HD + quad*8;
    const u16* qpb = Q + qkbase + (size_t)(qtb*64 + wave*16 + lr)*HD + quad*8;
    bf16x8 qa0 = *(const bf16x8*)qpa, qa1 = *(const bf16x8*)(qpa + 32);
    bf16x8 qb0 = *(const bf16x8*)qpb, qb1 = *(const bf16x8*)(qpb + 32);

    f32x4 oa[4], ob[4];
    float la[4], lb[4];
    #pragma unroll
    for (int dt = 0; dt < 4; ++dt) { oa[dt] = fzero; ob[dt] = fzero; }
    #pragma unroll
    for (int r = 0; r < 4; ++r) { la[r] = 0.f; lb[r] = 0.f; }

    const u16* gK = Kg + qkbase + (size_t)(wave*16 + (lane>>2))*HD + (lane&3)*8;
    const u16* gV = Vt + qkbase + (size_t)(wave*16 + (lane>>2))*S_LEN + (lane&3)*8;
    u16* lK = Ks + wave*512;
    u16* lV = Vs + wave*512;

    const int qrow_qa = qta*64 + wave*16 + quad*4;
    const int qrow_qb = qtb*64 + wave*16 + quad*4;

    for (int kb = 0; kb <= qtb; ++kb) {
        __syncthreads();
        load_lds16(gK + (size_t)kb*4096,      lK);
        load_lds16(gK + (size_t)kb*4096 + 32, lK + 2048);
        load_lds16(gV + kb*64,                lV);
        load_lds16(gV + kb*64 + 32,           lV + 2048);
        __syncthreads();

        #pragma unroll
        for (int tile = 0; tile < 2; ++tile) {
            const int qt = tile ? qta : qtb;
            if (tile && kb > qta) break;
            bf16x8 qf0 = tile ? qa0 : qb0;
            bf16x8 qf1 = tile ? qa1 : qb1;
            f32x4* oacc = tile ? oa : ob;
            float* lp   = tile ? la : lb;
            const int qrowq = tile ? qrow_qa : qrow_qb;

            f32x4 sc[4];
            #pragma unroll
            for (int kt2 = 0; kt2 < 4; ++kt2) {
                bf16x8 kf0 = *(const bf16x8*)&Ks[(kt2*16 + lr)*32 + quad*8];
                bf16x8 kf1 = *(const bf16x8*)&Ks[2048 + (kt2*16 + lr)*32 + quad*8];
                sc[kt2] = __builtin_amdgcn_mfma_f32_16x16x32_bf16(qf0, kf0, fzero, 0, 0, 0);
                sc[kt2] = __builtin_amdgcn_mfma_f32_16x16x32_bf16(qf1, kf1, sc[kt2], 0, 0, 0);
            }
            const bool diag = (kb == qt);
            #pragma unroll
            for (int r = 0; r < 4; ++r) {
                #pragma unroll
                for (int kt2 = 0; kt2 < 4; ++kt2) {
                    int kcol = kb*64 + kt2*16 + lr;
                    float p = (!diag || kcol <= qrowq + r) ? __expf(fminf(sc[kt2][r]*0.125f, 30.f)) : 0.f;
                    lp[r] += p;
                    Pw[(quad*4 + r)*72 + kt2*16 + lr] = f2b(p);
                }
            }
            bf16x8 pf0 = *(const bf16x8*)&Pw[lr*72 + quad*8];
            bf16x8 pf1 = *(const bf16x8*)&Pw[lr*72 + 32 + quad*8];
            #pragma unroll
            for (int dt = 0; dt < 4; ++dt) {
                bf16x8 vf0 = *(const bf16x8*)&Vs[(dt*16 + lr)*32 + quad*8];
                bf16x8 vf1 = *(const bf16x8*)&Vs[2048 + (dt*16 + lr)*32 + quad*8];
                oacc[dt] = __builtin_amdgcn_mfma_f32_16x16x32_bf16(pf0, vf0, oacc[dt], 0, 0, 0);
                oacc[dt] = __builtin_amdgcn_mfma_f32_16x16x32_bf16(pf1, vf1, oacc[dt], 0, 0, 0);
            }
        }
    }

    #pragma unroll
    for (int tile = 0; tile < 2; ++tile) {
        const int qt = tile ? qta : qtb;
        f32x4* oacc = tile ? oa : ob;
        float* lp   = tile ? la : lb;
        #pragma unroll
        for (int r = 0; r < 4; ++r) {
            float v = lp[r];
            v += __shfl_xor(v, 1, 64); v += __shfl_xor(v, 2, 64);
            v += __shfl_xor(v, 4, 64); v += __shfl_xor(v, 8, 64);
            lp[r] = 1.0f / fmaxf(v, 1e-20f);
        }
        #pragma unroll
        for (int dt = 0; dt < 4; ++dt)
            #pragma unroll
            for (int r = 0; r < 4; ++r)
                Pw[(quad*4 + r)*64 + dt*16 + lr] = f2b(oacc[dt][r] * lp[r]);

        const int q = lane >> 2, d0 = (lane & 3)*16;
        u16* dst = O + ((size_t)(b*S_LEN + qt*64 + wave*16 + q))*EMB + h*HD + d0;
        *(uint4*)(dst)     = *(uint4*)&Pw[q*64 + d0];
        *(uint4*)(dst + 8) = *(uint4*)&Pw[q*64 + d0 + 8];
    }
}

// ---------------------------------------------------------------- launch
extern "C" void kernel_launch(void* const* d_in, const int* in_sizes, int n_in,
                              void* d_out, int out_size, void* d_ws, size_t ws_size,
                              hipStream_t stream)
{
    (void)in_sizes; (void)n_in; (void)out_size; (void)ws_size;
    const float* x    = (const float*)d_in[0];
    // d_in[1] = mask: causal tril, handled analytically
    const float* ln1g = (const float*)d_in[2];
    const float* ln1b = (const float*)d_in[3];
    const float* wq = (const float*)d_in[4];  const float* bq = (const float*)d_in[5];
    const float* wk = (const float*)d_in[6];  const float* bk = (const float*)d_in[7];
    const float* wv = (const float*)d_in[8];  const float* bv = (const float*)d_in[9];
    const float* wo = (const float*)d_in[10]; const float* bo = (const float*)d_in[11];
    const float* ln2g = (const float*)d_in[12]; const float* ln2b = (const float*)d_in[13];
    const float* w1 = (const float*)d_in[14]; const float* b1 = (const float*)d_in[15];
    const float* w2 = (const float*)d_in[16]; const float* b2 = (const float*)d_in[17];

    u16* ws = (u16*)d_ws;
    const size_t M1 = 1u << 20;             // 1M u16 elements (2 MB)
    u16* wqkvT = ws + 0*M1;                 // bf16 [3072][1024] = wqT|wkT|wvT contiguous
    u16* wqT = ws + 0*M1;
    u16* wkT = ws + 1*M1;
    u16* wvT = ws + 2*M1;
    u16* woT = ws + 3*M1;
    u16* w2T = ws + 0*M1;                   // bf16 [1024][4096], transposed AFTER wo-gemm
    u16* w1T = ws + 4*M1;                   // bf16 [4096][1024]
    u16* h0  = ws + 8*M1;                   // bf16 ln out (reused for ln2 out)
    u16* qb  = ws + 12*M1;                  // bf16 [B,H,S,D]
    u16* kb  = ws + 16*M1;                  // bf16 [B,H,S,D]
    u16* vT  = ws + 20*M1;                  // bf16 [B,H,D,S]
    u16* ao  = ws + 24*M1;                  // bf16 attn out [B,S,E]
    u16* vb  = ws + 24*M1;                  // bf16 V [B,H,S,D] (dead before attn writes ao)
    u16* x1  = ws + 28*M1;                  // bf16 residual-1 out
    u16* fb  = ws + 12*M1;                  // bf16 MLP hidden, overlays q/k/v/ao (dead)
    u16* wosl = ws + 8*M1;                  // wo split-K: 4 bf16 slabs over dead h0/qb/kb/vT (8..24M1)
    u16* ffsl_lo = ws + 4*M1;               // ff2 split-K slabs 0,1 over dead w1T/h0 (4..12M1)
    u16* ffsl_hi = ws + 20*M1;              // ff2 split-K slabs 2,3 over dead vT/ao (20..28M1)

    dim3 blk(256);
    transpose_k<<<dim3(16,16), blk, 0, stream>>>(wq, wqT, EMB, EMB);
    transpose_k<<<dim3(16,16), blk, 0, stream>>>(wk, wkT, EMB, EMB);
    transpose_k<<<dim3(16,16), blk, 0, stream>>>(wv, wvT, EMB, EMB);
    transpose_k<<<dim3(16,16), blk, 0, stream>>>(wo, woT, EMB, EMB);
    transpose_k<<<dim3(64,16), blk, 0, stream>>>(w1, w1T, EMB, FF_DIM);

    ln_kernel<1><<<NROWS, blk, 0, stream>>>(x, ln1g, ln1b, h0);

    // fused QKV: 256^2 8-phase kernel, grid = (3072/256, 4096/256)
    gemm256<5><<<dim3(12,16), dim3(512), 0, stream>>>(h0, wqkvT, bq, bk, bv,
                                                      qb, kb, vb, NROWS, 3072, EMB);

    vtrans<<<dim3(32,32), blk, 0, stream>>>(vb, vT);

    attn_kernel<<<dim3(32,16), blk, 0, stream>>>(qb, kb, vT, ao);

    // wo projection: split-K=4 gemm256 (256 blocks = 1/CU), partials in dead 8..24M1
    gemm256sk<<<dim3(4,16,4), dim3(512), 0, stream>>>(ao, woT, wosl, wosl + 8*M1, EMB, EMB);
    reduce_wo<<<2048, blk, 0, stream>>>(wosl, wosl + 8*M1, x, bo, x1);

    transpose_k<<<dim3(16,64), blk, 0, stream>>>(w2, w2T, FF_DIM, EMB);

    ln_kernel<0><<<NROWS, blk, 0, stream>>>(x1, ln2g, ln2b, h0);

    // FF1 (gelu): 256^2 8-phase kernel, grid = (4096/256, 4096/256)
    gemm256<2><<<dim3(16,16), dim3(512), 0, stream>>>(h0, w1T, b1, nullptr, nullptr,
                                                      fb, nullptr, nullptr, NROWS, FF_DIM, EMB);

    // FF2: split-K=4, all 4 slabs in dead ws regions; single fused reduce writes d_out
    gemm256sk<<<dim3(4,16,4), dim3(512), 0, stream>>>(fb, w2T, ffsl_lo, ffsl_hi, EMB, FF_DIM);
    reduce_ff2<<<2048, blk, 0, stream>>>(ffsl_lo, ffsl_hi, x1, b2, (float*)d_out);
}

// Round 9
// 351.122 us; speedup vs baseline: 1.1955x; 1.0358x over previous
//
#include <hip/hip_runtime.h>

typedef unsigned short u16;
typedef unsigned int   u32;
typedef __attribute__((ext_vector_type(8))) short bf16x8;   // 8 bf16 in 4 VGPRs
typedef __attribute__((ext_vector_type(4))) float f32x4;

#define S_LEN 2048
#define EMB   1024
#define NH    16
#define HD    64
#define FF_DIM 4096
#define NROWS 4096   // B*S

__device__ __forceinline__ float b2f(u16 u){ union{u32 i; float f;} c; c.i = ((u32)u)<<16; return c.f; }
// round-half-up bf16 pack: 2 VALU ops (vs 5 for RNE); differs from RNE only on exact ties
__device__ __forceinline__ u16 f2b(float f){ union{float f; u32 u;} c; c.f=f; return (u16)((c.u + 0x8000u)>>16); }
// fast erf-based gelu: A&S 7.1.26 poly, |eps_erf| ~1.5e-7 (invisible after bf16 round)
__device__ __forceinline__ float gelu_f(float x){
    float z  = x * 0.70710678118f;
    float az = fabsf(z);
    float t  = 1.0f / (1.0f + 0.3275911f * az);
    float p  = ((((1.061405429f*t - 1.453152027f)*t + 1.421413741f)*t - 0.284496736f)*t + 0.254829592f)*t;
    float e  = __expf(-az*az);
    float erfv = 1.0f - p*e;
    erfv = (z < 0.f) ? -erfv : erfv;
    return 0.5f*x*(1.0f + erfv);
}

// async global->LDS, 16B per lane; lds dest = wave-uniform base + lane*16 (m97/m104)
__device__ __forceinline__ void load_lds16(const u16* g, u16* l) {
    __builtin_amdgcn_global_load_lds((const __attribute__((address_space(1))) u32*)g,
                                     (__attribute__((address_space(3))) u32*)l, 16, 0, 0);
}

// ---------------------------------------------------------------- LayerNorm (ln1 only; ln2 fused into red_wo_ln2)
template<int XF32>
__global__ __launch_bounds__(256)
void ln_kernel(const void* __restrict__ Xv, const float* __restrict__ G,
               const float* __restrict__ Bv, u16* __restrict__ Y)
{
    const int row = blockIdx.x, t = threadIdx.x;
    float v0, v1, v2, v3;
    if constexpr (XF32) {
        float4 r4 = ((const float4*)((const float*)Xv + (size_t)row*EMB))[t];
        v0 = r4.x; v1 = r4.y; v2 = r4.z; v3 = r4.w;
    } else {
        const u16* xr = (const u16*)Xv + (size_t)row*EMB;
        uint2 raw = *(const uint2*)(xr + t*4);
        v0 = b2f(raw.x & 0xffff); v1 = b2f(raw.x >> 16);
        v2 = b2f(raw.y & 0xffff); v3 = b2f(raw.y >> 16);
    }
    float s  = v0+v1+v2+v3;
    float s2 = v0*v0+v1*v1+v2*v2+v3*v3;
    #pragma unroll
    for (int off = 1; off < 64; off <<= 1) {
        s  += __shfl_xor(s,  off, 64);
        s2 += __shfl_xor(s2, off, 64);
    }
    __shared__ float ps[4], ps2[4];
    const int w = t >> 6, lane = t & 63;
    if (lane == 0) { ps[w] = s; ps2[w] = s2; }
    __syncthreads();
    s  = ps[0]+ps[1]+ps[2]+ps[3];
    s2 = ps2[0]+ps2[1]+ps2[2]+ps2[3];
    const float mu   = s * (1.0f/EMB);
    const float rstd = rsqrtf(fmaxf(s2*(1.0f/EMB) - mu*mu, 0.f) + 1e-5f);
    float4 g4 = ((const float4*)G)[t];
    float4 c4 = ((const float4*)Bv)[t];
    u32 lo = (u32)f2b((v0-mu)*rstd*g4.x + c4.x) | ((u32)f2b((v1-mu)*rstd*g4.y + c4.y) << 16);
    u32 hi = (u32)f2b((v2-mu)*rstd*g4.z + c4.z) | ((u32)f2b((v3-mu)*rstd*g4.w + c4.w) << 16);
    uint2 o; o.x = lo; o.y = hi;
    *(uint2*)(Y + (size_t)row*EMB + t*4) = o;
}

// ---------------------------------------------------------------- transpose+downconvert (f32 [K][N] -> bf16 [N][K])
__global__ __launch_bounds__(256)
void transpose_k(const float* __restrict__ in, u16* __restrict__ out, int K, int N)
{
    __shared__ __align__(16) u16 T[64*72];
    const int k0 = blockIdx.y*64, n0 = blockIdx.x*64, t = threadIdx.x;
    #pragma unroll
    for (int c = 0; c < 4; ++c) {
        int e = t*4 + c*1024, ki = e >> 6, nj = e & 63;
        float4 f = *(const float4*)(in + (size_t)(k0+ki)*N + n0 + nj);
        ushort4 s4; s4.x = f2b(f.x); s4.y = f2b(f.y); s4.z = f2b(f.z); s4.w = f2b(f.w);
        *(ushort4*)&T[ki*72 + nj] = s4;
    }
    __syncthreads();
    #pragma unroll
    for (int c = 0; c < 2; ++c) {
        int e = t*8 + c*2048, ni = e >> 6, kj = e & 63;
        uint4 v; u16* pv = (u16*)&v;
        #pragma unroll
        for (int j = 0; j < 8; ++j) pv[j] = T[(kj+j)*72 + ni];
        *(uint4*)(out + (size_t)(n0+ni)*K + k0 + kj) = v;
    }
}

// ---------------------------------------------------------------- batched weight transpose: wq,wk,wv,wo,w1 in ONE launch
// id<1024: square weight (id>>8), 16x16 tile grid. id>=1024: w1 (1024x4096 -> [4096][1024]).
// Outputs contiguous in ws: wqT|wkT|wvT|woT at 0..4M1, w1T at 4M1.
__global__ __launch_bounds__(256)
void transpose5(const float* __restrict__ wq, const float* __restrict__ wk,
                const float* __restrict__ wv, const float* __restrict__ wo,
                const float* __restrict__ w1, u16* __restrict__ out0)
{
    __shared__ __align__(16) u16 T[64*72];
    const int id = blockIdx.x, t = threadIdx.x;
    const float* in; u16* out; int K, N, n0, k0;
    if (id < 1024) {
        const int w = id >> 8, bid = id & 255;
        in  = (w==0) ? wq : (w==1) ? wk : (w==2) ? wv : wo;
        out = out0 + (size_t)w*(1u<<20);
        K = 1024; N = 1024;
        n0 = (bid & 15)*64; k0 = (bid >> 4)*64;
    } else {
        const int bid = id - 1024;
        in = w1; out = out0 + (size_t)4*(1u<<20);
        K = 1024; N = 4096;
        n0 = (bid & 63)*64; k0 = (bid >> 6)*64;
    }
    #pragma unroll
    for (int c = 0; c < 4; ++c) {
        int e = t*4 + c*1024, ki = e >> 6, nj = e & 63;
        float4 f = *(const float4*)(in + (size_t)(k0+ki)*N + n0 + nj);
        ushort4 s4; s4.x = f2b(f.x); s4.y = f2b(f.y); s4.z = f2b(f.z); s4.w = f2b(f.w);
        *(ushort4*)&T[ki*72 + nj] = s4;
    }
    __syncthreads();
    #pragma unroll
    for (int c = 0; c < 2; ++c) {
        int e = t*8 + c*2048, ni = e >> 6, kj = e & 63;
        uint4 v; u16* pv = (u16*)&v;
        #pragma unroll
        for (int j = 0; j < 8; ++j) pv[j] = T[(kj+j)*72 + ni];
        *(uint4*)(out + (size_t)(n0+ni)*K + k0 + kj) = v;
    }
}

// ---------------------------------------------------------------- bf16 transpose: V [B*H][S][64] -> V^T [B*H][64][S]
__global__ __launch_bounds__(256)
void vtrans(const u16* __restrict__ in, u16* __restrict__ out)
{
    __shared__ __align__(16) u16 T[64*72];
    const int bh = blockIdx.y, s0 = blockIdx.x*64, t = threadIdx.x;
    const size_t base = (size_t)bh * (S_LEN*HD);
    #pragma unroll
    for (int c = 0; c < 2; ++c) {
        int e = t*8 + c*2048, r = e >> 6, d = e & 63;
        *(uint4*)&T[r*72 + d] = *(const uint4*)(in + base + (size_t)(s0 + r)*HD + d);
    }
    __syncthreads();
    #pragma unroll
    for (int c = 0; c < 2; ++c) {
        int e = t*8 + c*2048, d = e >> 6, sj = e & 63;
        uint4 v; u16* pv = (u16*)&v;
        #pragma unroll
        for (int j = 0; j < 8; ++j) pv[j] = T[(sj + j)*72 + d];
        *(uint4*)(out + base + (size_t)d*S_LEN + s0 + sj) = v;
    }
}

// ================================================================ 256x256 8-phase GEMM  (r6 form)
// T2+T3+T4+T5 (m194-m201 template, plain HIP): 512 thr = 8 waves (2M x 4N), BK=64,
// LDS 128 KiB = 2 buf x {A,B} x 2 k-halves x [256 rows][32 k] bf16.
// Bank swizzle (T2): involution off ^= (off>>3)&0x18, BOTH sides (rule 21).
// Read-once quadrants (k-half x MF-half): 24 ds_read/K-tile (minimum).
// vmcnt discipline: ONE vmcnt(4) per K-tile at its LAST phase; at that point the entire
// next tile is forced-landed; every stage has >=4 phases issue->forced-land.
// NOTE: r7's fragment-prefetch variant and r5's 2-wait cadence were REAL-NEUTRAL
// (wall totals flat); profiled 2x swings were replay artifacts. Keeping simplest form.
__device__ __forceinline__ void stage2(const u16* s0, const u16* s1, int koff, u16* dst, int wave){
    load_lds16(s0 + koff, dst + wave*512);
    load_lds16(s1 + koff, dst + 4096 + wave*512);
}

template<int CBUF, int KS, int MFH, int TAILVM>
__device__ __forceinline__ void phase256(u16* Ls, f32x4 (&acc)[8][4], bf16x8 (&bf)[4],
    int wm, int wn, int lr, int quad, int wave,
    const u16* s0, const u16* s1, int koff, u16* dst)
{
    const u16* ak = Ls + CBUF*32768 + KS*8192;
    const u16* bk = Ls + CBUF*32768 + 16384 + KS*8192;
    bf16x8 af[4];
    #pragma unroll
    for (int i = 0; i < 4; ++i) {
        int off = (wm*128 + (MFH*4 + i)*16 + lr)*32 + quad*8;
        af[i] = *(const bf16x8*)(ak + (off ^ ((off>>3)&0x18)));
    }
    if constexpr (MFH == 0) {
        #pragma unroll
        for (int nf = 0; nf < 4; ++nf) {
            int off = (wn*64 + nf*16 + lr)*32 + quad*8;
            bf[nf] = *(const bf16x8*)(bk + (off ^ ((off>>3)&0x18)));
        }
    }
    stage2(s0, s1, koff, dst, wave);
    __builtin_amdgcn_s_barrier();
    asm volatile("s_waitcnt lgkmcnt(0)" ::: "memory");
    __builtin_amdgcn_s_setprio(1);
    #pragma unroll
    for (int i = 0; i < 4; ++i)
        #pragma unroll
        for (int nf = 0; nf < 4; ++nf)
            acc[MFH*4 + i][nf] = __builtin_amdgcn_mfma_f32_16x16x32_bf16(af[i], bf[nf], acc[MFH*4 + i][nf], 0, 0, 0);
    __builtin_amdgcn_s_setprio(0);
    if constexpr (TAILVM) asm volatile("s_waitcnt vmcnt(4)" ::: "memory");
    __builtin_amdgcn_s_barrier();
}

// shared main loop: runs the 8-phase pipeline over NT K-tiles starting at srcA/B (already K-offset)
__device__ __forceinline__ void gemm256_main(u16* Ls, f32x4 (&acc)[8][4],
    int wm, int wn, int lr, int quad, int wave, int NT,
    const u16* srcA0, const u16* srcA1, const u16* srcB0, const u16* srcB1)
{
    u16* A00 = Ls + 0;
    u16* A01 = Ls + 8192;
    u16* B00 = Ls + 16384;
    u16* B01 = Ls + 16384 + 8192;
    u16* A10 = Ls + 32768;
    u16* A11 = Ls + 32768 + 8192;
    u16* B10 = Ls + 32768 + 16384;
    u16* B11 = Ls + 32768 + 16384 + 8192;

    // prologue: tile0 {Akh0,Bkh0,Akh1,Bkh1}, tile1 {Akh0,Bkh0} = 12 loads (2/stage)
    stage2(srcA0, srcA1, 0,   A00, wave);
    stage2(srcB0, srcB1, 0,   B00, wave);
    stage2(srcA0, srcA1, 32,  A01, wave);
    stage2(srcB0, srcB1, 32,  B01, wave);
    stage2(srcA0, srcA1, 64,  A10, wave);
    stage2(srcB0, srcB1, 64,  B10, wave);
    asm volatile("s_waitcnt vmcnt(4)" ::: "memory");   // tile0 fully resident
    __builtin_amdgcn_s_barrier();

    bf16x8 bf[4];
    for (int U = 0; U < NT; U += 2) {
        const int k1 = ((U+1) & (NT-1))*64;
        const int k2 = ((U+2) & (NT-1))*64;   // wraps at tail: redundant-but-safe reload
        const int k3 = ((U+3) & (NT-1))*64;
        // tile U (buf0): stage targets free'd >=1 barrier earlier (per-slot WAR audit r6)
        phase256<0,0,0,0>(Ls, acc, bf, wm, wn, lr, quad, wave, srcA0, srcA1, k1+32, A11);
        phase256<0,0,1,0>(Ls, acc, bf, wm, wn, lr, quad, wave, srcB0, srcB1, k1+32, B11);
        phase256<0,1,0,0>(Ls, acc, bf, wm, wn, lr, quad, wave, srcA0, srcA1, k2,    A00);
        phase256<0,1,1,1>(Ls, acc, bf, wm, wn, lr, quad, wave, srcB0, srcB1, k2,    B00);
        // tile U+1 (buf1)
        phase256<1,0,0,0>(Ls, acc, bf, wm, wn, lr, quad, wave, srcA0, srcA1, k2+32, A01);
        phase256<1,0,1,0>(Ls, acc, bf, wm, wn, lr, quad, wave, srcB0, srcB1, k2+32, B01);
        phase256<1,1,0,0>(Ls, acc, bf, wm, wn, lr, quad, wave, srcA0, srcA1, k3,    A10);
        phase256<1,1,1,1>(Ls, acc, bf, wm, wn, lr, quad, wave, srcB0, srcB1, k3,    B10);
    }

    // drain ALL DMAs (incl. wrapped tail stages) before repurposing LDS
    asm volatile("s_waitcnt vmcnt(0)" ::: "memory");
    __syncthreads();
}

// MODE 2: gelu -> bf16 C.   MODE 5: fused QKV head-split scatter (C=Q, C2=K, C3=V).
template<int MODE>
__global__ __launch_bounds__(512, 2)
void gemm256(const u16* __restrict__ A, const u16* __restrict__ Bt,
             const float* __restrict__ bias, const float* __restrict__ bias2,
             const float* __restrict__ bias3,
             void* __restrict__ C, void* __restrict__ C2, void* __restrict__ C3,
             int M, int N, int K)
{
    (void)M;
    __shared__ __align__(16) u16 Ls[65536];     // 128 KiB
    const int t = threadIdx.x;
    const int wave = t >> 6, lane = t & 63;
    const int wm = wave >> 2, wn = wave & 3;    // 2 x 4 wave grid
    const int lr = lane & 15, quad = lane >> 4;
    const int n0 = blockIdx.x*256, m0 = blockIdx.y*256;

    // per-lane pre-swizzled global sources: phys chunk c (16B) <- logical chunk c^((c>>3)&3)
    const int c0 = wave*64 + lane, c1 = 512 + wave*64 + lane;
    const int l0 = c0 ^ ((c0 >> 3) & 3), l1 = c1 ^ ((c1 >> 3) & 3);
    const int r0 = l0 >> 2, g0 = l0 & 3;
    const int r1 = l1 >> 2, g1 = l1 & 3;
    const u16* srcA0 = A  + (size_t)(m0 + r0)*K + g0*8;
    const u16* srcA1 = A  + (size_t)(m0 + r1)*K + g1*8;
    const u16* srcB0 = Bt + (size_t)(n0 + r0)*K + g0*8;
    const u16* srcB1 = Bt + (size_t)(n0 + r1)*K + g1*8;

    f32x4 acc[8][4];
    const f32x4 fzero = {0.f, 0.f, 0.f, 0.f};
    #pragma unroll
    for (int i = 0; i < 8; ++i)
        #pragma unroll
        for (int j = 0; j < 4; ++j) acc[i][j] = fzero;

    gemm256_main(Ls, acc, wm, wn, lr, quad, wave, K >> 6, srcA0, srcA1, srcB0, srcB1);

    // ---------------- epilogue: bias(+gelu), stage [256][256] bf16 in LDS, coalesced stores
    float bv[4];
    #pragma unroll
    for (int nf = 0; nf < 4; ++nf) {
        const int col = n0 + wn*64 + nf*16 + lr;
        if constexpr (MODE == 5) {
            const int seg = n0 >> 10;    // 256 | 1024: no straddle
            bv[nf] = (seg == 0 ? bias : (seg == 1 ? bias2 : bias3))[col & 1023];
        } else {
            bv[nf] = bias[col];
        }
    }
    #pragma unroll
    for (int mf = 0; mf < 8; ++mf)
        #pragma unroll
        for (int nf = 0; nf < 4; ++nf)
            #pragma unroll
            for (int r = 0; r < 4; ++r) {
                float v = acc[mf][nf][r] + bv[nf];
                if constexpr (MODE == 2) v = gelu_f(v);
                Ls[(wm*128 + mf*16 + quad*4 + r)*256 + wn*64 + nf*16 + lr] = f2b(v);
            }
    __syncthreads();
    // 256x256 u16 = 8192 16B-chunks; 512 threads x 16 iters
    #pragma unroll
    for (int j = 0; j < 16; ++j) {
        const int idx = j*512 + t;
        const int rr = idx >> 5, ck = idx & 31;
        const u16* src = Ls + rr*256 + ck*8;
        const int row = m0 + rr, col = n0 + ck*8;
        if constexpr (MODE == 5) {
            const int seg = n0 >> 10;
            u16* dstb = (u16*)(seg == 0 ? C : (seg == 1 ? C2 : C3));
            const int cs = col & 1023;
            const int h = cs >> 6, d = cs & 63;
            const int b_ = row >> 11, s = row & 2047;
            *(uint4*)(dstb + ((((size_t)(b_*NH + h))*S_LEN + s) << 6) + d) = *(const uint4*)src;
        } else {
            *(uint4*)((u16*)C + (size_t)row*N + col) = *(const uint4*)src;
        }
    }
}

// ================================================================ split-K=4 variant
// grid (N/256, M/256, 4): z = K-split. Writes RAW bf16 partial (no bias) to slab
// (z<2 ? Cl : Ch) + (z&1)*M*N. Fills all 256 CUs for narrow-N deep-K GEMMs (wo, FF2).
__global__ __launch_bounds__(512, 2)
void gemm256sk(const u16* __restrict__ A, const u16* __restrict__ Bt,
               u16* __restrict__ Cl, u16* __restrict__ Ch, int N, int K)
{
    __shared__ __align__(16) u16 Ls[65536];
    const int t = threadIdx.x;
    const int wave = t >> 6, lane = t & 63;
    const int wm = wave >> 2, wn = wave & 3;
    const int lr = lane & 15, quad = lane >> 4;
    const int n0 = blockIdx.x*256, m0 = blockIdx.y*256;
    const int z  = blockIdx.z;
    const int Ks = K >> 2;                       // K-slice per split

    const int c0 = wave*64 + lane, c1 = 512 + wave*64 + lane;
    const int l0 = c0 ^ ((c0 >> 3) & 3), l1 = c1 ^ ((c1 >> 3) & 3);
    const int r0 = l0 >> 2, g0 = l0 & 3;
    const int r1 = l1 >> 2, g1 = l1 & 3;
    const u16* srcA0 = A  + (size_t)(m0 + r0)*K + g0*8 + z*Ks;
    const u16* srcA1 = A  + (size_t)(m0 + r1)*K + g1*8 + z*Ks;
    const u16* srcB0 = Bt + (size_t)(n0 + r0)*K + g0*8 + z*Ks;
    const u16* srcB1 = Bt + (size_t)(n0 + r1)*K + g1*8 + z*Ks;

    f32x4 acc[8][4];
    const f32x4 fzero = {0.f, 0.f, 0.f, 0.f};
    #pragma unroll
    for (int i = 0; i < 8; ++i)
        #pragma unroll
        for (int j = 0; j < 4; ++j) acc[i][j] = fzero;

    gemm256_main(Ls, acc, wm, wn, lr, quad, wave, Ks >> 6, srcA0, srcA1, srcB0, srcB1);

    // epilogue: raw bf16 partial, linear [M][N]
    #pragma unroll
    for (int mf = 0; mf < 8; ++mf)
        #pragma unroll
        for (int nf = 0; nf < 4; ++nf)
            #pragma unroll
            for (int r = 0; r < 4; ++r)
                Ls[(wm*128 + mf*16 + quad*4 + r)*256 + wn*64 + nf*16 + lr] = f2b(acc[mf][nf][r]);
    __syncthreads();
    u16* dst = (z < 2 ? Cl : Ch) + (size_t)(z & 1)*(1u<<22);   // slab stride M*N = 2^22
    #pragma unroll
    for (int j = 0; j < 16; ++j) {
        const int idx = j*512 + t;
        const int rr = idx >> 5, ck = idx & 31;
        *(uint4*)(dst + (size_t)(m0 + rr)*N + n0 + ck*8) = *(const uint4*)(Ls + rr*256 + ck*8);
    }
}

// ---------------------------------------------------------------- fused wo-reduce + LN2
// Per row: y = p0+p1+p2+p3 + bias + x_res(f32); write x1=bf16(y); LN(y) -> h0.
// Writes are same-thread same-element over dead slabs -> race-free. LN uses
// unrounded f32 y (closer to reference than the old rounded-x1 path).
__global__ __launch_bounds__(256)
void red_wo_ln2(const u16* __restrict__ pl, const u16* __restrict__ ph,
                const float* __restrict__ xres, const float* __restrict__ bias,
                const float* __restrict__ G, const float* __restrict__ Bv,
                u16* __restrict__ x1, u16* __restrict__ h0)
{
    const int row = blockIdx.x, t = threadIdx.x;
    const int i0 = row*EMB + t*4;
    uint2 a0 = *(const uint2*)(pl + i0);
    uint2 a1 = *(const uint2*)(pl + (1u<<22) + i0);
    uint2 a2 = *(const uint2*)(ph + i0);
    uint2 a3 = *(const uint2*)(ph + (1u<<22) + i0);
    float4 bb = *(const float4*)(bias + t*4);
    float4 xx = *(const float4*)(xres + i0);
    const u16 *q0=(const u16*)&a0, *q1=(const u16*)&a1, *q2=(const u16*)&a2, *q3=(const u16*)&a3;
    const float* bp = (const float*)&bb;
    const float* xp = (const float*)&xx;
    float y[4];
    #pragma unroll
    for (int j = 0; j < 4; ++j)
        y[j] = b2f(q0[j]) + b2f(q1[j]) + b2f(q2[j]) + b2f(q3[j]) + bp[j] + xp[j];
    u16 o16[4];
    #pragma unroll
    for (int j = 0; j < 4; ++j) o16[j] = f2b(y[j]);
    *(uint2*)(x1 + i0) = *(const uint2*)o16;

    float s  = y[0]+y[1]+y[2]+y[3];
    float s2 = y[0]*y[0]+y[1]*y[1]+y[2]*y[2]+y[3]*y[3];
    #pragma unroll
    for (int off = 1; off < 64; off <<= 1) {
        s  += __shfl_xor(s,  off, 64);
        s2 += __shfl_xor(s2, off, 64);
    }
    __shared__ float ps[4], ps2[4];
    const int w = t >> 6, lane = t & 63;
    if (lane == 0) { ps[w] = s; ps2[w] = s2; }
    __syncthreads();
    s  = ps[0]+ps[1]+ps[2]+ps[3];
    s2 = ps2[0]+ps2[1]+ps2[2]+ps2[3];
    const float mu   = s * (1.0f/EMB);
    const float rstd = rsqrtf(fmaxf(s2*(1.0f/EMB) - mu*mu, 0.f) + 1e-5f);
    float4 g4 = *(const float4*)(G + t*4);
    float4 c4 = *(const float4*)(Bv + t*4);
    const float* gp = (const float*)&g4;
    const float* cp = (const float*)&c4;
    u16 h16[4];
    #pragma unroll
    for (int j = 0; j < 4; ++j) h16[j] = f2b((y[j]-mu)*rstd*gp[j] + cp[j]);
    *(uint2*)(h0 + i0) = *(const uint2*)h16;
}

// ff2 fused reduce: out_f32 = (p0+p1+p2+p3) + bias[col] + x1_bf16.
// All 4 slabs live in ws (dead regions), d_out written fresh -> race-free single pass.
__global__ __launch_bounds__(256)
void reduce_ff2(const u16* __restrict__ pl, const u16* __restrict__ ph,
                const u16* __restrict__ x1b, const float* __restrict__ bias,
                float* __restrict__ out)
{
    const int i0 = (blockIdx.x*256 + threadIdx.x)*8;
    uint4 a0 = *(const uint4*)(pl + i0);
    uint4 a1 = *(const uint4*)(pl + (1u<<22) + i0);
    uint4 a2 = *(const uint4*)(ph + i0);
    uint4 a3 = *(const uint4*)(ph + (1u<<22) + i0);
    uint4 xr = *(const uint4*)(x1b + i0);
    const int col = i0 & 1023;
    float4 b0 = *(const float4*)(bias + col);
    float4 b1 = *(const float4*)(bias + col + 4);
    const u16 *q0=(const u16*)&a0, *q1=(const u16*)&a1, *q2=(const u16*)&a2, *q3=(const u16*)&a3;
    const u16 *xp=(const u16*)&xr;
    const float bb[8] = {b0.x,b0.y,b0.z,b0.w,b1.x,b1.y,b1.z,b1.w};
    float f[8];
    #pragma unroll
    for (int j = 0; j < 8; ++j)
        f[j] = b2f(q0[j]) + b2f(q1[j]) + b2f(q2[j]) + b2f(q3[j]) + b2f(xp[j]) + bb[j];
    float4 o0 = {f[0],f[1],f[2],f[3]}, o1 = {f[4],f[5],f[6],f[7]};
    *(float4*)(out + i0) = o0;
    *(float4*)(out + i0 + 4) = o1;
}

// ---------------------------------------------------------------- attention (causal)
// Grid (bh fastest): XCD-local KV. Block handles pair {pr, 31-pr}; ONE merged K-loop
// stages each K/V tile once via global_load_lds (shared by 4 waves) and feeds up to
// two Q-tiles. LDS layout [k-half][row][32] keeps the m97 64-B-stride fragment reads.
// Q,K: [B*H][S][64]; Vt: [B*H][64][S]; O: [B][S][1024]
__global__ __launch_bounds__(256, 2)
void attn_kernel(const u16* __restrict__ Q, const u16* __restrict__ Kg,
                 const u16* __restrict__ Vt, u16* __restrict__ O)
{
    const int bh = blockIdx.x;            // fastest -> XCD = bh % 8
    const int pr = blockIdx.y;            // 0..15
    const int qta = pr, qtb = 31 - pr;
    const int t = threadIdx.x, wave = t >> 6, lane = t & 63;
    const int lr = lane & 15, quad = lane >> 4;

    __shared__ __align__(16) u16 Ks[4096];        // [2][64][32]
    __shared__ __align__(16) u16 Vs[4096];        // [2][64][32]
    __shared__ __align__(16) u16 Ps[4][16*72];    // wave-private P round-trip

    const size_t qkbase = (size_t)bh * (S_LEN*HD);
    const int b = bh >> 4, h = bh & 15;
    u16* Pw = Ps[wave];
    const f32x4 fzero = {0.f, 0.f, 0.f, 0.f};

    const u16* qpa = Q + qkbase + (size_t)(qta*64 + wave*16 + lr)*HD + quad*8;
    const u16* qpb = Q + qkbase + (size_t)(qtb*64 + wave*16 + lr)*HD + quad*8;
    bf16x8 qa0 = *(const bf16x8*)qpa, qa1 = *(const bf16x8*)(qpa + 32);
    bf16x8 qb0 = *(const bf16x8*)qpb, qb1 = *(const bf16x8*)(qpb + 32);

    f32x4 oa[4], ob[4];
    float la[4], lb[4];
    #pragma unroll
    for (int dt = 0; dt < 4; ++dt) { oa[dt] = fzero; ob[dt] = fzero; }
    #pragma unroll
    for (int r = 0; r < 4; ++r) { la[r] = 0.f; lb[r] = 0.f; }

    const u16* gK = Kg + qkbase + (size_t)(wave*16 + (lane>>2))*HD + (lane&3)*8;
    const u16* gV = Vt + qkbase + (size_t)(wave*16 + (lane>>2))*S_LEN + (lane&3)*8;
    u16* lK = Ks + wave*512;
    u16* lV = Vs + wave*512;

    const int qrow_qa = qta*64 + wave*16 + quad*4;
    const int qrow_qb = qtb*64 + wave*16 + quad*4;

    for (int kb = 0; kb <= qtb; ++kb) {
        __syncthreads();
        load_lds16(gK + (size_t)kb*4096,      lK);
        load_lds16(gK + (size_t)kb*4096 + 32, lK + 2048);
        load_lds16(gV + kb*64,                lV);
        load_lds16(gV + kb*64 + 32,           lV + 2048);
        __syncthreads();

        #pragma unroll
        for (int tile = 0; tile < 2; ++tile) {
            const int qt = tile ? qta : qtb;
            if (tile && kb > qta) break;
            bf16x8 qf0 = tile ? qa0 : qb0;
            bf16x8 qf1 = tile ? qa1 : qb1;
            f32x4* oacc = tile ? oa : ob;
            float* lp   = tile ? la : lb;
            const int qrowq = tile ? qrow_qa : qrow_qb;

            f32x4 sc[4];
            #pragma unroll
            for (int kt2 = 0; kt2 < 4; ++kt2) {
                bf16x8 kf0 = *(const bf16x8*)&Ks[(kt2*16 + lr)*32 + quad*8];
                bf16x8 kf1 = *(const bf16x8*)&Ks[2048 + (kt2*16 + lr)*32 + quad*8];
                sc[kt2] = __builtin_amdgcn_mfma_f32_16x16x32_bf16(qf0, kf0, fzero, 0, 0, 0);
                sc[kt2] = __builtin_amdgcn_mfma_f32_16x16x32_bf16(qf1, kf1, sc[kt2], 0, 0, 0);
            }
            const bool diag = (kb == qt);
            #pragma unroll
            for (int r = 0; r < 4; ++r) {
                #pragma unroll
                for (int kt2 = 0; kt2 < 4; ++kt2) {
                    int kcol = kb*64 + kt2*16 + lr;
                    float p = (!diag || kcol <= qrowq + r) ? __expf(fminf(sc[kt2][r]*0.125f, 30.f)) : 0.f;
                    lp[r] += p;
                    Pw[(quad*4 + r)*72 + kt2*16 + lr] = f2b(p);
                }
            }
            bf16x8 pf0 = *(const bf16x8*)&Pw[lr*72 + quad*8];
            bf16x8 pf1 = *(const bf16x8*)&Pw[lr*72 + 32 + quad*8];
            #pragma unroll
            for (int dt = 0; dt < 4; ++dt) {
                bf16x8 vf0 = *(const bf16x8*)&Vs[(dt*16 + lr)*32 + quad*8];
                bf16x8 vf1 = *(const bf16x8*)&Vs[2048 + (dt*16 + lr)*32 + quad*8];
                oacc[dt] = __builtin_amdgcn_mfma_f32_16x16x32_bf16(pf0, vf0, oacc[dt], 0, 0, 0);
                oacc[dt] = __builtin_amdgcn_mfma_f32_16x16x32_bf16(pf1, vf1, oacc[dt], 0, 0, 0);
            }
        }
    }

    #pragma unroll
    for (int tile = 0; tile < 2; ++tile) {
        const int qt = tile ? qta : qtb;
        f32x4* oacc = tile ? oa : ob;
        float* lp   = tile ? la : lb;
        #pragma unroll
        for (int r = 0; r < 4; ++r) {
            float v = lp[r];
            v += __shfl_xor(v, 1, 64); v += __shfl_xor(v, 2, 64);
            v += __shfl_xor(v, 4, 64); v += __shfl_xor(v, 8, 64);
            lp[r] = 1.0f / fmaxf(v, 1e-20f);
        }
        #pragma unroll
        for (int dt = 0; dt < 4; ++dt)
            #pragma unroll
            for (int r = 0; r < 4; ++r)
                Pw[(quad*4 + r)*64 + dt*16 + lr] = f2b(oacc[dt][r] * lp[r]);

        const int q = lane >> 2, d0 = (lane & 3)*16;
        u16* dst = O + ((size_t)(b*S_LEN + qt*64 + wave*16 + q))*EMB + h*HD + d0;
        *(uint4*)(dst)     = *(uint4*)&Pw[q*64 + d0];
        *(uint4*)(dst + 8) = *(uint4*)&Pw[q*64 + d0 + 8];
    }
}

// ---------------------------------------------------------------- launch
extern "C" void kernel_launch(void* const* d_in, const int* in_sizes, int n_in,
                              void* d_out, int out_size, void* d_ws, size_t ws_size,
                              hipStream_t stream)
{
    (void)in_sizes; (void)n_in; (void)out_size; (void)ws_size;
    const float* x    = (const float*)d_in[0];
    // d_in[1] = mask: causal tril, handled analytically
    const float* ln1g = (const float*)d_in[2];
    const float* ln1b = (const float*)d_in[3];
    const float* wq = (const float*)d_in[4];  const float* bq = (const float*)d_in[5];
    const float* wk = (const float*)d_in[6];  const float* bk = (const float*)d_in[7];
    const float* wv = (const float*)d_in[8];  const float* bv = (const float*)d_in[9];
    const float* wo = (const float*)d_in[10]; const float* bo = (const float*)d_in[11];
    const float* ln2g = (const float*)d_in[12]; const float* ln2b = (const float*)d_in[13];
    const float* w1 = (const float*)d_in[14]; const float* b1 = (const float*)d_in[15];
    const float* w2 = (const float*)d_in[16]; const float* b2 = (const float*)d_in[17];

    u16* ws = (u16*)d_ws;
    const size_t M1 = 1u << 20;             // 1M u16 elements (2 MB)
    u16* wqkvT = ws + 0*M1;                 // bf16 [3072][1024] = wqT|wkT|wvT contiguous
    u16* woT = ws + 3*M1;
    u16* w2T = ws + 0*M1;                   // bf16 [1024][4096], transposed AFTER wo-gemm
    u16* w1T = ws + 4*M1;                   // bf16 [4096][1024]
    u16* h0  = ws + 8*M1;                   // bf16 ln out (reused for ln2 out)
    u16* qb  = ws + 12*M1;                  // bf16 [B,H,S,D]
    u16* kb  = ws + 16*M1;                  // bf16 [B,H,S,D]
    u16* vT  = ws + 20*M1;                  // bf16 [B,H,D,S]
    u16* ao  = ws + 24*M1;                  // bf16 attn out [B,S,E]
    u16* vb  = ws + 24*M1;                  // bf16 V [B,H,S,D] (dead before attn writes ao)
    u16* x1  = ws + 28*M1;                  // bf16 residual-1 out
    u16* fb  = ws + 12*M1;                  // bf16 MLP hidden, overlays q/k/v/ao (dead)
    u16* wosl = ws + 8*M1;                  // wo split-K: 4 bf16 slabs over dead h0/qb/kb/vT (8..24M1)
    u16* ffsl_lo = ws + 4*M1;               // ff2 split-K slabs 0,1 over dead w1T/h0 (4..12M1)
    u16* ffsl_hi = ws + 20*M1;              // ff2 split-K slabs 2,3 over dead vT/ao (20..28M1)

    dim3 blk(256);
    // all 5 weight transposes in ONE launch: wq,wk,wv,wo -> 0..4M1, w1 -> 4M1
    transpose5<<<2048, blk, 0, stream>>>(wq, wk, wv, wo, w1, ws);

    ln_kernel<1><<<NROWS, blk, 0, stream>>>(x, ln1g, ln1b, h0);

    // fused QKV: 256^2 8-phase kernel, grid = (3072/256, 4096/256)
    gemm256<5><<<dim3(12,16), dim3(512), 0, stream>>>(h0, wqkvT, bq, bk, bv,
                                                      qb, kb, vb, NROWS, 3072, EMB);

    vtrans<<<dim3(32,32), blk, 0, stream>>>(vb, vT);

    attn_kernel<<<dim3(32,16), blk, 0, stream>>>(qb, kb, vT, ao);

    // wo projection: split-K=4 gemm256 (256 blocks = 1/CU), partials in dead 8..24M1
    gemm256sk<<<dim3(4,16,4), dim3(512), 0, stream>>>(ao, woT, wosl, wosl + 8*M1, EMB, EMB);

    // fused wo-reduce + LN2: writes x1 (residual) and h0 (ln2 out) in one pass
    red_wo_ln2<<<NROWS, blk, 0, stream>>>(wosl, wosl + 8*M1, x, bo, ln2g, ln2b, x1, h0);

    transpose_k<<<dim3(16,64), blk, 0, stream>>>(w2, w2T, FF_DIM, EMB);

    // FF1 (gelu): 256^2 8-phase kernel, grid = (4096/256, 4096/256)
    gemm256<2><<<dim3(16,16), dim3(512), 0, stream>>>(h0, w1T, b1, nullptr, nullptr,
                                                      fb, nullptr, nullptr, NROWS, FF_DIM, EMB);

    // FF2: split-K=4, all 4 slabs in dead ws regions; single fused reduce writes d_out
    gemm256sk<<<dim3(4,16,4), dim3(512), 0, stream>>>(fb, w2T, ffsl_lo, ffsl_hi, EMB, FF_DIM);
    reduce_ff2<<<2048, blk, 0, stream>>>(ffsl_lo, ffsl_hi, x1, b2, (float*)d_out);
}